// Round 8
// baseline (1091.696 us; speedup 1.0000x reference)
//
#include <hip/hip_runtime.h>
#include <cmath>

#define KNN 20
#define NPTS 4096
#define BATCH 2
#define SLOPE 0.2f
#define BNEPS 1e-5
#define GTK 16
#define MAXCAND 256

static __device__ __host__ inline int imin(int a, int b) { return a < b ? a : b; }

// ---------------- utility kernels ----------------
// x (B,3,N) -> xb (B,N,3)
__global__ void xtrans_kernel(const float* __restrict__ x, float* __restrict__ xb) {
  int i = blockIdx.x * 256 + threadIdx.x;
  if (i < BATCH * 3 * NPTS) {
    int b = i / (3 * NPTS);
    int r = i - b * 3 * NPTS;
    int c = r / NPTS;
    int n = r - c * NPTS;
    xb[((size_t)b * NPTS + n) * 3 + c] = x[i];
  }
}

// w (O,I) -> wt (I,O)
__global__ void wtrans_kernel(const float* __restrict__ w, float* __restrict__ wt, int O, int I) {
  int i = blockIdx.x * 256 + threadIdx.x;
  if (i < O * I) {
    int o = i / I, j = i - o * I;
    wt[(size_t)j * O + o] = w[i];
  }
}

// W (O, 2C) -> U (C, 2O): U[j][o]=W[o][j]; U[j][O+o]=W[o][C+j]-W[o][j]
__global__ void uprep_kernel(const float* __restrict__ W, float* __restrict__ U, int O, int C) {
  int i = blockIdx.x * 256 + threadIdx.x;
  if (i < C * O) {
    int j = i / O, o = i - j * O;
    float w1 = W[(size_t)o * 2 * C + j];
    float w2 = W[(size_t)o * 2 * C + C + j];
    U[(size_t)j * 2 * O + o] = w1;
    U[(size_t)j * 2 * O + O + o] = w2 - w1;
  }
}

// squared norms per point (fp64 accumulate, fp32 store — candidate pass only)
__global__ void xx_kernel(const float* __restrict__ X, int stride, int C, float* __restrict__ xx) {
  int i = blockIdx.x * 256 + threadIdx.x;
  if (i < BATCH * NPTS) {
    const float* r = X + (size_t)i * stride;
    double s = 0.0;
    for (int c = 0; c < C; ++c) s += (double)r[c] * (double)r[c];
    xx[i] = (float)s;
  }
}

// ---------------- generic 128x128 fp32 GEMM, 8x8 micro, double-buffered ----------------
// C[M x N] = A[M x K] * (BT ? B[N x K]^T : B[K x N]); DIST epilogue: 2*acc - xxA[r] - xxB[c]
// k-major swizzled LDS: phys(row) = row + (row>>5)*4, line stride 144 floats.
// 1 barrier per k-step: prefetch next tile to regs before compute, store to alt buffer after.
template <bool BT, bool DIST>
__global__ __launch_bounds__(256) void gemm128(const float* __restrict__ A, int lda,
                                               const float* __restrict__ B, int ldb,
                                               float* __restrict__ C, int ldc, int K,
                                               const float* __restrict__ xxA,
                                               const float* __restrict__ xxB) {
  __shared__ __align__(16) float sA[2][GTK][144];
  __shared__ __align__(16) float sB[2][GTK][144];
  int t = threadIdx.x;
  int tx = t & 15, ty = t >> 4;
  int row0 = blockIdx.y * 128, col0 = blockIdx.x * 128;
  float acc[8][8] = {};
  float4 fa[2], fb[2];

  auto loadA = [&](int k0) {
#pragma unroll
    for (int it = 0; it < 2; ++it) {
      int i = t + it * 256;
      int r = i >> 2, q = i & 3;
      if (k0 + GTK <= K) {
        fa[it] = *(const float4*)&A[(size_t)(row0 + r) * lda + k0 + q * 4];
      } else {
        float tmp[4];
#pragma unroll
        for (int j = 0; j < 4; ++j) {
          int k = q * 4 + j;
          tmp[j] = (k0 + k < K) ? A[(size_t)(row0 + r) * lda + k0 + k] : 0.f;
        }
        fa[it] = make_float4(tmp[0], tmp[1], tmp[2], tmp[3]);
      }
    }
  };
  auto loadB = [&](int k0) {
#pragma unroll
    for (int it = 0; it < 2; ++it) {
      int i = t + it * 256;
      if (BT) {
        int r = i >> 2, q = i & 3;
        if (k0 + GTK <= K) {
          fb[it] = *(const float4*)&B[(size_t)(col0 + r) * ldb + k0 + q * 4];
        } else {
          float tmp[4];
#pragma unroll
          for (int j = 0; j < 4; ++j) {
            int k = q * 4 + j;
            tmp[j] = (k0 + k < K) ? B[(size_t)(col0 + r) * ldb + k0 + k] : 0.f;
          }
          fb[it] = make_float4(tmp[0], tmp[1], tmp[2], tmp[3]);
        }
      } else {
        int k = i >> 5, nq = (i & 31) * 4;
        fb[it] = (k0 + k < K) ? *(const float4*)&B[(size_t)(k0 + k) * ldb + col0 + nq]
                              : make_float4(0.f, 0.f, 0.f, 0.f);
      }
    }
  };
  auto storeAB = [&](int buf) {
#pragma unroll
    for (int it = 0; it < 2; ++it) {
      int i = t + it * 256;
      int r = i >> 2, q = i & 3;
      int pr = r + ((r >> 5) << 2);
      const float* av = (const float*)&fa[it];
      sA[buf][q * 4 + 0][pr] = av[0];
      sA[buf][q * 4 + 1][pr] = av[1];
      sA[buf][q * 4 + 2][pr] = av[2];
      sA[buf][q * 4 + 3][pr] = av[3];
      if (BT) {
        const float* bv = (const float*)&fb[it];
        sB[buf][q * 4 + 0][pr] = bv[0];
        sB[buf][q * 4 + 1][pr] = bv[1];
        sB[buf][q * 4 + 2][pr] = bv[2];
        sB[buf][q * 4 + 3][pr] = bv[3];
      } else {
        int k = i >> 5, nq = (i & 31) * 4;
        int pc = nq + ((nq >> 5) << 2);
        *(float4*)&sB[buf][k][pc] = fb[it];
      }
    }
  };

  int nk = (K + GTK - 1) / GTK;
  loadA(0);
  loadB(0);
  storeAB(0);
  __syncthreads();
  int prA = ty * 8 + ((ty >> 2) << 2);
  int prB = tx * 8 + ((tx >> 2) << 2);
  for (int kt = 0; kt < nk; ++kt) {
    int buf = kt & 1;
    if (kt + 1 < nk) {
      loadA((kt + 1) * GTK);
      loadB((kt + 1) * GTK);
    }
#pragma unroll
    for (int kk = 0; kk < GTK; ++kk) {
      float a[8], b[8];
      *(float4*)&a[0] = *(const float4*)&sA[buf][kk][prA];
      *(float4*)&a[4] = *(const float4*)&sA[buf][kk][prA + 4];
      *(float4*)&b[0] = *(const float4*)&sB[buf][kk][prB];
      *(float4*)&b[4] = *(const float4*)&sB[buf][kk][prB + 4];
#pragma unroll
      for (int i = 0; i < 8; ++i)
#pragma unroll
        for (int j = 0; j < 8; ++j) acc[i][j] += a[i] * b[j];
    }
    if (kt + 1 < nk) storeAB(1 - buf);
    __syncthreads();
  }

#pragma unroll
  for (int i = 0; i < 8; ++i) {
    int gr = row0 + ty * 8 + i;
    float xa = DIST ? xxA[gr] : 0.f;
#pragma unroll
    for (int jq = 0; jq < 2; ++jq) {
      float4 o;
#pragma unroll
      for (int j = 0; j < 4; ++j) {
        int gc = col0 + tx * 8 + jq * 4 + j;
        float v = acc[i][jq * 4 + j];
        ((float*)&o)[j] = DIST ? (2.f * v - xa - xxB[gc]) : v;
      }
      *(float4*)&C[(size_t)gr * ldc + col0 + tx * 8 + jq * 4] = o;
    }
  }
}

// ---------------- shared top-k selection helpers ----------------
__device__ inline bool comp_less(double v, int i, double ov, int oi) {
  // ascending-by-value; equal values: larger index sorts "less" so that reading
  // descending gives ties -> lower index first (lax.top_k semantics)
  return (v < ov) || (v == ov && i > oi);
}

// ---------------- fast top-k: threshold filter + fp64 rescore + bitonic sort ----------------
// One wave per row. T = 20th-largest lane-max guarantees >=20 pass and fp32-top-20 subset.
// Final ranking: exact fp64 diff-form distance, composite key (-d2, idx), lax.top_k order.
__global__ __launch_bounds__(256) void topk_fast_kernel(const float* __restrict__ dist,
                                                        const float* __restrict__ Xb, int lda,
                                                        int C, int* __restrict__ idxout, int n0,
                                                        int rows) {
  __shared__ int scand[4][MAXCAND];
  int wave = threadIdx.x >> 6, lane = threadIdx.x & 63;
  int row = blockIdx.x * 4 + wave;
  if (row >= rows) return;
  const float* d = dist + (size_t)row * NPTS;
  float v[16][4];
  float lmax = -__builtin_inff();
#pragma unroll
  for (int s = 0; s < 16; ++s) {
    *(float4*)v[s] = *(const float4*)&d[s * 256 + lane * 4];
#pragma unroll
    for (int c = 0; c < 4; ++c) lmax = fmaxf(lmax, v[s][c]);
  }

  // bitonic ascending sort of lane-maxes (values only) -> T at lane 44 (20th largest)
  float sv = lmax;
  for (int k = 2; k <= 64; k <<= 1) {
    for (int j = k >> 1; j > 0; j >>= 1) {
      float ov = __shfl_xor(sv, j);
      bool up = ((lane & k) == 0);
      bool lower = ((lane & j) == 0);
      bool mineLess = sv < ov;
      bool keepMine = (up == lower) ? mineLess : !mineLess;
      sv = keepMine ? sv : ov;
    }
  }
  float T = __shfl(sv, 44);

  // count passers and compact indices into per-wave LDS slab (deterministic order)
  int myCnt = 0;
#pragma unroll
  for (int s = 0; s < 16; ++s)
#pragma unroll
    for (int c = 0; c < 4; ++c) myCnt += (v[s][c] >= T) ? 1 : 0;
  int ofs = myCnt;
  for (int dlt = 1; dlt < 64; dlt <<= 1) {
    int o = __shfl_up(ofs, dlt);
    if (lane >= dlt) ofs += o;
  }
  int total = __shfl(ofs, 63);
  ofs -= myCnt;  // exclusive prefix
  int w = ofs;
#pragma unroll
  for (int s = 0; s < 16; ++s)
#pragma unroll
    for (int c = 0; c < 4; ++c) {
      if (v[s][c] >= T) {
        if (w < MAXCAND) scand[wave][w] = s * 256 + lane * 4 + c;
        ++w;
      }
    }
  int cnt = imin(total, MAXCAND);
  int gn = n0 + row;
  const float* crow = Xb + (size_t)gn * lda;
  int nch = (cnt + 63) >> 6;

  double runV = -__builtin_inf();
  int runI = 0x7fffffff;
  for (int ch = 0; ch < nch; ++ch) {
    int slot = ch * 64 + lane;
    int m = (slot < cnt) ? scand[wave][slot] : -1;
    double val = -__builtin_inf();
    int vi = 0x7fffffff;
    if (m >= 0) {
      const float* mrow = Xb + (size_t)m * lda;
      double dd = 0.0;
      if (C == 3) {
#pragma unroll
        for (int c = 0; c < 3; ++c) {
          double df = (double)crow[c] - (double)mrow[c];
          dd = fma(df, df, dd);
        }
      } else {
        for (int c = 0; c < C; c += 4) {
          float4 a = *(const float4*)&crow[c];
          float4 b = *(const float4*)&mrow[c];
#pragma unroll
          for (int q = 0; q < 4; ++q) {
            double df = (double)((const float*)&a)[q] - (double)((const float*)&b)[q];
            dd = fma(df, df, dd);
          }
        }
      }
      val = -dd;
      vi = m;
    }
    // bitonic ascending sort of this chunk by composite key
    for (int k = 2; k <= 64; k <<= 1) {
      for (int j = k >> 1; j > 0; j >>= 1) {
        double ov = __shfl_xor(val, j);
        int oi = __shfl_xor(vi, j);
        bool up = ((lane & k) == 0);
        bool lower = ((lane & j) == 0);
        bool mineLess = comp_less(val, vi, ov, oi);
        bool keepMine = (up == lower) ? mineLess : !mineLess;
        if (!keepMine) { val = ov; vi = oi; }
      }
    }
    if (ch == 0) {
      runV = val;
      runI = vi;
    } else {
      // merge: pairwise max with reversed chunk -> bitonic clean (ascending)
      double rv = __shfl(val, 63 - lane);
      int ri = __shfl(vi, 63 - lane);
      if (comp_less(runV, runI, rv, ri)) { runV = rv; runI = ri; }
      for (int j = 32; j > 0; j >>= 1) {
        double ov = __shfl_xor(runV, j);
        int oi = __shfl_xor(runI, j);
        bool lower = ((lane & j) == 0);
        bool mineLess = comp_less(runV, runI, ov, oi);
        bool keepMine = lower ? mineLess : !mineLess;
        if (!keepMine) { runV = ov; runI = oi; }
      }
    }
  }
  // ascending run: lane 63 = best. Emit top-20 in descending order.
  if (lane >= 44) idxout[(size_t)gn * KNN + (63 - lane)] = runI;
}

// ---------------- fused layer-1 kNN (C=3): whole point set in LDS ----------------
// grid (NPTS/4, BATCH). Same filter/rescore/sort machinery as topk_fast, distances on the fly.
__global__ __launch_bounds__(256) void dist3_topk_kernel(const float* __restrict__ Xb,
                                                         int* __restrict__ idxout) {
  __shared__ float xs[NPTS], ys[NPTS], zs[NPTS];
  __shared__ int scand[4][MAXCAND];
  int t = threadIdx.x;
  const float* Xbb = Xb + (size_t)blockIdx.y * NPTS * 3;
  for (int i = t; i < NPTS * 3; i += 256) {
    int n = i / 3, c = i - n * 3;
    float v = Xbb[i];
    if (c == 0) xs[n] = v;
    else if (c == 1) ys[n] = v;
    else zs[n] = v;
  }
  __syncthreads();
  int wave = t >> 6, lane = t & 63;
  int row = blockIdx.x * 4 + wave;
  float cx = xs[row], cy = ys[row], cz = zs[row];
  float v[16][4];
  float lmax = -__builtin_inff();
#pragma unroll
  for (int s = 0; s < 16; ++s)
#pragma unroll
    for (int c = 0; c < 4; ++c) {
      int m = s * 256 + c * 64 + lane;  // lane-contiguous: conflict-free LDS
      float dx = cx - xs[m], dy = cy - ys[m], dz = cz - zs[m];
      float dv = -(dx * dx + dy * dy + dz * dz);
      v[s][c] = dv;
      lmax = fmaxf(lmax, dv);
    }

  float sv = lmax;
  for (int k = 2; k <= 64; k <<= 1) {
    for (int j = k >> 1; j > 0; j >>= 1) {
      float ov = __shfl_xor(sv, j);
      bool up = ((lane & k) == 0);
      bool lower = ((lane & j) == 0);
      bool mineLess = sv < ov;
      bool keepMine = (up == lower) ? mineLess : !mineLess;
      sv = keepMine ? sv : ov;
    }
  }
  float T = __shfl(sv, 44);

  int myCnt = 0;
#pragma unroll
  for (int s = 0; s < 16; ++s)
#pragma unroll
    for (int c = 0; c < 4; ++c) myCnt += (v[s][c] >= T) ? 1 : 0;
  int ofs = myCnt;
  for (int dlt = 1; dlt < 64; dlt <<= 1) {
    int o = __shfl_up(ofs, dlt);
    if (lane >= dlt) ofs += o;
  }
  int total = __shfl(ofs, 63);
  ofs -= myCnt;
  int w = ofs;
#pragma unroll
  for (int s = 0; s < 16; ++s)
#pragma unroll
    for (int c = 0; c < 4; ++c) {
      if (v[s][c] >= T) {
        if (w < MAXCAND) scand[wave][w] = s * 256 + c * 64 + lane;
        ++w;
      }
    }
  int cnt = imin(total, MAXCAND);
  int nch = (cnt + 63) >> 6;

  double runV = -__builtin_inf();
  int runI = 0x7fffffff;
  for (int ch = 0; ch < nch; ++ch) {
    int slot = ch * 64 + lane;
    int m = (slot < cnt) ? scand[wave][slot] : -1;
    double val = -__builtin_inf();
    int vi = 0x7fffffff;
    if (m >= 0) {
      double dx = (double)cx - (double)xs[m];
      double dy = (double)cy - (double)ys[m];
      double dz = (double)cz - (double)zs[m];
      val = -(dx * dx + dy * dy + dz * dz);
      vi = m;
    }
    for (int k = 2; k <= 64; k <<= 1) {
      for (int j = k >> 1; j > 0; j >>= 1) {
        double ov = __shfl_xor(val, j);
        int oi = __shfl_xor(vi, j);
        bool up = ((lane & k) == 0);
        bool lower = ((lane & j) == 0);
        bool mineLess = comp_less(val, vi, ov, oi);
        bool keepMine = (up == lower) ? mineLess : !mineLess;
        if (!keepMine) { val = ov; vi = oi; }
      }
    }
    if (ch == 0) {
      runV = val;
      runI = vi;
    } else {
      double rv = __shfl(val, 63 - lane);
      int ri = __shfl(vi, 63 - lane);
      if (comp_less(runV, runI, rv, ri)) { runV = rv; runI = ri; }
      for (int j = 32; j > 0; j >>= 1) {
        double ov = __shfl_xor(runV, j);
        int oi = __shfl_xor(runI, j);
        bool lower = ((lane & j) == 0);
        bool mineLess = comp_less(runV, runI, ov, oi);
        bool keepMine = lower ? mineLess : !mineLess;
        if (!keepMine) { runV = ov; runI = oi; }
      }
    }
  }
  if (lane >= 44)
    idxout[((size_t)blockIdx.y * NPTS + row) * KNN + (63 - lane)] = runI;
}

// ---------------- gather-max + per-block fp64 BN partial stats ----------------
// h[n,k,o] = P[idx[n,k],o] + Q[n,o]; PQ row = [P | Q] (stride 2O). One wave per point.
// Block partials (fp64) to pbuf[blk][2*O] = [sum | sumsq].
template <int NO>
__global__ __launch_bounds__(256) void gathermax_kernel(const float* __restrict__ PQ,
                                                        const int* __restrict__ idx,
                                                        float* __restrict__ hmax, int O,
                                                        double* __restrict__ pbuf) {
  __shared__ double sh1[4][256];
  __shared__ double sh2[4][256];
  int t = threadIdx.x;
  int wave = t >> 6, lane = t & 63;
  int pt = blockIdx.x * 4 + wave;
  int b = pt >> 12;
  int O2 = 2 * O;
  int iv = idx[(size_t)pt * KNN + (lane % KNN)];
  const float* Qp = PQ + (size_t)pt * O2 + O + lane * NO;
  float q[NO], mx[NO];
  double s1[NO], s2[NO];
#pragma unroll
  for (int c = 0; c < NO; ++c) {
    q[c] = Qp[c];
    mx[c] = -__builtin_inff();
    s1[c] = 0.0;
    s2[c] = 0.0;
  }
#pragma unroll
  for (int k = 0; k < KNN; ++k) {
    int m = __shfl(iv, k);
    const float* Pp = PQ + ((size_t)(b << 12) + m) * O2 + lane * NO;
    float p[NO];
#pragma unroll
    for (int c = 0; c < NO; ++c) p[c] = Pp[c];
#pragma unroll
    for (int c = 0; c < NO; ++c) {
      float h = p[c] + q[c];
      mx[c] = fmaxf(mx[c], h);
      double hd = (double)h;
      s1[c] += hd;
      s2[c] += hd * hd;
    }
  }
  float* Hp = hmax + (size_t)pt * O + lane * NO;
#pragma unroll
  for (int c = 0; c < NO; ++c) {
    Hp[c] = mx[c];
    sh1[wave][lane * NO + c] = s1[c];
    sh2[wave][lane * NO + c] = s2[c];
  }
  __syncthreads();
  if (t < O) {
    double a = 0.0, bb = 0.0;
#pragma unroll
    for (int w = 0; w < 4; ++w) {
      a += sh1[w][t];
      bb += sh2[w][t];
    }
    pbuf[(size_t)blockIdx.x * O2 + t] = a;
    pbuf[(size_t)blockIdx.x * O2 + O + t] = bb;
  }
}

// ---------------- deterministic parallel fp64 BN reduce + finalize ----------------
__global__ __launch_bounds__(256) void bn_reduce_finalize(const double* __restrict__ pbuf,
                                                          int nblk, int O,
                                                          const float* __restrict__ g,
                                                          const float* __restrict__ bb,
                                                          double invcount,
                                                          float* __restrict__ s_out,
                                                          float* __restrict__ t_out) {
  __shared__ double sh1[256];
  __shared__ double sh2[256];
  int o = blockIdx.x;
  int t = threadIdx.x;
  double s1 = 0.0, s2 = 0.0;
  for (int blk = t; blk < nblk; blk += 256) {
    s1 += pbuf[(size_t)blk * 2 * O + o];
    s2 += pbuf[(size_t)blk * 2 * O + O + o];
  }
  sh1[t] = s1;
  sh2[t] = s2;
  __syncthreads();
  for (int s = 128; s > 0; s >>= 1) {
    if (t < s) {
      sh1[t] += sh1[t + s];
      sh2[t] += sh2[t + s];
    }
    __syncthreads();
  }
  if (t == 0) {
    double mean = sh1[0] * invcount;
    double var = sh2[0] * invcount - mean * mean;
    double s = (double)g[o] / sqrt(var + BNEPS);
    s_out[o] = (float)s;
    t_out[o] = (float)((double)bb[o] - mean * s);
  }
}

// y = leaky(hmax*s+t) into feat column slice
__global__ void apply_kernel(const float* __restrict__ hmax, const float* __restrict__ s,
                             const float* __restrict__ tt, float* __restrict__ feat,
                             int colOff, int logO, int total) {
  int i = blockIdx.x * 256 + threadIdx.x;
  if (i >= total) return;
  int O = 1 << logO;
  int o = i & (O - 1);
  int pp = i >> logO;
  float v = hmax[i] * s[o] + tt[o];
  feat[(size_t)pp * 512 + colOff + o] = v > 0.f ? v : SLOPE * v;
}

// column partial stats over H (rows x 1024): pbuf[rb][2048] = [sum | sq] (fp64)
__global__ void colstats_kernel(const float* __restrict__ H, double* __restrict__ pbuf) {
  int o = blockIdx.x * 256 + threadIdx.x;
  int rb = blockIdx.y;
  int r0 = rb * 128;
  double s1 = 0.0, s2 = 0.0;
  for (int r = 0; r < 128; ++r) {
    double v = (double)H[(size_t)(r0 + r) * 1024 + o];
    s1 += v;
    s2 += v * v;
  }
  pbuf[(size_t)rb * 2048 + o] = s1;
  pbuf[(size_t)rb * 2048 + 1024 + o] = s2;
}

// out[b][o][n] = leaky(h5[b][n][o]*s+t)
__global__ void out_kernel(const float* __restrict__ h5, const float* __restrict__ s,
                           const float* __restrict__ tt, float* __restrict__ out) {
  __shared__ float tile[32][33];
  int b = blockIdx.z;
  int n0 = blockIdx.x * 32, o0 = blockIdx.y * 32;
  int t = threadIdx.x;
  for (int e = t; e < 1024; e += 256) {
    int rn = e >> 5, co = e & 31;
    int o = o0 + co;
    float v = h5[((size_t)b * NPTS + n0 + rn) * 1024 + o] * s[o] + tt[o];
    tile[rn][co] = v > 0.f ? v : SLOPE * v;
  }
  __syncthreads();
  for (int e = t; e < 1024; e += 256) {
    int ro = e >> 5, cn = e & 31;
    out[((size_t)b * 1024 + o0 + ro) * NPTS + n0 + cn] = tile[cn][ro];
  }
}

// ---------------- host ----------------
extern "C" void kernel_launch(void* const* d_in, const int* in_sizes, int n_in,
                              void* d_out, int out_size, void* d_ws, size_t ws_size,
                              hipStream_t stream) {
  const float* x = (const float*)d_in[0];
  const float* Wm[5] = {(const float*)d_in[1], (const float*)d_in[4], (const float*)d_in[7],
                        (const float*)d_in[10], (const float*)d_in[13]};
  const float* gv[5] = {(const float*)d_in[2], (const float*)d_in[5], (const float*)d_in[8],
                        (const float*)d_in[11], (const float*)d_in[14]};
  const float* bvv[5] = {(const float*)d_in[3], (const float*)d_in[6], (const float*)d_in[9],
                         (const float*)d_in[12], (const float*)d_in[15]};
  float* out = (float*)d_out;

  char* wsb = (char*)d_ws;
  size_t off = 0;
  auto alloc = [&](size_t bytes) -> char* {
    off = (off + 255) & ~(size_t)255;
    char* p = wsb + off;
    off += bytes;
    return p;
  };
  float* xb = (float*)alloc((size_t)BATCH * NPTS * 3 * 4);
  float* xxb = (float*)alloc((size_t)BATCH * NPTS * 4);
  int* idxb = (int*)alloc((size_t)BATCH * NPTS * KNN * 4);
  float* feat = (float*)alloc((size_t)BATCH * NPTS * 512 * 4);
  float* hmax = (float*)alloc((size_t)BATCH * NPTS * 256 * 4);
  float* h5 = (float*)alloc((size_t)BATCH * NPTS * 1024 * 4);
  float* PQ = h5;  // alias: PQ (<=8192x512) used per-layer, h5 only needed after
  float* U1 = (float*)alloc(3 * 128 * 4);
  float* U2 = (float*)alloc(64 * 128 * 4);
  float* U3 = (float*)alloc(64 * 256 * 4);
  float* U4 = (float*)alloc(128 * 512 * 4);
  float* w5t = (float*)alloc(512 * 1024 * 4);
  double* pbuf = (double*)alloc((size_t)2048 * 512 * 8);  // fp64 block partials (max O=256)
  float* stv = (float*)alloc(3072 * 4);
  off = (off + 255) & ~(size_t)255;
  size_t avail = (ws_size > off) ? (ws_size - off) : 0;
  size_t rmax = avail / ((size_t)NPTS * 4);
  int R;
  if (rmax >= NPTS) R = NPTS;
  else {
    R = (int)(rmax & ~(size_t)127);
    if (R < 128) R = 128;
  }
  float* distbuf = (float*)(wsb + off);

  float* sv[5] = {stv + 0, stv + 128, stv + 256, stv + 512, stv + 1024};
  float* tv[5] = {stv + 64, stv + 192, stv + 384, stv + 768, stv + 2048};
  float* Us[4] = {U1, U2, U3, U4};
  const int Cs[4] = {3, 64, 64, 128};
  const int Osz[4] = {64, 64, 128, 256};

  xtrans_kernel<<<(BATCH * 3 * NPTS + 255) / 256, 256, 0, stream>>>(x, xb);
  for (int l = 0; l < 4; ++l)
    uprep_kernel<<<(Cs[l] * Osz[l] + 255) / 256, 256, 0, stream>>>(Wm[l], Us[l], Osz[l], Cs[l]);
  wtrans_kernel<<<(1024 * 512 + 255) / 256, 256, 0, stream>>>(Wm[4], w5t, 1024, 512);

  auto knn = [&](const float* Xbase, int lda, int C) {
    xx_kernel<<<(BATCH * NPTS + 255) / 256, 256, 0, stream>>>(Xbase, lda, C, xxb);
    for (int b = 0; b < BATCH; ++b) {
      const float* Xb = Xbase + (size_t)b * NPTS * lda;
      for (int n0 = 0; n0 < NPTS; n0 += R) {
        int rows = imin(R, NPTS - n0);
        gemm128<true, true><<<dim3(NPTS / 128, rows / 128), 256, 0, stream>>>(
            Xb + (size_t)n0 * lda, lda, Xb, lda, distbuf, NPTS, C, xxb + (size_t)b * NPTS + n0,
            xxb + (size_t)b * NPTS);
        topk_fast_kernel<<<rows / 4, 256, 0, stream>>>(distbuf, Xb, lda, C,
                                                       idxb + (size_t)b * NPTS * KNN, n0, rows);
      }
    }
  };

  auto edge = [&](int li, const float* Xbase, int lda, int C, int O, int colOff) {
    if (li == 0) {
      // fused C=3 kNN: whole point set staged in LDS, no dist matrix
      dist3_topk_kernel<<<dim3(NPTS / 4, BATCH), 256, 0, stream>>>(Xbase, idxb);
    } else {
      knn(Xbase, lda, C);
    }
    int O2 = 2 * O;
    gemm128<false, false><<<dim3(O2 / 128, BATCH * NPTS / 128), 256, 0, stream>>>(
        Xbase, lda, Us[li], O2, PQ, O2, C, nullptr, nullptr);
    int nblk = BATCH * NPTS / 4;
    if (O == 64)
      gathermax_kernel<1><<<nblk, 256, 0, stream>>>(PQ, idxb, hmax, O, pbuf);
    else if (O == 128)
      gathermax_kernel<2><<<nblk, 256, 0, stream>>>(PQ, idxb, hmax, O, pbuf);
    else
      gathermax_kernel<4><<<nblk, 256, 0, stream>>>(PQ, idxb, hmax, O, pbuf);
    bn_reduce_finalize<<<O, 256, 0, stream>>>(pbuf, nblk, O, gv[li], bvv[li],
                                              1.0 / ((double)BATCH * NPTS * KNN), sv[li], tv[li]);
    int logO = (O == 64) ? 6 : (O == 128) ? 7 : 8;
    int total = BATCH * NPTS * O;
    apply_kernel<<<(total + 255) / 256, 256, 0, stream>>>(hmax, sv[li], tv[li], feat, colOff, logO,
                                                          total);
  };

  edge(0, xb, 3, 3, 64, 0);
  edge(1, feat, 512, 64, 64, 64);
  edge(2, feat + 64, 512, 64, 128, 128);
  edge(3, feat + 128, 512, 128, 256, 256);

  gemm128<false, false><<<dim3(1024 / 128, BATCH * NPTS / 128), 256, 0, stream>>>(
      feat, 512, w5t, 1024, h5, 1024, 512, nullptr, nullptr);
  colstats_kernel<<<dim3(4, 64), 256, 0, stream>>>(h5, pbuf);
  bn_reduce_finalize<<<1024, 256, 0, stream>>>(pbuf, 64, 1024, gv[4], bvv[4],
                                               1.0 / ((double)BATCH * NPTS), sv[4], tv[4]);
  out_kernel<<<dim3(NPTS / 32, 1024 / 32, BATCH), 256, 0, stream>>>(h5, sv[4], tv[4], out);
}

// Round 10
// 808.775 us; speedup vs baseline: 1.3498x; 1.3498x over previous
//
#include <hip/hip_runtime.h>
#include <cmath>

#define KNN 20
#define NPTS 4096
#define BATCH 2
#define SLOPE 0.2f
#define BNEPS 1e-5
#define GTK 16
#define MAXCAND 256

typedef unsigned short u16;
typedef __attribute__((ext_vector_type(8))) short bf16x8;
typedef __attribute__((ext_vector_type(4))) float f32x4;

static __device__ __host__ inline int imin(int a, int b) { return a < b ? a : b; }

// ---------------- utility kernels ----------------
// x (B,3,N) -> xb (B,N,3)
__global__ void xtrans_kernel(const float* __restrict__ x, float* __restrict__ xb) {
  int i = blockIdx.x * 256 + threadIdx.x;
  if (i < BATCH * 3 * NPTS) {
    int b = i / (3 * NPTS);
    int r = i - b * 3 * NPTS;
    int c = r / NPTS;
    int n = r - c * NPTS;
    xb[((size_t)b * NPTS + n) * 3 + c] = x[i];
  }
}

// W (O, 2C) -> U (C, 2O): U[j][o]=W[o][j]; U[j][O+o]=W[o][C+j]-W[o][j]
__global__ void uprep_kernel(const float* __restrict__ W, float* __restrict__ U, int O, int C) {
  int i = blockIdx.x * 256 + threadIdx.x;
  if (i < C * O) {
    int j = i / O, o = i - j * O;
    float w1 = W[(size_t)o * 2 * C + j];
    float w2 = W[(size_t)o * 2 * C + C + j];
    U[(size_t)j * 2 * O + o] = w1;
    U[(size_t)j * 2 * O + O + o] = w2 - w1;
  }
}

// squared norms per point (fp64 accumulate, fp32 store — candidate pass only)
__global__ void xx_kernel(const float* __restrict__ X, int stride, int C, float* __restrict__ xx) {
  int i = blockIdx.x * 256 + threadIdx.x;
  if (i < BATCH * NPTS) {
    const float* r = X + (size_t)i * stride;
    double s = 0.0;
    for (int c = 0; c < C; ++c) s += (double)r[c] * (double)r[c];
    xx[i] = (float)s;
  }
}

// fp32 -> bf16 (RNE), 4 elements/thread
__global__ void tobf16_kernel(const float* __restrict__ src, u16* __restrict__ dst, int n4) {
  int i = blockIdx.x * 256 + threadIdx.x;
  if (i < n4) {
    float4 v = *(const float4*)&src[(size_t)i * 4];
    unsigned o[4];
#pragma unroll
    for (int j = 0; j < 4; ++j) {
      unsigned x = __float_as_uint(((const float*)&v)[j]);
      unsigned rr = x + 0x7fff + ((x >> 16) & 1);
      o[j] = rr >> 16;
    }
    uint2 pk;
    pk.x = o[0] | (o[1] << 16);
    pk.y = o[2] | (o[3] << 16);
    *(uint2*)&dst[(size_t)i * 4] = pk;
  }
}

// ---------------- generic 128x128 fp32 GEMM, 8x8 micro (single-buffered) ----------------
// C[M x N] = A[M x K] * (BT ? B[N x K]^T : B[K x N]); DIST epilogue: 2*acc - xxA[r] - xxB[c]
// k-major swizzled LDS: phys(row) = row + (row>>5)*4, line stride 144 floats.
template <bool BT, bool DIST>
__global__ __launch_bounds__(256) void gemm128(const float* __restrict__ A, int lda,
                                               const float* __restrict__ B, int ldb,
                                               float* __restrict__ C, int ldc, int K,
                                               const float* __restrict__ xxA,
                                               const float* __restrict__ xxB) {
  __shared__ __align__(16) float sA[GTK][144];
  __shared__ __align__(16) float sB[GTK][144];
  int t = threadIdx.x;
  int tx = t & 15, ty = t >> 4;
  int row0 = blockIdx.y * 128, col0 = blockIdx.x * 128;
  float acc[8][8] = {};

  for (int k0 = 0; k0 < K; k0 += GTK) {
    bool fast = (k0 + GTK <= K);
    if (fast) {
#pragma unroll
      for (int it = 0; it < 2; ++it) {
        int i = t + it * 256;
        int r = i >> 2, q = i & 3;
        const float4 av = *(const float4*)&A[(size_t)(row0 + r) * lda + k0 + q * 4];
        int pr = r + ((r >> 5) << 2);
        sA[q * 4 + 0][pr] = av.x;
        sA[q * 4 + 1][pr] = av.y;
        sA[q * 4 + 2][pr] = av.z;
        sA[q * 4 + 3][pr] = av.w;
      }
    } else {
#pragma unroll
      for (int it = 0; it < 2; ++it) {
        int i = t + it * 256;
        int r = i >> 2, q = i & 3;
        int pr = r + ((r >> 5) << 2);
#pragma unroll
        for (int j = 0; j < 4; ++j) {
          int k = q * 4 + j;
          sA[k][pr] = (k0 + k < K) ? A[(size_t)(row0 + r) * lda + k0 + k] : 0.f;
        }
      }
    }
    if (BT) {
      if (fast) {
#pragma unroll
        for (int it = 0; it < 2; ++it) {
          int i = t + it * 256;
          int r = i >> 2, q = i & 3;
          const float4 bv = *(const float4*)&B[(size_t)(col0 + r) * ldb + k0 + q * 4];
          int pr = r + ((r >> 5) << 2);
          sB[q * 4 + 0][pr] = bv.x;
          sB[q * 4 + 1][pr] = bv.y;
          sB[q * 4 + 2][pr] = bv.z;
          sB[q * 4 + 3][pr] = bv.w;
        }
      } else {
#pragma unroll
        for (int it = 0; it < 2; ++it) {
          int i = t + it * 256;
          int r = i >> 2, q = i & 3;
          int pr = r + ((r >> 5) << 2);
#pragma unroll
          for (int j = 0; j < 4; ++j) {
            int k = q * 4 + j;
            sB[k][pr] = (k0 + k < K) ? B[(size_t)(col0 + r) * ldb + k0 + k] : 0.f;
          }
        }
      }
    } else {
#pragma unroll
      for (int it = 0; it < 2; ++it) {
        int i = t + it * 256;
        int k = i >> 5, nq = (i & 31) * 4;
        int pc = nq + ((nq >> 5) << 2);
        float4 bv = make_float4(0.f, 0.f, 0.f, 0.f);
        if (k0 + k < K) bv = *(const float4*)&B[(size_t)(k0 + k) * ldb + col0 + nq];
        *(float4*)&sB[k][pc] = bv;
      }
    }
    __syncthreads();
    int prA = ty * 8 + ((ty >> 2) << 2);
    int prB = tx * 8 + ((tx >> 2) << 2);
#pragma unroll
    for (int kk = 0; kk < GTK; ++kk) {
      float a[8], b[8];
      *(float4*)&a[0] = *(const float4*)&sA[kk][prA];
      *(float4*)&a[4] = *(const float4*)&sA[kk][prA + 4];
      *(float4*)&b[0] = *(const float4*)&sB[kk][prB];
      *(float4*)&b[4] = *(const float4*)&sB[kk][prB + 4];
#pragma unroll
      for (int i = 0; i < 8; ++i)
#pragma unroll
        for (int j = 0; j < 8; ++j) acc[i][j] += a[i] * b[j];
    }
    __syncthreads();
  }

#pragma unroll
  for (int i = 0; i < 8; ++i) {
    int gr = row0 + ty * 8 + i;
    float xa = DIST ? xxA[gr] : 0.f;
#pragma unroll
    for (int jq = 0; jq < 2; ++jq) {
      float4 o;
#pragma unroll
      for (int j = 0; j < 4; ++j) {
        int gc = col0 + tx * 8 + jq * 4 + j;
        float v = acc[i][jq * 4 + j];
        ((float*)&o)[j] = DIST ? (2.f * v - xa - xxB[gc]) : v;
      }
      *(float4*)&C[(size_t)gr * ldc + col0 + tx * 8 + jq * 4] = o;
    }
  }
}

// ---------------- bf16 MFMA FC: C[8192x1024] = A[8192x512] * B[1024x512]^T ----------------
// A,B bf16 row-major; fp32 accumulate. Tile 128x128, 4 waves x (64x64), 16x16x32 MFMA.
// LDS rows padded to 56 u16 (16B aligned, <=2-way banks). Fragment map per m89/m97.
// Loader: 2 iterations x 256 threads x uint4 = 128 rows x 32 u16 per matrix per k-step.
__global__ __launch_bounds__(256) void fc_mfma_kernel(const u16* __restrict__ A,
                                                      const u16* __restrict__ B,
                                                      float* __restrict__ C) {
  __shared__ u16 sA[128][56];
  __shared__ u16 sB[128][56];
  int t = threadIdx.x;
  int lane = t & 63, wave = t >> 6;
  int row0 = blockIdx.y * 128, col0 = blockIdx.x * 128;
  int wr = (wave >> 1) * 64, wc = (wave & 1) * 64;
  int m = lane & 15, q = lane >> 4;
  f32x4 acc[4][4];
#pragma unroll
  for (int i = 0; i < 4; ++i)
#pragma unroll
    for (int j = 0; j < 4; ++j) acc[i][j] = (f32x4){0.f, 0.f, 0.f, 0.f};
  for (int k0 = 0; k0 < 512; k0 += 32) {
#pragma unroll
    for (int it = 0; it < 2; ++it) {
      int i = t + it * 256;
      int r = i >> 2, ch = (i & 3) * 8;
      *(uint4*)&sA[r][ch] = *(const uint4*)&A[(size_t)(row0 + r) * 512 + k0 + ch];
      *(uint4*)&sB[r][ch] = *(const uint4*)&B[(size_t)(col0 + r) * 512 + k0 + ch];
    }
    __syncthreads();
    bf16x8 af[4], bf[4];
#pragma unroll
    for (int i = 0; i < 4; ++i) af[i] = *(const bf16x8*)&sA[wr + i * 16 + m][q * 8];
#pragma unroll
    for (int j = 0; j < 4; ++j) bf[j] = *(const bf16x8*)&sB[wc + j * 16 + m][q * 8];
#pragma unroll
    for (int i = 0; i < 4; ++i)
#pragma unroll
      for (int j = 0; j < 4; ++j)
        acc[i][j] = __builtin_amdgcn_mfma_f32_16x16x32_bf16(af[i], bf[j], acc[i][j], 0, 0, 0);
    __syncthreads();
  }
#pragma unroll
  for (int i = 0; i < 4; ++i)
#pragma unroll
    for (int j = 0; j < 4; ++j)
#pragma unroll
      for (int reg = 0; reg < 4; ++reg)
        C[(size_t)(row0 + wr + i * 16 + q * 4 + reg) * 1024 + col0 + wc + j * 16 + m] =
            acc[i][j][reg];
}

// ---------------- shared top-k selection helpers ----------------
__device__ inline bool comp_less(double v, int i, double ov, int oi) {
  // ascending-by-value; ties: larger index sorts "less" -> descending read gives lower idx first
  return (v < ov) || (v == ov && i > oi);
}

// ---------------- fast top-k: threshold filter + fp64 rescore + bitonic sort ----------------
__global__ __launch_bounds__(256) void topk_fast_kernel(const float* __restrict__ dist,
                                                        const float* __restrict__ Xb, int lda,
                                                        int C, int* __restrict__ idxout, int n0,
                                                        int rows) {
  __shared__ int scand[4][MAXCAND];
  int wave = threadIdx.x >> 6, lane = threadIdx.x & 63;
  int row = blockIdx.x * 4 + wave;
  if (row >= rows) return;
  const float* d = dist + (size_t)row * NPTS;
  float v[16][4];
  float lmax = -__builtin_inff();
#pragma unroll
  for (int s = 0; s < 16; ++s) {
    *(float4*)v[s] = *(const float4*)&d[s * 256 + lane * 4];
#pragma unroll
    for (int c = 0; c < 4; ++c) lmax = fmaxf(lmax, v[s][c]);
  }

  float sv = lmax;
  for (int k = 2; k <= 64; k <<= 1) {
    for (int j = k >> 1; j > 0; j >>= 1) {
      float ov = __shfl_xor(sv, j);
      bool up = ((lane & k) == 0);
      bool lower = ((lane & j) == 0);
      bool mineLess = sv < ov;
      bool keepMine = (up == lower) ? mineLess : !mineLess;
      sv = keepMine ? sv : ov;
    }
  }
  float T = __shfl(sv, 44);

  int myCnt = 0;
#pragma unroll
  for (int s = 0; s < 16; ++s)
#pragma unroll
    for (int c = 0; c < 4; ++c) myCnt += (v[s][c] >= T) ? 1 : 0;
  int ofs = myCnt;
  for (int dlt = 1; dlt < 64; dlt <<= 1) {
    int o = __shfl_up(ofs, dlt);
    if (lane >= dlt) ofs += o;
  }
  int total = __shfl(ofs, 63);
  ofs -= myCnt;
  int w = ofs;
#pragma unroll
  for (int s = 0; s < 16; ++s)
#pragma unroll
    for (int c = 0; c < 4; ++c) {
      if (v[s][c] >= T) {
        if (w < MAXCAND) scand[wave][w] = s * 256 + lane * 4 + c;
        ++w;
      }
    }
  int cnt = imin(total, MAXCAND);
  int gn = n0 + row;
  const float* crow = Xb + (size_t)gn * lda;
  int nch = (cnt + 63) >> 6;

  double runV = -__builtin_inf();
  int runI = 0x7fffffff;
  for (int ch = 0; ch < nch; ++ch) {
    int slot = ch * 64 + lane;
    int m = (slot < cnt) ? scand[wave][slot] : -1;
    double val = -__builtin_inf();
    int vi = 0x7fffffff;
    if (m >= 0) {
      const float* mrow = Xb + (size_t)m * lda;
      double dd = 0.0;
      for (int c = 0; c < C; c += 4) {
        float4 a = *(const float4*)&crow[c];
        float4 b = *(const float4*)&mrow[c];
#pragma unroll
        for (int qq = 0; qq < 4; ++qq) {
          double df = (double)((const float*)&a)[qq] - (double)((const float*)&b)[qq];
          dd = fma(df, df, dd);
        }
      }
      val = -dd;
      vi = m;
    }
    for (int k = 2; k <= 64; k <<= 1) {
      for (int j = k >> 1; j > 0; j >>= 1) {
        double ov = __shfl_xor(val, j);
        int oi = __shfl_xor(vi, j);
        bool up = ((lane & k) == 0);
        bool lower = ((lane & j) == 0);
        bool mineLess = comp_less(val, vi, ov, oi);
        bool keepMine = (up == lower) ? mineLess : !mineLess;
        if (!keepMine) { val = ov; vi = oi; }
      }
    }
    if (ch == 0) {
      runV = val;
      runI = vi;
    } else {
      double rv = __shfl(val, 63 - lane);
      int ri = __shfl(vi, 63 - lane);
      if (comp_less(runV, runI, rv, ri)) { runV = rv; runI = ri; }
      for (int j = 32; j > 0; j >>= 1) {
        double ov = __shfl_xor(runV, j);
        int oi = __shfl_xor(runI, j);
        bool lower = ((lane & j) == 0);
        bool mineLess = comp_less(runV, runI, ov, oi);
        bool keepMine = lower ? mineLess : !mineLess;
        if (!keepMine) { runV = ov; runI = oi; }
      }
    }
  }
  if (lane >= 44) idxout[(size_t)gn * KNN + (63 - lane)] = runI;
}

// ---------------- fused layer-1 kNN (C=3): whole point set in LDS ----------------
__global__ __launch_bounds__(256) void dist3_topk_kernel(const float* __restrict__ Xb,
                                                         int* __restrict__ idxout) {
  __shared__ float xs[NPTS], ys[NPTS], zs[NPTS];
  __shared__ int scand[4][MAXCAND];
  int t = threadIdx.x;
  const float* Xbb = Xb + (size_t)blockIdx.y * NPTS * 3;
  for (int i = t; i < NPTS * 3; i += 256) {
    int n = i / 3, c = i - n * 3;
    float v = Xbb[i];
    if (c == 0) xs[n] = v;
    else if (c == 1) ys[n] = v;
    else zs[n] = v;
  }
  __syncthreads();
  int wave = t >> 6, lane = t & 63;
  int row = blockIdx.x * 4 + wave;
  float cx = xs[row], cy = ys[row], cz = zs[row];
  float v[16][4];
  float lmax = -__builtin_inff();
#pragma unroll
  for (int s = 0; s < 16; ++s)
#pragma unroll
    for (int c = 0; c < 4; ++c) {
      int m = s * 256 + c * 64 + lane;
      float dx = cx - xs[m], dy = cy - ys[m], dz = cz - zs[m];
      float dv = -(dx * dx + dy * dy + dz * dz);
      v[s][c] = dv;
      lmax = fmaxf(lmax, dv);
    }

  float sv = lmax;
  for (int k = 2; k <= 64; k <<= 1) {
    for (int j = k >> 1; j > 0; j >>= 1) {
      float ov = __shfl_xor(sv, j);
      bool up = ((lane & k) == 0);
      bool lower = ((lane & j) == 0);
      bool mineLess = sv < ov;
      bool keepMine = (up == lower) ? mineLess : !mineLess;
      sv = keepMine ? sv : ov;
    }
  }
  float T = __shfl(sv, 44);

  int myCnt = 0;
#pragma unroll
  for (int s = 0; s < 16; ++s)
#pragma unroll
    for (int c = 0; c < 4; ++c) myCnt += (v[s][c] >= T) ? 1 : 0;
  int ofs = myCnt;
  for (int dlt = 1; dlt < 64; dlt <<= 1) {
    int o = __shfl_up(ofs, dlt);
    if (lane >= dlt) ofs += o;
  }
  int total = __shfl(ofs, 63);
  ofs -= myCnt;
  int w = ofs;
#pragma unroll
  for (int s = 0; s < 16; ++s)
#pragma unroll
    for (int c = 0; c < 4; ++c) {
      if (v[s][c] >= T) {
        if (w < MAXCAND) scand[wave][w] = s * 256 + c * 64 + lane;
        ++w;
      }
    }
  int cnt = imin(total, MAXCAND);
  int nch = (cnt + 63) >> 6;

  double runV = -__builtin_inf();
  int runI = 0x7fffffff;
  for (int ch = 0; ch < nch; ++ch) {
    int slot = ch * 64 + lane;
    int m = (slot < cnt) ? scand[wave][slot] : -1;
    double val = -__builtin_inf();
    int vi = 0x7fffffff;
    if (m >= 0) {
      double dx = (double)cx - (double)xs[m];
      double dy = (double)cy - (double)ys[m];
      double dz = (double)cz - (double)zs[m];
      val = -(dx * dx + dy * dy + dz * dz);
      vi = m;
    }
    for (int k = 2; k <= 64; k <<= 1) {
      for (int j = k >> 1; j > 0; j >>= 1) {
        double ov = __shfl_xor(val, j);
        int oi = __shfl_xor(vi, j);
        bool up = ((lane & k) == 0);
        bool lower = ((lane & j) == 0);
        bool mineLess = comp_less(val, vi, ov, oi);
        bool keepMine = (up == lower) ? mineLess : !mineLess;
        if (!keepMine) { val = ov; vi = oi; }
      }
    }
    if (ch == 0) {
      runV = val;
      runI = vi;
    } else {
      double rv = __shfl(val, 63 - lane);
      int ri = __shfl(vi, 63 - lane);
      if (comp_less(runV, runI, rv, ri)) { runV = rv; runI = ri; }
      for (int j = 32; j > 0; j >>= 1) {
        double ov = __shfl_xor(runV, j);
        int oi = __shfl_xor(runI, j);
        bool lower = ((lane & j) == 0);
        bool mineLess = comp_less(runV, runI, ov, oi);
        bool keepMine = lower ? mineLess : !mineLess;
        if (!keepMine) { runV = ov; runI = oi; }
      }
    }
  }
  if (lane >= 44)
    idxout[((size_t)blockIdx.y * NPTS + row) * KNN + (63 - lane)] = runI;
}

// ---------------- gather-max + per-block fp64 BN partial stats ----------------
template <int NO>
__global__ __launch_bounds__(256) void gathermax_kernel(const float* __restrict__ PQ,
                                                        const int* __restrict__ idx,
                                                        float* __restrict__ hmax, int O,
                                                        double* __restrict__ pbuf) {
  __shared__ double sh1[4][256];
  __shared__ double sh2[4][256];
  int t = threadIdx.x;
  int wave = t >> 6, lane = t & 63;
  int pt = blockIdx.x * 4 + wave;
  int b = pt >> 12;
  int O2 = 2 * O;
  int iv = idx[(size_t)pt * KNN + (lane % KNN)];
  const float* Qp = PQ + (size_t)pt * O2 + O + lane * NO;
  float q[NO], mx[NO];
  double s1[NO], s2[NO];
#pragma unroll
  for (int c = 0; c < NO; ++c) {
    q[c] = Qp[c];
    mx[c] = -__builtin_inff();
    s1[c] = 0.0;
    s2[c] = 0.0;
  }
#pragma unroll
  for (int k = 0; k < KNN; ++k) {
    int m = __shfl(iv, k);
    const float* Pp = PQ + ((size_t)(b << 12) + m) * O2 + lane * NO;
    float p[NO];
#pragma unroll
    for (int c = 0; c < NO; ++c) p[c] = Pp[c];
#pragma unroll
    for (int c = 0; c < NO; ++c) {
      float h = p[c] + q[c];
      mx[c] = fmaxf(mx[c], h);
      double hd = (double)h;
      s1[c] += hd;
      s2[c] += hd * hd;
    }
  }
  float* Hp = hmax + (size_t)pt * O + lane * NO;
#pragma unroll
  for (int c = 0; c < NO; ++c) {
    Hp[c] = mx[c];
    sh1[wave][lane * NO + c] = s1[c];
    sh2[wave][lane * NO + c] = s2[c];
  }
  __syncthreads();
  if (t < O) {
    double a = 0.0, bb = 0.0;
#pragma unroll
    for (int w = 0; w < 4; ++w) {
      a += sh1[w][t];
      bb += sh2[w][t];
    }
    pbuf[(size_t)blockIdx.x * O2 + t] = a;
    pbuf[(size_t)blockIdx.x * O2 + O + t] = bb;
  }
}

// ---------------- deterministic parallel fp64 BN reduce + finalize ----------------
__global__ __launch_bounds__(256) void bn_reduce_finalize(const double* __restrict__ pbuf,
                                                          int nblk, int O,
                                                          const float* __restrict__ g,
                                                          const float* __restrict__ bb,
                                                          double invcount,
                                                          float* __restrict__ s_out,
                                                          float* __restrict__ t_out) {
  __shared__ double sh1[256];
  __shared__ double sh2[256];
  int o = blockIdx.x;
  int t = threadIdx.x;
  double s1 = 0.0, s2 = 0.0;
  for (int blk = t; blk < nblk; blk += 256) {
    s1 += pbuf[(size_t)blk * 2 * O + o];
    s2 += pbuf[(size_t)blk * 2 * O + O + o];
  }
  sh1[t] = s1;
  sh2[t] = s2;
  __syncthreads();
  for (int s = 128; s > 0; s >>= 1) {
    if (t < s) {
      sh1[t] += sh1[t + s];
      sh2[t] += sh2[t + s];
    }
    __syncthreads();
  }
  if (t == 0) {
    double mean = sh1[0] * invcount;
    double var = sh2[0] * invcount - mean * mean;
    double s = (double)g[o] / sqrt(var + BNEPS);
    s_out[o] = (float)s;
    t_out[o] = (float)((double)bb[o] - mean * s);
  }
}

// y = leaky(hmax*s+t) into feat column slice
__global__ void apply_kernel(const float* __restrict__ hmax, const float* __restrict__ s,
                             const float* __restrict__ tt, float* __restrict__ feat,
                             int colOff, int logO, int total) {
  int i = blockIdx.x * 256 + threadIdx.x;
  if (i >= total) return;
  int O = 1 << logO;
  int o = i & (O - 1);
  int pp = i >> logO;
  float v = hmax[i] * s[o] + tt[o];
  feat[(size_t)pp * 512 + colOff + o] = v > 0.f ? v : SLOPE * v;
}

// column partial stats over H (rows x 1024): pbuf[rb][2048] = [sum | sq] (fp64)
__global__ void colstats_kernel(const float* __restrict__ H, double* __restrict__ pbuf) {
  int o = blockIdx.x * 256 + threadIdx.x;
  int rb = blockIdx.y;
  int r0 = rb * 128;
  double s1 = 0.0, s2 = 0.0;
  for (int r = 0; r < 128; ++r) {
    double v = (double)H[(size_t)(r0 + r) * 1024 + o];
    s1 += v;
    s2 += v * v;
  }
  pbuf[(size_t)rb * 2048 + o] = s1;
  pbuf[(size_t)rb * 2048 + 1024 + o] = s2;
}

// out[b][o][n] = leaky(h5[b][n][o]*s+t)
__global__ void out_kernel(const float* __restrict__ h5, const float* __restrict__ s,
                           const float* __restrict__ tt, float* __restrict__ out) {
  __shared__ float tile[32][33];
  int b = blockIdx.z;
  int n0 = blockIdx.x * 32, o0 = blockIdx.y * 32;
  int t = threadIdx.x;
  for (int e = t; e < 1024; e += 256) {
    int rn = e >> 5, co = e & 31;
    int o = o0 + co;
    float v = h5[((size_t)b * NPTS + n0 + rn) * 1024 + o] * s[o] + tt[o];
    tile[rn][co] = v > 0.f ? v : SLOPE * v;
  }
  __syncthreads();
  for (int e = t; e < 1024; e += 256) {
    int ro = e >> 5, cn = e & 31;
    out[((size_t)b * 1024 + o0 + ro) * NPTS + n0 + cn] = tile[cn][ro];
  }
}

// ---------------- host ----------------
extern "C" void kernel_launch(void* const* d_in, const int* in_sizes, int n_in,
                              void* d_out, int out_size, void* d_ws, size_t ws_size,
                              hipStream_t stream) {
  const float* x = (const float*)d_in[0];
  const float* Wm[5] = {(const float*)d_in[1], (const float*)d_in[4], (const float*)d_in[7],
                        (const float*)d_in[10], (const float*)d_in[13]};
  const float* gv[5] = {(const float*)d_in[2], (const float*)d_in[5], (const float*)d_in[8],
                        (const float*)d_in[11], (const float*)d_in[14]};
  const float* bvv[5] = {(const float*)d_in[3], (const float*)d_in[6], (const float*)d_in[9],
                         (const float*)d_in[12], (const float*)d_in[15]};
  float* out = (float*)d_out;

  char* wsb = (char*)d_ws;
  size_t off = 0;
  auto alloc = [&](size_t bytes) -> char* {
    off = (off + 255) & ~(size_t)255;
    char* p = wsb + off;
    off += bytes;
    return p;
  };
  float* xb = (float*)alloc((size_t)BATCH * NPTS * 3 * 4);
  float* xxb = (float*)alloc((size_t)BATCH * NPTS * 4);
  int* idxb = (int*)alloc((size_t)BATCH * NPTS * KNN * 4);
  float* feat = (float*)alloc((size_t)BATCH * NPTS * 512 * 4);
  float* hmax = (float*)alloc((size_t)BATCH * NPTS * 256 * 4);
  float* h5 = (float*)alloc((size_t)BATCH * NPTS * 1024 * 4);
  float* PQ = h5;  // alias: PQ used per-layer, h5 only needed after
  float* U1 = (float*)alloc(3 * 128 * 4);
  float* U2 = (float*)alloc(64 * 128 * 4);
  float* U3 = (float*)alloc(64 * 256 * 4);
  float* U4 = (float*)alloc(128 * 512 * 4);
  u16* featbf = (u16*)alloc((size_t)BATCH * NPTS * 512 * 2);
  u16* w5bf = (u16*)alloc((size_t)1024 * 512 * 2);
  double* pbuf = (double*)alloc((size_t)2048 * 512 * 8);
  float* stv = (float*)alloc(3072 * 4);
  off = (off + 255) & ~(size_t)255;
  size_t avail = (ws_size > off) ? (ws_size - off) : 0;
  size_t rmax = avail / ((size_t)NPTS * 4);
  int R;
  if (rmax >= NPTS) R = NPTS;
  else {
    R = (int)(rmax & ~(size_t)127);
    if (R < 128) R = 128;
  }
  float* distbuf = (float*)(wsb + off);

  float* sv[5] = {stv + 0, stv + 128, stv + 256, stv + 512, stv + 1024};
  float* tv[5] = {stv + 64, stv + 192, stv + 384, stv + 768, stv + 2048};
  float* Us[4] = {U1, U2, U3, U4};
  const int Cs[4] = {3, 64, 64, 128};
  const int Osz[4] = {64, 64, 128, 256};

  xtrans_kernel<<<(BATCH * 3 * NPTS + 255) / 256, 256, 0, stream>>>(x, xb);
  for (int l = 0; l < 4; ++l)
    uprep_kernel<<<(Cs[l] * Osz[l] + 255) / 256, 256, 0, stream>>>(Wm[l], Us[l], Osz[l], Cs[l]);
  tobf16_kernel<<<(1024 * 512 / 4 + 255) / 256, 256, 0, stream>>>(Wm[4], w5bf, 1024 * 512 / 4);

  auto knn = [&](const float* Xbase, int lda, int C) {
    xx_kernel<<<(BATCH * NPTS + 255) / 256, 256, 0, stream>>>(Xbase, lda, C, xxb);
    for (int b = 0; b < BATCH; ++b) {
      const float* Xb = Xbase + (size_t)b * NPTS * lda;
      for (int n0 = 0; n0 < NPTS; n0 += R) {
        int rows = imin(R, NPTS - n0);
        gemm128<true, true><<<dim3(NPTS / 128, rows / 128), 256, 0, stream>>>(
            Xb + (size_t)n0 * lda, lda, Xb, lda, distbuf, NPTS, C, xxb + (size_t)b * NPTS + n0,
            xxb + (size_t)b * NPTS);
        topk_fast_kernel<<<rows / 4, 256, 0, stream>>>(distbuf, Xb, lda, C,
                                                       idxb + (size_t)b * NPTS * KNN, n0, rows);
      }
    }
  };

  auto edge = [&](int li, const float* Xbase, int lda, int C, int O, int colOff) {
    if (li == 0) {
      dist3_topk_kernel<<<dim3(NPTS / 4, BATCH), 256, 0, stream>>>(Xbase, idxb);
    } else {
      knn(Xbase, lda, C);
    }
    int O2 = 2 * O;
    gemm128<false, false><<<dim3(O2 / 128, BATCH * NPTS / 128), 256, 0, stream>>>(
        Xbase, lda, Us[li], O2, PQ, O2, C, nullptr, nullptr);
    int nblk = BATCH * NPTS / 4;
    if (O == 64)
      gathermax_kernel<1><<<nblk, 256, 0, stream>>>(PQ, idxb, hmax, O, pbuf);
    else if (O == 128)
      gathermax_kernel<2><<<nblk, 256, 0, stream>>>(PQ, idxb, hmax, O, pbuf);
    else
      gathermax_kernel<4><<<nblk, 256, 0, stream>>>(PQ, idxb, hmax, O, pbuf);
    bn_reduce_finalize<<<O, 256, 0, stream>>>(pbuf, nblk, O, gv[li], bvv[li],
                                              1.0 / ((double)BATCH * NPTS * KNN), sv[li], tv[li]);
    int logO = (O == 64) ? 6 : (O == 128) ? 7 : 8;
    int total = BATCH * NPTS * O;
    apply_kernel<<<(total + 255) / 256, 256, 0, stream>>>(hmax, sv[li], tv[li], feat, colOff, logO,
                                                          total);
  };

  edge(0, xb, 3, 3, 64, 0);
  edge(1, feat, 512, 64, 64, 64);
  edge(2, feat + 64, 512, 64, 128, 128);
  edge(3, feat + 128, 512, 128, 256, 256);

  tobf16_kernel<<<((int)((size_t)BATCH * NPTS * 512 / 4) + 255) / 256, 256, 0, stream>>>(
      feat, featbf, (int)((size_t)BATCH * NPTS * 512 / 4));
  fc_mfma_kernel<<<dim3(1024 / 128, BATCH * NPTS / 128), 256, 0, stream>>>(featbf, w5bf, h5);
  colstats_kernel<<<dim3(4, 64), 256, 0, stream>>>(h5, pbuf);
  bn_reduce_finalize<<<1024, 256, 0, stream>>>(pbuf, 64, 1024, gv[4], bvv[4],
                                               1.0 / ((double)BATCH * NPTS), sv[4], tv[4]);
  out_kernel<<<dim3(NPTS / 32, 1024 / 32, BATCH), 256, 0, stream>>>(h5, sv[4], tv[4], out);
}

// Round 11
// 774.050 us; speedup vs baseline: 1.4104x; 1.0449x over previous
//
#include <hip/hip_runtime.h>
#include <cmath>

#define KNN 20
#define NPTS 4096
#define BATCH 2
#define SLOPE 0.2f
#define BNEPS 1e-5
#define GTK 16
#define MAXCAND 256

typedef unsigned short u16;
typedef __attribute__((ext_vector_type(8))) short bf16x8;
typedef __attribute__((ext_vector_type(4))) float f32x4;

static __device__ __host__ inline int imin(int a, int b) { return a < b ? a : b; }

// ---------------- utility kernels ----------------
// x (B,3,N) -> xb (B,N,3)
__global__ void xtrans_kernel(const float* __restrict__ x, float* __restrict__ xb) {
  int i = blockIdx.x * 256 + threadIdx.x;
  if (i < BATCH * 3 * NPTS) {
    int b = i / (3 * NPTS);
    int r = i - b * 3 * NPTS;
    int c = r / NPTS;
    int n = r - c * NPTS;
    xb[((size_t)b * NPTS + n) * 3 + c] = x[i];
  }
}

// W (O, 2C) -> U (C, 2O): U[j][o]=W[o][j]; U[j][O+o]=W[o][C+j]-W[o][j]
__global__ void uprep_kernel(const float* __restrict__ W, float* __restrict__ U, int O, int C) {
  int i = blockIdx.x * 256 + threadIdx.x;
  if (i < C * O) {
    int j = i / O, o = i - j * O;
    float w1 = W[(size_t)o * 2 * C + j];
    float w2 = W[(size_t)o * 2 * C + C + j];
    U[(size_t)j * 2 * O + o] = w1;
    U[(size_t)j * 2 * O + O + o] = w2 - w1;
  }
}

// squared norms per point (fp64 accumulate, fp32 store — candidate pass only)
__global__ void xx_kernel(const float* __restrict__ X, int stride, int C, float* __restrict__ xx) {
  int i = blockIdx.x * 256 + threadIdx.x;
  if (i < BATCH * NPTS) {
    const float* r = X + (size_t)i * stride;
    double s = 0.0;
    for (int c = 0; c < C; ++c) s += (double)r[c] * (double)r[c];
    xx[i] = (float)s;
  }
}

// fp32 -> bf16 (RNE), 4 elements/thread
__global__ void tobf16_kernel(const float* __restrict__ src, u16* __restrict__ dst, int n4) {
  int i = blockIdx.x * 256 + threadIdx.x;
  if (i < n4) {
    float4 v = *(const float4*)&src[(size_t)i * 4];
    unsigned o[4];
#pragma unroll
    for (int j = 0; j < 4; ++j) {
      unsigned x = __float_as_uint(((const float*)&v)[j]);
      unsigned rr = x + 0x7fff + ((x >> 16) & 1);
      o[j] = rr >> 16;
    }
    uint2 pk;
    pk.x = o[0] | (o[1] << 16);
    pk.y = o[2] | (o[3] << 16);
    *(uint2*)&dst[(size_t)i * 4] = pk;
  }
}

// ---------------- generic 128x128 fp32 GEMM, 8x8 micro (single-buffered) ----------------
// C[M x N] = A[M x K] * (BT ? B[N x K]^T : B[K x N]); DIST epilogue: 2*acc - xxA[r] - xxB[c]
// k-major swizzled LDS: phys(row) = row + (row>>5)*4, line stride 144 floats.
template <bool BT, bool DIST>
__global__ __launch_bounds__(256) void gemm128(const float* __restrict__ A, int lda,
                                               const float* __restrict__ B, int ldb,
                                               float* __restrict__ C, int ldc, int K,
                                               const float* __restrict__ xxA,
                                               const float* __restrict__ xxB) {
  __shared__ __align__(16) float sA[GTK][144];
  __shared__ __align__(16) float sB[GTK][144];
  int t = threadIdx.x;
  int tx = t & 15, ty = t >> 4;
  int row0 = blockIdx.y * 128, col0 = blockIdx.x * 128;
  float acc[8][8] = {};

  for (int k0 = 0; k0 < K; k0 += GTK) {
    bool fast = (k0 + GTK <= K);
    if (fast) {
#pragma unroll
      for (int it = 0; it < 2; ++it) {
        int i = t + it * 256;
        int r = i >> 2, q = i & 3;
        const float4 av = *(const float4*)&A[(size_t)(row0 + r) * lda + k0 + q * 4];
        int pr = r + ((r >> 5) << 2);
        sA[q * 4 + 0][pr] = av.x;
        sA[q * 4 + 1][pr] = av.y;
        sA[q * 4 + 2][pr] = av.z;
        sA[q * 4 + 3][pr] = av.w;
      }
    } else {
#pragma unroll
      for (int it = 0; it < 2; ++it) {
        int i = t + it * 256;
        int r = i >> 2, q = i & 3;
        int pr = r + ((r >> 5) << 2);
#pragma unroll
        for (int j = 0; j < 4; ++j) {
          int k = q * 4 + j;
          sA[k][pr] = (k0 + k < K) ? A[(size_t)(row0 + r) * lda + k0 + k] : 0.f;
        }
      }
    }
    if (BT) {
      if (fast) {
#pragma unroll
        for (int it = 0; it < 2; ++it) {
          int i = t + it * 256;
          int r = i >> 2, q = i & 3;
          const float4 bv = *(const float4*)&B[(size_t)(col0 + r) * ldb + k0 + q * 4];
          int pr = r + ((r >> 5) << 2);
          sB[q * 4 + 0][pr] = bv.x;
          sB[q * 4 + 1][pr] = bv.y;
          sB[q * 4 + 2][pr] = bv.z;
          sB[q * 4 + 3][pr] = bv.w;
        }
      } else {
#pragma unroll
        for (int it = 0; it < 2; ++it) {
          int i = t + it * 256;
          int r = i >> 2, q = i & 3;
          int pr = r + ((r >> 5) << 2);
#pragma unroll
          for (int j = 0; j < 4; ++j) {
            int k = q * 4 + j;
            sB[k][pr] = (k0 + k < K) ? B[(size_t)(col0 + r) * ldb + k0 + k] : 0.f;
          }
        }
      }
    } else {
#pragma unroll
      for (int it = 0; it < 2; ++it) {
        int i = t + it * 256;
        int k = i >> 5, nq = (i & 31) * 4;
        int pc = nq + ((nq >> 5) << 2);
        float4 bv = make_float4(0.f, 0.f, 0.f, 0.f);
        if (k0 + k < K) bv = *(const float4*)&B[(size_t)(k0 + k) * ldb + col0 + nq];
        *(float4*)&sB[k][pc] = bv;
      }
    }
    __syncthreads();
    int prA = ty * 8 + ((ty >> 2) << 2);
    int prB = tx * 8 + ((tx >> 2) << 2);
#pragma unroll
    for (int kk = 0; kk < GTK; ++kk) {
      float a[8], b[8];
      *(float4*)&a[0] = *(const float4*)&sA[kk][prA];
      *(float4*)&a[4] = *(const float4*)&sA[kk][prA + 4];
      *(float4*)&b[0] = *(const float4*)&sB[kk][prB];
      *(float4*)&b[4] = *(const float4*)&sB[kk][prB + 4];
#pragma unroll
      for (int i = 0; i < 8; ++i)
#pragma unroll
        for (int j = 0; j < 8; ++j) acc[i][j] += a[i] * b[j];
    }
    __syncthreads();
  }

#pragma unroll
  for (int i = 0; i < 8; ++i) {
    int gr = row0 + ty * 8 + i;
    float xa = DIST ? xxA[gr] : 0.f;
#pragma unroll
    for (int jq = 0; jq < 2; ++jq) {
      float4 o;
#pragma unroll
      for (int j = 0; j < 4; ++j) {
        int gc = col0 + tx * 8 + jq * 4 + j;
        float v = acc[i][jq * 4 + j];
        ((float*)&o)[j] = DIST ? (2.f * v - xa - xxB[gc]) : v;
      }
      *(float4*)&C[(size_t)gr * ldc + col0 + tx * 8 + jq * 4] = o;
    }
  }
}

// ---------------- symmetric distance GEMM: only lower-triangle tiles, mirrored write ------
// dist (NPTS x NPTS) = 2*X.X^T - xx - xx^T for one batch; K multiple of 16.
// grid.x = 528 linearized (bi,bj<=bi) tile pairs; off-diag tiles written twice
// (direct + LDS-transposed). Values bit-identical to the full gemm128 path.
__global__ __launch_bounds__(256) void gemm_dist_sym_kernel(const float* __restrict__ X, int lda,
                                                            const float* __restrict__ xx,
                                                            float* __restrict__ dist, int K) {
  __shared__ __align__(16) float lds[2 * GTK * 144];
  float(*sA)[144] = (float(*)[144])lds;
  float(*sB)[144] = (float(*)[144])(lds + GTK * 144);
  int t = threadIdx.x;
  int tx = t & 15, ty = t >> 4;
  int l = blockIdx.x;
  int bi = (int)((sqrtf(8.f * (float)l + 1.f) - 1.f) * 0.5f);
  while ((bi + 1) * (bi + 2) / 2 <= l) ++bi;
  while (bi * (bi + 1) / 2 > l) --bi;
  int bj = l - bi * (bi + 1) / 2;
  int row0 = bi * 128, col0 = bj * 128;
  float acc[8][8] = {};

  for (int k0 = 0; k0 < K; k0 += GTK) {
#pragma unroll
    for (int it = 0; it < 2; ++it) {
      int i = t + it * 256;
      int r = i >> 2, q = i & 3;
      const float4 av = *(const float4*)&X[(size_t)(row0 + r) * lda + k0 + q * 4];
      const float4 bv = *(const float4*)&X[(size_t)(col0 + r) * lda + k0 + q * 4];
      int pr = r + ((r >> 5) << 2);
      sA[q * 4 + 0][pr] = av.x;
      sA[q * 4 + 1][pr] = av.y;
      sA[q * 4 + 2][pr] = av.z;
      sA[q * 4 + 3][pr] = av.w;
      sB[q * 4 + 0][pr] = bv.x;
      sB[q * 4 + 1][pr] = bv.y;
      sB[q * 4 + 2][pr] = bv.z;
      sB[q * 4 + 3][pr] = bv.w;
    }
    __syncthreads();
    int prA = ty * 8 + ((ty >> 2) << 2);
    int prB = tx * 8 + ((tx >> 2) << 2);
#pragma unroll
    for (int kk = 0; kk < GTK; ++kk) {
      float a[8], b[8];
      *(float4*)&a[0] = *(const float4*)&sA[kk][prA];
      *(float4*)&a[4] = *(const float4*)&sA[kk][prA + 4];
      *(float4*)&b[0] = *(const float4*)&sB[kk][prB];
      *(float4*)&b[4] = *(const float4*)&sB[kk][prB + 4];
#pragma unroll
      for (int i = 0; i < 8; ++i)
#pragma unroll
        for (int j = 0; j < 8; ++j) acc[i][j] += a[i] * b[j];
    }
    __syncthreads();
  }

  // DIST transform in place, then direct (coalesced) write of tile (row0, col0)
  {
    float xa[8], xb_[8];
#pragma unroll
    for (int i = 0; i < 8; ++i) xa[i] = xx[row0 + ty * 8 + i];
#pragma unroll
    for (int j = 0; j < 8; ++j) xb_[j] = xx[col0 + tx * 8 + j];
#pragma unroll
    for (int i = 0; i < 8; ++i)
#pragma unroll
      for (int j = 0; j < 8; ++j) acc[i][j] = 2.f * acc[i][j] - xa[i] - xb_[j];
#pragma unroll
    for (int i = 0; i < 8; ++i) {
      int gr = row0 + ty * 8 + i;
#pragma unroll
      for (int jq = 0; jq < 2; ++jq) {
        float4 o;
#pragma unroll
        for (int j = 0; j < 4; ++j) ((float*)&o)[j] = acc[i][jq * 4 + j];
        *(float4*)&dist[(size_t)gr * NPTS + col0 + tx * 8 + jq * 4] = o;
      }
    }
  }

  // mirrored tile (col0, row0) via LDS transpose, 4 chunks of 32 columns
  if (bi != bj) {
    float(*trans)[132] = (float(*)[132])lds;  // 32 x 132 floats = 16.5 KB <= 18 KB
    for (int cc = 0; cc < 4; ++cc) {
      __syncthreads();
      if ((tx >> 2) == cc) {
        int lc = (tx & 3) * 8;
#pragma unroll
        for (int j = 0; j < 8; ++j)
#pragma unroll
          for (int i = 0; i < 8; ++i) trans[lc + j][ty * 8 + i] = acc[i][j];
      }
      __syncthreads();
      int tr = t >> 3, seg = t & 7;
      size_t base = (size_t)(col0 + cc * 32 + tr) * NPTS + row0 + seg * 16;
#pragma unroll
      for (int qq = 0; qq < 4; ++qq)
        *(float4*)&dist[base + qq * 4] = *(const float4*)&trans[tr][seg * 16 + qq * 4];
    }
  }
}

// ---------------- bf16 MFMA FC: C[8192x1024] = A[8192x512] * B[1024x512]^T ----------------
// A,B bf16 row-major; fp32 accumulate. Tile 128x128, 4 waves x (64x64), 16x16x32 MFMA.
__global__ __launch_bounds__(256) void fc_mfma_kernel(const u16* __restrict__ A,
                                                      const u16* __restrict__ B,
                                                      float* __restrict__ C) {
  __shared__ u16 sA[128][56];
  __shared__ u16 sB[128][56];
  int t = threadIdx.x;
  int lane = t & 63, wave = t >> 6;
  int row0 = blockIdx.y * 128, col0 = blockIdx.x * 128;
  int wr = (wave >> 1) * 64, wc = (wave & 1) * 64;
  int m = lane & 15, q = lane >> 4;
  f32x4 acc[4][4];
#pragma unroll
  for (int i = 0; i < 4; ++i)
#pragma unroll
    for (int j = 0; j < 4; ++j) acc[i][j] = (f32x4){0.f, 0.f, 0.f, 0.f};
  for (int k0 = 0; k0 < 512; k0 += 32) {
#pragma unroll
    for (int it = 0; it < 2; ++it) {
      int i = t + it * 256;
      int r = i >> 2, ch = (i & 3) * 8;
      *(uint4*)&sA[r][ch] = *(const uint4*)&A[(size_t)(row0 + r) * 512 + k0 + ch];
      *(uint4*)&sB[r][ch] = *(const uint4*)&B[(size_t)(col0 + r) * 512 + k0 + ch];
    }
    __syncthreads();
    bf16x8 af[4], bf[4];
#pragma unroll
    for (int i = 0; i < 4; ++i) af[i] = *(const bf16x8*)&sA[wr + i * 16 + m][q * 8];
#pragma unroll
    for (int j = 0; j < 4; ++j) bf[j] = *(const bf16x8*)&sB[wc + j * 16 + m][q * 8];
#pragma unroll
    for (int i = 0; i < 4; ++i)
#pragma unroll
      for (int j = 0; j < 4; ++j)
        acc[i][j] = __builtin_amdgcn_mfma_f32_16x16x32_bf16(af[i], bf[j], acc[i][j], 0, 0, 0);
    __syncthreads();
  }
#pragma unroll
  for (int i = 0; i < 4; ++i)
#pragma unroll
    for (int j = 0; j < 4; ++j)
#pragma unroll
      for (int reg = 0; reg < 4; ++reg)
        C[(size_t)(row0 + wr + i * 16 + q * 4 + reg) * 1024 + col0 + wc + j * 16 + m] =
            acc[i][j][reg];
}

// ---------------- shared top-k selection helpers ----------------
__device__ inline bool comp_less(double v, int i, double ov, int oi) {
  // ascending-by-value; ties: larger index sorts "less" -> descending read gives lower idx first
  return (v < ov) || (v == ov && i > oi);
}

// ---------------- fast top-k: threshold filter + fp64 rescore + bitonic sort ----------------
__global__ __launch_bounds__(256) void topk_fast_kernel(const float* __restrict__ dist,
                                                        const float* __restrict__ Xb, int lda,
                                                        int C, int* __restrict__ idxout, int n0,
                                                        int rows) {
  __shared__ int scand[4][MAXCAND];
  int wave = threadIdx.x >> 6, lane = threadIdx.x & 63;
  int row = blockIdx.x * 4 + wave;
  if (row >= rows) return;
  const float* d = dist + (size_t)row * NPTS;
  float v[16][4];
  float lmax = -__builtin_inff();
#pragma unroll
  for (int s = 0; s < 16; ++s) {
    *(float4*)v[s] = *(const float4*)&d[s * 256 + lane * 4];
#pragma unroll
    for (int c = 0; c < 4; ++c) lmax = fmaxf(lmax, v[s][c]);
  }

  float sv = lmax;
  for (int k = 2; k <= 64; k <<= 1) {
    for (int j = k >> 1; j > 0; j >>= 1) {
      float ov = __shfl_xor(sv, j);
      bool up = ((lane & k) == 0);
      bool lower = ((lane & j) == 0);
      bool mineLess = sv < ov;
      bool keepMine = (up == lower) ? mineLess : !mineLess;
      sv = keepMine ? sv : ov;
    }
  }
  float T = __shfl(sv, 44);

  int myCnt = 0;
#pragma unroll
  for (int s = 0; s < 16; ++s)
#pragma unroll
    for (int c = 0; c < 4; ++c) myCnt += (v[s][c] >= T) ? 1 : 0;
  int ofs = myCnt;
  for (int dlt = 1; dlt < 64; dlt <<= 1) {
    int o = __shfl_up(ofs, dlt);
    if (lane >= dlt) ofs += o;
  }
  int total = __shfl(ofs, 63);
  ofs -= myCnt;
  int w = ofs;
#pragma unroll
  for (int s = 0; s < 16; ++s)
#pragma unroll
    for (int c = 0; c < 4; ++c) {
      if (v[s][c] >= T) {
        if (w < MAXCAND) scand[wave][w] = s * 256 + lane * 4 + c;
        ++w;
      }
    }
  int cnt = imin(total, MAXCAND);
  int gn = n0 + row;
  const float* crow = Xb + (size_t)gn * lda;
  int nch = (cnt + 63) >> 6;

  double runV = -__builtin_inf();
  int runI = 0x7fffffff;
  for (int ch = 0; ch < nch; ++ch) {
    int slot = ch * 64 + lane;
    int m = (slot < cnt) ? scand[wave][slot] : -1;
    double val = -__builtin_inf();
    int vi = 0x7fffffff;
    if (m >= 0) {
      const float* mrow = Xb + (size_t)m * lda;
      double dd = 0.0;
      for (int c = 0; c < C; c += 4) {
        float4 a = *(const float4*)&crow[c];
        float4 b = *(const float4*)&mrow[c];
#pragma unroll
        for (int qq = 0; qq < 4; ++qq) {
          double df = (double)((const float*)&a)[qq] - (double)((const float*)&b)[qq];
          dd = fma(df, df, dd);
        }
      }
      val = -dd;
      vi = m;
    }
    for (int k = 2; k <= 64; k <<= 1) {
      for (int j = k >> 1; j > 0; j >>= 1) {
        double ov = __shfl_xor(val, j);
        int oi = __shfl_xor(vi, j);
        bool up = ((lane & k) == 0);
        bool lower = ((lane & j) == 0);
        bool mineLess = comp_less(val, vi, ov, oi);
        bool keepMine = (up == lower) ? mineLess : !mineLess;
        if (!keepMine) { val = ov; vi = oi; }
      }
    }
    if (ch == 0) {
      runV = val;
      runI = vi;
    } else {
      double rv = __shfl(val, 63 - lane);
      int ri = __shfl(vi, 63 - lane);
      if (comp_less(runV, runI, rv, ri)) { runV = rv; runI = ri; }
      for (int j = 32; j > 0; j >>= 1) {
        double ov = __shfl_xor(runV, j);
        int oi = __shfl_xor(runI, j);
        bool lower = ((lane & j) == 0);
        bool mineLess = comp_less(runV, runI, ov, oi);
        bool keepMine = lower ? mineLess : !mineLess;
        if (!keepMine) { runV = ov; runI = oi; }
      }
    }
  }
  if (lane >= 44) idxout[(size_t)gn * KNN + (63 - lane)] = runI;
}

// ---------------- fused layer-1 kNN (C=3): whole point set in LDS ----------------
__global__ __launch_bounds__(256) void dist3_topk_kernel(const float* __restrict__ Xb,
                                                         int* __restrict__ idxout) {
  __shared__ float xs[NPTS], ys[NPTS], zs[NPTS];
  __shared__ int scand[4][MAXCAND];
  int t = threadIdx.x;
  const float* Xbb = Xb + (size_t)blockIdx.y * NPTS * 3;
  for (int i = t; i < NPTS * 3; i += 256) {
    int n = i / 3, c = i - n * 3;
    float v = Xbb[i];
    if (c == 0) xs[n] = v;
    else if (c == 1) ys[n] = v;
    else zs[n] = v;
  }
  __syncthreads();
  int wave = t >> 6, lane = t & 63;
  int row = blockIdx.x * 4 + wave;
  float cx = xs[row], cy = ys[row], cz = zs[row];
  float v[16][4];
  float lmax = -__builtin_inff();
#pragma unroll
  for (int s = 0; s < 16; ++s)
#pragma unroll
    for (int c = 0; c < 4; ++c) {
      int m = s * 256 + c * 64 + lane;
      float dx = cx - xs[m], dy = cy - ys[m], dz = cz - zs[m];
      float dv = -(dx * dx + dy * dy + dz * dz);
      v[s][c] = dv;
      lmax = fmaxf(lmax, dv);
    }

  float sv = lmax;
  for (int k = 2; k <= 64; k <<= 1) {
    for (int j = k >> 1; j > 0; j >>= 1) {
      float ov = __shfl_xor(sv, j);
      bool up = ((lane & k) == 0);
      bool lower = ((lane & j) == 0);
      bool mineLess = sv < ov;
      bool keepMine = (up == lower) ? mineLess : !mineLess;
      sv = keepMine ? sv : ov;
    }
  }
  float T = __shfl(sv, 44);

  int myCnt = 0;
#pragma unroll
  for (int s = 0; s < 16; ++s)
#pragma unroll
    for (int c = 0; c < 4; ++c) myCnt += (v[s][c] >= T) ? 1 : 0;
  int ofs = myCnt;
  for (int dlt = 1; dlt < 64; dlt <<= 1) {
    int o = __shfl_up(ofs, dlt);
    if (lane >= dlt) ofs += o;
  }
  int total = __shfl(ofs, 63);
  ofs -= myCnt;
  int w = ofs;
#pragma unroll
  for (int s = 0; s < 16; ++s)
#pragma unroll
    for (int c = 0; c < 4; ++c) {
      if (v[s][c] >= T) {
        if (w < MAXCAND) scand[wave][w] = s * 256 + c * 64 + lane;
        ++w;
      }
    }
  int cnt = imin(total, MAXCAND);
  int nch = (cnt + 63) >> 6;

  double runV = -__builtin_inf();
  int runI = 0x7fffffff;
  for (int ch = 0; ch < nch; ++ch) {
    int slot = ch * 64 + lane;
    int m = (slot < cnt) ? scand[wave][slot] : -1;
    double val = -__builtin_inf();
    int vi = 0x7fffffff;
    if (m >= 0) {
      double dx = (double)cx - (double)xs[m];
      double dy = (double)cy - (double)ys[m];
      double dz = (double)cz - (double)zs[m];
      val = -(dx * dx + dy * dy + dz * dz);
      vi = m;
    }
    for (int k = 2; k <= 64; k <<= 1) {
      for (int j = k >> 1; j > 0; j >>= 1) {
        double ov = __shfl_xor(val, j);
        int oi = __shfl_xor(vi, j);
        bool up = ((lane & k) == 0);
        bool lower = ((lane & j) == 0);
        bool mineLess = comp_less(val, vi, ov, oi);
        bool keepMine = (up == lower) ? mineLess : !mineLess;
        if (!keepMine) { val = ov; vi = oi; }
      }
    }
    if (ch == 0) {
      runV = val;
      runI = vi;
    } else {
      double rv = __shfl(val, 63 - lane);
      int ri = __shfl(vi, 63 - lane);
      if (comp_less(runV, runI, rv, ri)) { runV = rv; runI = ri; }
      for (int j = 32; j > 0; j >>= 1) {
        double ov = __shfl_xor(runV, j);
        int oi = __shfl_xor(runI, j);
        bool lower = ((lane & j) == 0);
        bool mineLess = comp_less(runV, runI, ov, oi);
        bool keepMine = lower ? mineLess : !mineLess;
        if (!keepMine) { runV = ov; runI = oi; }
      }
    }
  }
  if (lane >= 44)
    idxout[((size_t)blockIdx.y * NPTS + row) * KNN + (63 - lane)] = runI;
}

// ---------------- gather-max + per-block fp64 BN partial stats ----------------
template <int NO>
__global__ __launch_bounds__(256) void gathermax_kernel(const float* __restrict__ PQ,
                                                        const int* __restrict__ idx,
                                                        float* __restrict__ hmax, int O,
                                                        double* __restrict__ pbuf) {
  __shared__ double sh1[4][256];
  __shared__ double sh2[4][256];
  int t = threadIdx.x;
  int wave = t >> 6, lane = t & 63;
  int pt = blockIdx.x * 4 + wave;
  int b = pt >> 12;
  int O2 = 2 * O;
  int iv = idx[(size_t)pt * KNN + (lane % KNN)];
  const float* Qp = PQ + (size_t)pt * O2 + O + lane * NO;
  float q[NO], mx[NO];
  double s1[NO], s2[NO];
#pragma unroll
  for (int c = 0; c < NO; ++c) {
    q[c] = Qp[c];
    mx[c] = -__builtin_inff();
    s1[c] = 0.0;
    s2[c] = 0.0;
  }
#pragma unroll
  for (int k = 0; k < KNN; ++k) {
    int m = __shfl(iv, k);
    const float* Pp = PQ + ((size_t)(b << 12) + m) * O2 + lane * NO;
    float p[NO];
#pragma unroll
    for (int c = 0; c < NO; ++c) p[c] = Pp[c];
#pragma unroll
    for (int c = 0; c < NO; ++c) {
      float h = p[c] + q[c];
      mx[c] = fmaxf(mx[c], h);
      double hd = (double)h;
      s1[c] += hd;
      s2[c] += hd * hd;
    }
  }
  float* Hp = hmax + (size_t)pt * O + lane * NO;
#pragma unroll
  for (int c = 0; c < NO; ++c) {
    Hp[c] = mx[c];
    sh1[wave][lane * NO + c] = s1[c];
    sh2[wave][lane * NO + c] = s2[c];
  }
  __syncthreads();
  if (t < O) {
    double a = 0.0, bb = 0.0;
#pragma unroll
    for (int w = 0; w < 4; ++w) {
      a += sh1[w][t];
      bb += sh2[w][t];
    }
    pbuf[(size_t)blockIdx.x * O2 + t] = a;
    pbuf[(size_t)blockIdx.x * O2 + O + t] = bb;
  }
}

// ---------------- deterministic parallel fp64 BN reduce + finalize ----------------
__global__ __launch_bounds__(256) void bn_reduce_finalize(const double* __restrict__ pbuf,
                                                          int nblk, int O,
                                                          const float* __restrict__ g,
                                                          const float* __restrict__ bb,
                                                          double invcount,
                                                          float* __restrict__ s_out,
                                                          float* __restrict__ t_out) {
  __shared__ double sh1[256];
  __shared__ double sh2[256];
  int o = blockIdx.x;
  int t = threadIdx.x;
  double s1 = 0.0, s2 = 0.0;
  for (int blk = t; blk < nblk; blk += 256) {
    s1 += pbuf[(size_t)blk * 2 * O + o];
    s2 += pbuf[(size_t)blk * 2 * O + O + o];
  }
  sh1[t] = s1;
  sh2[t] = s2;
  __syncthreads();
  for (int s = 128; s > 0; s >>= 1) {
    if (t < s) {
      sh1[t] += sh1[t + s];
      sh2[t] += sh2[t + s];
    }
    __syncthreads();
  }
  if (t == 0) {
    double mean = sh1[0] * invcount;
    double var = sh2[0] * invcount - mean * mean;
    double s = (double)g[o] / sqrt(var + BNEPS);
    s_out[o] = (float)s;
    t_out[o] = (float)((double)bb[o] - mean * s);
  }
}

// y = leaky(hmax*s+t) into feat column slice
__global__ void apply_kernel(const float* __restrict__ hmax, const float* __restrict__ s,
                             const float* __restrict__ tt, float* __restrict__ feat,
                             int colOff, int logO, int total) {
  int i = blockIdx.x * 256 + threadIdx.x;
  if (i >= total) return;
  int O = 1 << logO;
  int o = i & (O - 1);
  int pp = i >> logO;
  float v = hmax[i] * s[o] + tt[o];
  feat[(size_t)pp * 512 + colOff + o] = v > 0.f ? v : SLOPE * v;
}

// column partial stats over H (rows x 1024): pbuf[rb][2048] = [sum | sq] (fp64)
__global__ void colstats_kernel(const float* __restrict__ H, double* __restrict__ pbuf) {
  int o = blockIdx.x * 256 + threadIdx.x;
  int rb = blockIdx.y;
  int r0 = rb * 128;
  double s1 = 0.0, s2 = 0.0;
  for (int r = 0; r < 128; ++r) {
    double v = (double)H[(size_t)(r0 + r) * 1024 + o];
    s1 += v;
    s2 += v * v;
  }
  pbuf[(size_t)rb * 2048 + o] = s1;
  pbuf[(size_t)rb * 2048 + 1024 + o] = s2;
}

// out[b][o][n] = leaky(h5[b][n][o]*s+t)
__global__ void out_kernel(const float* __restrict__ h5, const float* __restrict__ s,
                           const float* __restrict__ tt, float* __restrict__ out) {
  __shared__ float tile[32][33];
  int b = blockIdx.z;
  int n0 = blockIdx.x * 32, o0 = blockIdx.y * 32;
  int t = threadIdx.x;
  for (int e = t; e < 1024; e += 256) {
    int rn = e >> 5, co = e & 31;
    int o = o0 + co;
    float v = h5[((size_t)b * NPTS + n0 + rn) * 1024 + o] * s[o] + tt[o];
    tile[rn][co] = v > 0.f ? v : SLOPE * v;
  }
  __syncthreads();
  for (int e = t; e < 1024; e += 256) {
    int ro = e >> 5, cn = e & 31;
    out[((size_t)b * 1024 + o0 + ro) * NPTS + n0 + cn] = tile[cn][ro];
  }
}

// ---------------- host ----------------
extern "C" void kernel_launch(void* const* d_in, const int* in_sizes, int n_in,
                              void* d_out, int out_size, void* d_ws, size_t ws_size,
                              hipStream_t stream) {
  const float* x = (const float*)d_in[0];
  const float* Wm[5] = {(const float*)d_in[1], (const float*)d_in[4], (const float*)d_in[7],
                        (const float*)d_in[10], (const float*)d_in[13]};
  const float* gv[5] = {(const float*)d_in[2], (const float*)d_in[5], (const float*)d_in[8],
                        (const float*)d_in[11], (const float*)d_in[14]};
  const float* bvv[5] = {(const float*)d_in[3], (const float*)d_in[6], (const float*)d_in[9],
                         (const float*)d_in[12], (const float*)d_in[15]};
  float* out = (float*)d_out;

  char* wsb = (char*)d_ws;
  size_t off = 0;
  auto alloc = [&](size_t bytes) -> char* {
    off = (off + 255) & ~(size_t)255;
    char* p = wsb + off;
    off += bytes;
    return p;
  };
  float* xb = (float*)alloc((size_t)BATCH * NPTS * 3 * 4);
  float* xxb = (float*)alloc((size_t)BATCH * NPTS * 4);
  int* idxb = (int*)alloc((size_t)BATCH * NPTS * KNN * 4);
  float* feat = (float*)alloc((size_t)BATCH * NPTS * 512 * 4);
  float* hmax = (float*)alloc((size_t)BATCH * NPTS * 256 * 4);
  float* h5 = (float*)alloc((size_t)BATCH * NPTS * 1024 * 4);
  float* PQ = h5;  // alias: PQ used per-layer, h5 only needed after
  float* U1 = (float*)alloc(3 * 128 * 4);
  float* U2 = (float*)alloc(64 * 128 * 4);
  float* U3 = (float*)alloc(64 * 256 * 4);
  float* U4 = (float*)alloc(128 * 512 * 4);
  u16* featbf = (u16*)alloc((size_t)BATCH * NPTS * 512 * 2);
  u16* w5bf = (u16*)alloc((size_t)1024 * 512 * 2);
  double* pbuf = (double*)alloc((size_t)2048 * 512 * 8);
  float* stv = (float*)alloc(3072 * 4);
  off = (off + 255) & ~(size_t)255;
  size_t avail = (ws_size > off) ? (ws_size - off) : 0;
  size_t rmax = avail / ((size_t)NPTS * 4);
  int R;
  if (rmax >= NPTS) R = NPTS;
  else {
    R = (int)(rmax & ~(size_t)127);
    if (R < 128) R = 128;
  }
  float* distbuf = (float*)(wsb + off);

  float* sv[5] = {stv + 0, stv + 128, stv + 256, stv + 512, stv + 1024};
  float* tv[5] = {stv + 64, stv + 192, stv + 384, stv + 768, stv + 2048};
  float* Us[4] = {U1, U2, U3, U4};
  const int Cs[4] = {3, 64, 64, 128};
  const int Osz[4] = {64, 64, 128, 256};

  xtrans_kernel<<<(BATCH * 3 * NPTS + 255) / 256, 256, 0, stream>>>(x, xb);
  for (int l = 0; l < 4; ++l)
    uprep_kernel<<<(Cs[l] * Osz[l] + 255) / 256, 256, 0, stream>>>(Wm[l], Us[l], Osz[l], Cs[l]);
  tobf16_kernel<<<(1024 * 512 / 4 + 255) / 256, 256, 0, stream>>>(Wm[4], w5bf, 1024 * 512 / 4);

  auto knn = [&](const float* Xbase, int lda, int C) {
    xx_kernel<<<(BATCH * NPTS + 255) / 256, 256, 0, stream>>>(Xbase, lda, C, xxb);
    for (int b = 0; b < BATCH; ++b) {
      const float* Xb = Xbase + (size_t)b * NPTS * lda;
      if (R >= NPTS) {
        // symmetric path: 528 lower-triangle tiles, mirrored write (bit-identical values)
        int ntile = (NPTS / 128) * (NPTS / 128 + 1) / 2;
        gemm_dist_sym_kernel<<<ntile, 256, 0, stream>>>(Xb, lda, xxb + (size_t)b * NPTS, distbuf,
                                                        C);
        topk_fast_kernel<<<NPTS / 4, 256, 0, stream>>>(distbuf, Xb, lda, C,
                                                       idxb + (size_t)b * NPTS * KNN, 0, NPTS);
      } else {
        for (int n0 = 0; n0 < NPTS; n0 += R) {
          int rows = imin(R, NPTS - n0);
          gemm128<true, true><<<dim3(NPTS / 128, rows / 128), 256, 0, stream>>>(
              Xb + (size_t)n0 * lda, lda, Xb, lda, distbuf, NPTS, C, xxb + (size_t)b * NPTS + n0,
              xxb + (size_t)b * NPTS);
          topk_fast_kernel<<<rows / 4, 256, 0, stream>>>(distbuf, Xb, lda, C,
                                                         idxb + (size_t)b * NPTS * KNN, n0, rows);
        }
      }
    }
  };

  auto edge = [&](int li, const float* Xbase, int lda, int C, int O, int colOff) {
    if (li == 0) {
      dist3_topk_kernel<<<dim3(NPTS / 4, BATCH), 256, 0, stream>>>(Xbase, idxb);
    } else {
      knn(Xbase, lda, C);
    }
    int O2 = 2 * O;
    gemm128<false, false><<<dim3(O2 / 128, BATCH * NPTS / 128), 256, 0, stream>>>(
        Xbase, lda, Us[li], O2, PQ, O2, C, nullptr, nullptr);
    int nblk = BATCH * NPTS / 4;
    if (O == 64)
      gathermax_kernel<1><<<nblk, 256, 0, stream>>>(PQ, idxb, hmax, O, pbuf);
    else if (O == 128)
      gathermax_kernel<2><<<nblk, 256, 0, stream>>>(PQ, idxb, hmax, O, pbuf);
    else
      gathermax_kernel<4><<<nblk, 256, 0, stream>>>(PQ, idxb, hmax, O, pbuf);
    bn_reduce_finalize<<<O, 256, 0, stream>>>(pbuf, nblk, O, gv[li], bvv[li],
                                              1.0 / ((double)BATCH * NPTS * KNN), sv[li], tv[li]);
    int logO = (O == 64) ? 6 : (O == 128) ? 7 : 8;
    int total = BATCH * NPTS * O;
    apply_kernel<<<(total + 255) / 256, 256, 0, stream>>>(hmax, sv[li], tv[li], feat, colOff, logO,
                                                          total);
  };

  edge(0, xb, 3, 3, 64, 0);
  edge(1, feat, 512, 64, 64, 64);
  edge(2, feat + 64, 512, 64, 128, 128);
  edge(3, feat + 128, 512, 128, 256, 256);

  tobf16_kernel<<<((int)((size_t)BATCH * NPTS * 512 / 4) + 255) / 256, 256, 0, stream>>>(
      feat, featbf, (int)((size_t)BATCH * NPTS * 512 / 4));
  fc_mfma_kernel<<<dim3(1024 / 128, BATCH * NPTS / 128), 256, 0, stream>>>(featbf, w5bf, h5);
  colstats_kernel<<<dim3(4, 64), 256, 0, stream>>>(h5, pbuf);
  bn_reduce_finalize<<<1024, 256, 0, stream>>>(pbuf, 64, 1024, gv[4], bvv[4],
                                               1.0 / ((double)BATCH * NPTS), sv[4], tv[4]);
  out_kernel<<<dim3(NPTS / 32, 1024 / 32, BATCH), 256, 0, stream>>>(h5, sv[4], tv[4], out);
}

// Round 12
// 715.095 us; speedup vs baseline: 1.5266x; 1.0824x over previous
//
#include <hip/hip_runtime.h>
#include <cmath>

#define KNN 20
#define NPTS 4096
#define BATCH 2
#define SLOPE 0.2f
#define BNEPS 1e-5
#define GTK 16
#define MAXCAND 256

typedef unsigned short u16;
typedef __attribute__((ext_vector_type(8))) short bf16x8;
typedef __attribute__((ext_vector_type(4))) float f32x4;

static __device__ __host__ inline int imin(int a, int b) { return a < b ? a : b; }

// ---------------- utility kernels ----------------
// x (B,3,N) -> xb (B,N,3)
__global__ void xtrans_kernel(const float* __restrict__ x, float* __restrict__ xb) {
  int i = blockIdx.x * 256 + threadIdx.x;
  if (i < BATCH * 3 * NPTS) {
    int b = i / (3 * NPTS);
    int r = i - b * 3 * NPTS;
    int c = r / NPTS;
    int n = r - c * NPTS;
    xb[((size_t)b * NPTS + n) * 3 + c] = x[i];
  }
}

// W (O, 2C) -> U (C, 2O): U[j][o]=W[o][j]; U[j][O+o]=W[o][C+j]-W[o][j]
__global__ void uprep_kernel(const float* __restrict__ W, float* __restrict__ U, int O, int C) {
  int i = blockIdx.x * 256 + threadIdx.x;
  if (i < C * O) {
    int j = i / O, o = i - j * O;
    float w1 = W[(size_t)o * 2 * C + j];
    float w2 = W[(size_t)o * 2 * C + C + j];
    U[(size_t)j * 2 * O + o] = w1;
    U[(size_t)j * 2 * O + O + o] = w2 - w1;
  }
}

// squared norms per point (fp64 accumulate, fp32 store — candidate pass only)
__global__ void xx_kernel(const float* __restrict__ X, int stride, int C, float* __restrict__ xx) {
  int i = blockIdx.x * 256 + threadIdx.x;
  if (i < BATCH * NPTS) {
    const float* r = X + (size_t)i * stride;
    double s = 0.0;
    for (int c = 0; c < C; ++c) s += (double)r[c] * (double)r[c];
    xx[i] = (float)s;
  }
}

// fp32 -> bf16 (RNE), 4 elements/thread
__global__ void tobf16_kernel(const float* __restrict__ src, u16* __restrict__ dst, int n4) {
  int i = blockIdx.x * 256 + threadIdx.x;
  if (i < n4) {
    float4 v = *(const float4*)&src[(size_t)i * 4];
    unsigned o[4];
#pragma unroll
    for (int j = 0; j < 4; ++j) {
      unsigned x = __float_as_uint(((const float*)&v)[j]);
      unsigned rr = x + 0x7fff + ((x >> 16) & 1);
      o[j] = rr >> 16;
    }
    uint2 pk;
    pk.x = o[0] | (o[1] << 16);
    pk.y = o[2] | (o[3] << 16);
    *(uint2*)&dst[(size_t)i * 4] = pk;
  }
}

// ---------------- generic 128x128 fp32 GEMM, 8x8 micro (single-buffered) ----------------
// C[M x N] = A[M x K] * (BT ? B[N x K]^T : B[K x N]); DIST epilogue: 2*acc - xxA[r] - xxB[c]
// k-major swizzled LDS: phys(row) = row + (row>>5)*4, line stride 144 floats.
template <bool BT, bool DIST>
__global__ __launch_bounds__(256) void gemm128(const float* __restrict__ A, int lda,
                                               const float* __restrict__ B, int ldb,
                                               float* __restrict__ C, int ldc, int K,
                                               const float* __restrict__ xxA,
                                               const float* __restrict__ xxB) {
  __shared__ __align__(16) float sA[GTK][144];
  __shared__ __align__(16) float sB[GTK][144];
  int t = threadIdx.x;
  int tx = t & 15, ty = t >> 4;
  int row0 = blockIdx.y * 128, col0 = blockIdx.x * 128;
  float acc[8][8] = {};

  for (int k0 = 0; k0 < K; k0 += GTK) {
    bool fast = (k0 + GTK <= K);
    if (fast) {
#pragma unroll
      for (int it = 0; it < 2; ++it) {
        int i = t + it * 256;
        int r = i >> 2, q = i & 3;
        const float4 av = *(const float4*)&A[(size_t)(row0 + r) * lda + k0 + q * 4];
        int pr = r + ((r >> 5) << 2);
        sA[q * 4 + 0][pr] = av.x;
        sA[q * 4 + 1][pr] = av.y;
        sA[q * 4 + 2][pr] = av.z;
        sA[q * 4 + 3][pr] = av.w;
      }
    } else {
#pragma unroll
      for (int it = 0; it < 2; ++it) {
        int i = t + it * 256;
        int r = i >> 2, q = i & 3;
        int pr = r + ((r >> 5) << 2);
#pragma unroll
        for (int j = 0; j < 4; ++j) {
          int k = q * 4 + j;
          sA[k][pr] = (k0 + k < K) ? A[(size_t)(row0 + r) * lda + k0 + k] : 0.f;
        }
      }
    }
    if (BT) {
      if (fast) {
#pragma unroll
        for (int it = 0; it < 2; ++it) {
          int i = t + it * 256;
          int r = i >> 2, q = i & 3;
          const float4 bv = *(const float4*)&B[(size_t)(col0 + r) * ldb + k0 + q * 4];
          int pr = r + ((r >> 5) << 2);
          sB[q * 4 + 0][pr] = bv.x;
          sB[q * 4 + 1][pr] = bv.y;
          sB[q * 4 + 2][pr] = bv.z;
          sB[q * 4 + 3][pr] = bv.w;
        }
      } else {
#pragma unroll
        for (int it = 0; it < 2; ++it) {
          int i = t + it * 256;
          int r = i >> 2, q = i & 3;
          int pr = r + ((r >> 5) << 2);
#pragma unroll
          for (int j = 0; j < 4; ++j) {
            int k = q * 4 + j;
            sB[k][pr] = (k0 + k < K) ? B[(size_t)(col0 + r) * ldb + k0 + k] : 0.f;
          }
        }
      }
    } else {
#pragma unroll
      for (int it = 0; it < 2; ++it) {
        int i = t + it * 256;
        int k = i >> 5, nq = (i & 31) * 4;
        int pc = nq + ((nq >> 5) << 2);
        float4 bv = make_float4(0.f, 0.f, 0.f, 0.f);
        if (k0 + k < K) bv = *(const float4*)&B[(size_t)(k0 + k) * ldb + col0 + nq];
        *(float4*)&sB[k][pc] = bv;
      }
    }
    __syncthreads();
    int prA = ty * 8 + ((ty >> 2) << 2);
    int prB = tx * 8 + ((tx >> 2) << 2);
#pragma unroll
    for (int kk = 0; kk < GTK; ++kk) {
      float a[8], b[8];
      *(float4*)&a[0] = *(const float4*)&sA[kk][prA];
      *(float4*)&a[4] = *(const float4*)&sA[kk][prA + 4];
      *(float4*)&b[0] = *(const float4*)&sB[kk][prB];
      *(float4*)&b[4] = *(const float4*)&sB[kk][prB + 4];
#pragma unroll
      for (int i = 0; i < 8; ++i)
#pragma unroll
        for (int j = 0; j < 8; ++j) acc[i][j] += a[i] * b[j];
    }
    __syncthreads();
  }

#pragma unroll
  for (int i = 0; i < 8; ++i) {
    int gr = row0 + ty * 8 + i;
    float xa = DIST ? xxA[gr] : 0.f;
#pragma unroll
    for (int jq = 0; jq < 2; ++jq) {
      float4 o;
#pragma unroll
      for (int j = 0; j < 4; ++j) {
        int gc = col0 + tx * 8 + jq * 4 + j;
        float v = acc[i][jq * 4 + j];
        ((float*)&o)[j] = DIST ? (2.f * v - xa - xxB[gc]) : v;
      }
      *(float4*)&C[(size_t)gr * ldc + col0 + tx * 8 + jq * 4] = o;
    }
  }
}

// ---------------- symmetric distance GEMM: lower-triangle tiles, mirrored write ------
// grid (ntile, nbatch). dist batch slab stride = dstride elements.
// Values bit-identical to the full gemm128 path.
__global__ __launch_bounds__(256) void gemm_dist_sym_kernel(const float* __restrict__ X, int lda,
                                                            const float* __restrict__ xx,
                                                            float* __restrict__ dist, int K,
                                                            size_t dstride) {
  __shared__ __align__(16) float lds[2 * GTK * 144];
  float(*sA)[144] = (float(*)[144])lds;
  float(*sB)[144] = (float(*)[144])(lds + GTK * 144);
  int t = threadIdx.x;
  int tx = t & 15, ty = t >> 4;
  const float* Xb = X + (size_t)blockIdx.y * NPTS * lda;
  const float* xxv = xx + (size_t)blockIdx.y * NPTS;
  float* db = dist + (size_t)blockIdx.y * dstride;
  int l = blockIdx.x;
  int bi = (int)((sqrtf(8.f * (float)l + 1.f) - 1.f) * 0.5f);
  while ((bi + 1) * (bi + 2) / 2 <= l) ++bi;
  while (bi * (bi + 1) / 2 > l) --bi;
  int bj = l - bi * (bi + 1) / 2;
  int row0 = bi * 128, col0 = bj * 128;
  float acc[8][8] = {};

  for (int k0 = 0; k0 < K; k0 += GTK) {
#pragma unroll
    for (int it = 0; it < 2; ++it) {
      int i = t + it * 256;
      int r = i >> 2, q = i & 3;
      const float4 av = *(const float4*)&Xb[(size_t)(row0 + r) * lda + k0 + q * 4];
      const float4 bv = *(const float4*)&Xb[(size_t)(col0 + r) * lda + k0 + q * 4];
      int pr = r + ((r >> 5) << 2);
      sA[q * 4 + 0][pr] = av.x;
      sA[q * 4 + 1][pr] = av.y;
      sA[q * 4 + 2][pr] = av.z;
      sA[q * 4 + 3][pr] = av.w;
      sB[q * 4 + 0][pr] = bv.x;
      sB[q * 4 + 1][pr] = bv.y;
      sB[q * 4 + 2][pr] = bv.z;
      sB[q * 4 + 3][pr] = bv.w;
    }
    __syncthreads();
    int prA = ty * 8 + ((ty >> 2) << 2);
    int prB = tx * 8 + ((tx >> 2) << 2);
#pragma unroll
    for (int kk = 0; kk < GTK; ++kk) {
      float a[8], b[8];
      *(float4*)&a[0] = *(const float4*)&sA[kk][prA];
      *(float4*)&a[4] = *(const float4*)&sA[kk][prA + 4];
      *(float4*)&b[0] = *(const float4*)&sB[kk][prB];
      *(float4*)&b[4] = *(const float4*)&sB[kk][prB + 4];
#pragma unroll
      for (int i = 0; i < 8; ++i)
#pragma unroll
        for (int j = 0; j < 8; ++j) acc[i][j] += a[i] * b[j];
    }
    __syncthreads();
  }

  // DIST transform in place, then direct (coalesced) write of tile (row0, col0)
  {
    float xa[8], xb_[8];
#pragma unroll
    for (int i = 0; i < 8; ++i) xa[i] = xxv[row0 + ty * 8 + i];
#pragma unroll
    for (int j = 0; j < 8; ++j) xb_[j] = xxv[col0 + tx * 8 + j];
#pragma unroll
    for (int i = 0; i < 8; ++i)
#pragma unroll
      for (int j = 0; j < 8; ++j) acc[i][j] = 2.f * acc[i][j] - xa[i] - xb_[j];
#pragma unroll
    for (int i = 0; i < 8; ++i) {
      int gr = row0 + ty * 8 + i;
#pragma unroll
      for (int jq = 0; jq < 2; ++jq) {
        float4 o;
#pragma unroll
        for (int j = 0; j < 4; ++j) ((float*)&o)[j] = acc[i][jq * 4 + j];
        *(float4*)&db[(size_t)gr * NPTS + col0 + tx * 8 + jq * 4] = o;
      }
    }
  }

  // mirrored tile (col0, row0) via LDS transpose, 4 chunks of 32 columns
  if (bi != bj) {
    float(*trans)[132] = (float(*)[132])lds;  // 32 x 132 floats = 16.5 KB <= 18 KB
    for (int cc = 0; cc < 4; ++cc) {
      __syncthreads();
      if ((tx >> 2) == cc) {
        int lc = (tx & 3) * 8;
#pragma unroll
        for (int j = 0; j < 8; ++j)
#pragma unroll
          for (int i = 0; i < 8; ++i) trans[lc + j][ty * 8 + i] = acc[i][j];
      }
      __syncthreads();
      int tr = t >> 3, seg = t & 7;
      size_t base = (size_t)(col0 + cc * 32 + tr) * NPTS + row0 + seg * 16;
#pragma unroll
      for (int qq = 0; qq < 4; ++qq)
        *(float4*)&db[base + qq * 4] = *(const float4*)&trans[tr][seg * 16 + qq * 4];
    }
  }
}

// ---------------- bf16 MFMA FC: C[8192x1024] = A[8192x512] * B[1024x512]^T ----------------
__global__ __launch_bounds__(256) void fc_mfma_kernel(const u16* __restrict__ A,
                                                      const u16* __restrict__ B,
                                                      float* __restrict__ C) {
  __shared__ u16 sA[128][56];
  __shared__ u16 sB[128][56];
  int t = threadIdx.x;
  int lane = t & 63, wave = t >> 6;
  int row0 = blockIdx.y * 128, col0 = blockIdx.x * 128;
  int wr = (wave >> 1) * 64, wc = (wave & 1) * 64;
  int m = lane & 15, q = lane >> 4;
  f32x4 acc[4][4];
#pragma unroll
  for (int i = 0; i < 4; ++i)
#pragma unroll
    for (int j = 0; j < 4; ++j) acc[i][j] = (f32x4){0.f, 0.f, 0.f, 0.f};
  for (int k0 = 0; k0 < 512; k0 += 32) {
#pragma unroll
    for (int it = 0; it < 2; ++it) {
      int i = t + it * 256;
      int r = i >> 2, ch = (i & 3) * 8;
      *(uint4*)&sA[r][ch] = *(const uint4*)&A[(size_t)(row0 + r) * 512 + k0 + ch];
      *(uint4*)&sB[r][ch] = *(const uint4*)&B[(size_t)(col0 + r) * 512 + k0 + ch];
    }
    __syncthreads();
    bf16x8 af[4], bf[4];
#pragma unroll
    for (int i = 0; i < 4; ++i) af[i] = *(const bf16x8*)&sA[wr + i * 16 + m][q * 8];
#pragma unroll
    for (int j = 0; j < 4; ++j) bf[j] = *(const bf16x8*)&sB[wc + j * 16 + m][q * 8];
#pragma unroll
    for (int i = 0; i < 4; ++i)
#pragma unroll
      for (int j = 0; j < 4; ++j)
        acc[i][j] = __builtin_amdgcn_mfma_f32_16x16x32_bf16(af[i], bf[j], acc[i][j], 0, 0, 0);
    __syncthreads();
  }
#pragma unroll
  for (int i = 0; i < 4; ++i)
#pragma unroll
    for (int j = 0; j < 4; ++j)
#pragma unroll
      for (int reg = 0; reg < 4; ++reg)
        C[(size_t)(row0 + wr + i * 16 + q * 4 + reg) * 1024 + col0 + wc + j * 16 + m] =
            acc[i][j][reg];
}

// ---------------- shared top-k selection helpers ----------------
__device__ inline bool comp_less(double v, int i, double ov, int oi) {
  // ascending-by-value; ties: larger index sorts "less" -> descending read gives lower idx first
  return (v < ov) || (v == ov && i > oi);
}

// ---------------- fast top-k: threshold filter + fp64 rescore + bitonic sort ----------------
// grid (rows/4, nbatch); batch strides in elements.
__global__ __launch_bounds__(256) void topk_fast_kernel(const float* __restrict__ dist,
                                                        size_t dstride,
                                                        const float* __restrict__ Xb,
                                                        size_t xstride, int lda, int C,
                                                        int* __restrict__ idxout, size_t istride,
                                                        int n0, int rows) {
  __shared__ int scand[4][MAXCAND];
  int wave = threadIdx.x >> 6, lane = threadIdx.x & 63;
  int row = blockIdx.x * 4 + wave;
  if (row >= rows) return;
  const float* distb = dist + (size_t)blockIdx.y * dstride;
  const float* Xbb = Xb + (size_t)blockIdx.y * xstride;
  int* idxb = idxout + (size_t)blockIdx.y * istride;
  const float* d = distb + (size_t)row * NPTS;
  float v[16][4];
  float lmax = -__builtin_inff();
#pragma unroll
  for (int s = 0; s < 16; ++s) {
    *(float4*)v[s] = *(const float4*)&d[s * 256 + lane * 4];
#pragma unroll
    for (int c = 0; c < 4; ++c) lmax = fmaxf(lmax, v[s][c]);
  }

  float sv = lmax;
  for (int k = 2; k <= 64; k <<= 1) {
    for (int j = k >> 1; j > 0; j >>= 1) {
      float ov = __shfl_xor(sv, j);
      bool up = ((lane & k) == 0);
      bool lower = ((lane & j) == 0);
      bool mineLess = sv < ov;
      bool keepMine = (up == lower) ? mineLess : !mineLess;
      sv = keepMine ? sv : ov;
    }
  }
  float T = __shfl(sv, 44);

  int myCnt = 0;
#pragma unroll
  for (int s = 0; s < 16; ++s)
#pragma unroll
    for (int c = 0; c < 4; ++c) myCnt += (v[s][c] >= T) ? 1 : 0;
  int ofs = myCnt;
  for (int dlt = 1; dlt < 64; dlt <<= 1) {
    int o = __shfl_up(ofs, dlt);
    if (lane >= dlt) ofs += o;
  }
  int total = __shfl(ofs, 63);
  ofs -= myCnt;
  int w = ofs;
#pragma unroll
  for (int s = 0; s < 16; ++s)
#pragma unroll
    for (int c = 0; c < 4; ++c) {
      if (v[s][c] >= T) {
        if (w < MAXCAND) scand[wave][w] = s * 256 + lane * 4 + c;
        ++w;
      }
    }
  int cnt = imin(total, MAXCAND);
  int gn = n0 + row;
  const float* crow = Xbb + (size_t)gn * lda;
  int nch = (cnt + 63) >> 6;

  double runV = -__builtin_inf();
  int runI = 0x7fffffff;
  for (int ch = 0; ch < nch; ++ch) {
    int slot = ch * 64 + lane;
    int m = (slot < cnt) ? scand[wave][slot] : -1;
    double val = -__builtin_inf();
    int vi = 0x7fffffff;
    if (m >= 0) {
      const float* mrow = Xbb + (size_t)m * lda;
      double dd = 0.0;
      for (int c = 0; c < C; c += 4) {
        float4 a = *(const float4*)&crow[c];
        float4 b = *(const float4*)&mrow[c];
#pragma unroll
        for (int qq = 0; qq < 4; ++qq) {
          double df = (double)((const float*)&a)[qq] - (double)((const float*)&b)[qq];
          dd = fma(df, df, dd);
        }
      }
      val = -dd;
      vi = m;
    }
    for (int k = 2; k <= 64; k <<= 1) {
      for (int j = k >> 1; j > 0; j >>= 1) {
        double ov = __shfl_xor(val, j);
        int oi = __shfl_xor(vi, j);
        bool up = ((lane & k) == 0);
        bool lower = ((lane & j) == 0);
        bool mineLess = comp_less(val, vi, ov, oi);
        bool keepMine = (up == lower) ? mineLess : !mineLess;
        if (!keepMine) { val = ov; vi = oi; }
      }
    }
    if (ch == 0) {
      runV = val;
      runI = vi;
    } else {
      double rv = __shfl(val, 63 - lane);
      int ri = __shfl(vi, 63 - lane);
      if (comp_less(runV, runI, rv, ri)) { runV = rv; runI = ri; }
      for (int j = 32; j > 0; j >>= 1) {
        double ov = __shfl_xor(runV, j);
        int oi = __shfl_xor(runI, j);
        bool lower = ((lane & j) == 0);
        bool mineLess = comp_less(runV, runI, ov, oi);
        bool keepMine = lower ? mineLess : !mineLess;
        if (!keepMine) { runV = ov; runI = oi; }
      }
    }
  }
  if (lane >= 44) idxb[(size_t)gn * KNN + (63 - lane)] = runI;
}

// ---------------- fused layer-1 kNN (C=3): whole point set in LDS ----------------
__global__ __launch_bounds__(256) void dist3_topk_kernel(const float* __restrict__ Xb,
                                                         int* __restrict__ idxout) {
  __shared__ float xs[NPTS], ys[NPTS], zs[NPTS];
  __shared__ int scand[4][MAXCAND];
  int t = threadIdx.x;
  const float* Xbb = Xb + (size_t)blockIdx.y * NPTS * 3;
  for (int i = t; i < NPTS * 3; i += 256) {
    int n = i / 3, c = i - n * 3;
    float v = Xbb[i];
    if (c == 0) xs[n] = v;
    else if (c == 1) ys[n] = v;
    else zs[n] = v;
  }
  __syncthreads();
  int wave = t >> 6, lane = t & 63;
  int row = blockIdx.x * 4 + wave;
  float cx = xs[row], cy = ys[row], cz = zs[row];
  float v[16][4];
  float lmax = -__builtin_inff();
#pragma unroll
  for (int s = 0; s < 16; ++s)
#pragma unroll
    for (int c = 0; c < 4; ++c) {
      int m = s * 256 + c * 64 + lane;
      float dx = cx - xs[m], dy = cy - ys[m], dz = cz - zs[m];
      float dv = -(dx * dx + dy * dy + dz * dz);
      v[s][c] = dv;
      lmax = fmaxf(lmax, dv);
    }

  float sv = lmax;
  for (int k = 2; k <= 64; k <<= 1) {
    for (int j = k >> 1; j > 0; j >>= 1) {
      float ov = __shfl_xor(sv, j);
      bool up = ((lane & k) == 0);
      bool lower = ((lane & j) == 0);
      bool mineLess = sv < ov;
      bool keepMine = (up == lower) ? mineLess : !mineLess;
      sv = keepMine ? sv : ov;
    }
  }
  float T = __shfl(sv, 44);

  int myCnt = 0;
#pragma unroll
  for (int s = 0; s < 16; ++s)
#pragma unroll
    for (int c = 0; c < 4; ++c) myCnt += (v[s][c] >= T) ? 1 : 0;
  int ofs = myCnt;
  for (int dlt = 1; dlt < 64; dlt <<= 1) {
    int o = __shfl_up(ofs, dlt);
    if (lane >= dlt) ofs += o;
  }
  int total = __shfl(ofs, 63);
  ofs -= myCnt;
  int w = ofs;
#pragma unroll
  for (int s = 0; s < 16; ++s)
#pragma unroll
    for (int c = 0; c < 4; ++c) {
      if (v[s][c] >= T) {
        if (w < MAXCAND) scand[wave][w] = s * 256 + c * 64 + lane;
        ++w;
      }
    }
  int cnt = imin(total, MAXCAND);
  int nch = (cnt + 63) >> 6;

  double runV = -__builtin_inf();
  int runI = 0x7fffffff;
  for (int ch = 0; ch < nch; ++ch) {
    int slot = ch * 64 + lane;
    int m = (slot < cnt) ? scand[wave][slot] : -1;
    double val = -__builtin_inf();
    int vi = 0x7fffffff;
    if (m >= 0) {
      double dx = (double)cx - (double)xs[m];
      double dy = (double)cy - (double)ys[m];
      double dz = (double)cz - (double)zs[m];
      val = -(dx * dx + dy * dy + dz * dz);
      vi = m;
    }
    for (int k = 2; k <= 64; k <<= 1) {
      for (int j = k >> 1; j > 0; j >>= 1) {
        double ov = __shfl_xor(val, j);
        int oi = __shfl_xor(vi, j);
        bool up = ((lane & k) == 0);
        bool lower = ((lane & j) == 0);
        bool mineLess = comp_less(val, vi, ov, oi);
        bool keepMine = (up == lower) ? mineLess : !mineLess;
        if (!keepMine) { val = ov; vi = oi; }
      }
    }
    if (ch == 0) {
      runV = val;
      runI = vi;
    } else {
      double rv = __shfl(val, 63 - lane);
      int ri = __shfl(vi, 63 - lane);
      if (comp_less(runV, runI, rv, ri)) { runV = rv; runI = ri; }
      for (int j = 32; j > 0; j >>= 1) {
        double ov = __shfl_xor(runV, j);
        int oi = __shfl_xor(runI, j);
        bool lower = ((lane & j) == 0);
        bool mineLess = comp_less(runV, runI, ov, oi);
        bool keepMine = lower ? mineLess : !mineLess;
        if (!keepMine) { runV = ov; runI = oi; }
      }
    }
  }
  if (lane >= 44)
    idxout[((size_t)blockIdx.y * NPTS + row) * KNN + (63 - lane)] = runI;
}

// ---------------- gather-max + per-block fp64 BN partial stats ----------------
template <int NO>
__global__ __launch_bounds__(256) void gathermax_kernel(const float* __restrict__ PQ,
                                                        const int* __restrict__ idx,
                                                        float* __restrict__ hmax, int O,
                                                        double* __restrict__ pbuf) {
  __shared__ double sh1[4][256];
  __shared__ double sh2[4][256];
  int t = threadIdx.x;
  int wave = t >> 6, lane = t & 63;
  int pt = blockIdx.x * 4 + wave;
  int b = pt >> 12;
  int O2 = 2 * O;
  int iv = idx[(size_t)pt * KNN + (lane % KNN)];
  const float* Qp = PQ + (size_t)pt * O2 + O + lane * NO;
  float q[NO], mx[NO];
  double s1[NO], s2[NO];
#pragma unroll
  for (int c = 0; c < NO; ++c) {
    q[c] = Qp[c];
    mx[c] = -__builtin_inff();
    s1[c] = 0.0;
    s2[c] = 0.0;
  }
#pragma unroll
  for (int k = 0; k < KNN; ++k) {
    int m = __shfl(iv, k);
    const float* Pp = PQ + ((size_t)(b << 12) + m) * O2 + lane * NO;
    float p[NO];
#pragma unroll
    for (int c = 0; c < NO; ++c) p[c] = Pp[c];
#pragma unroll
    for (int c = 0; c < NO; ++c) {
      float h = p[c] + q[c];
      mx[c] = fmaxf(mx[c], h);
      double hd = (double)h;
      s1[c] += hd;
      s2[c] += hd * hd;
    }
  }
  float* Hp = hmax + (size_t)pt * O + lane * NO;
#pragma unroll
  for (int c = 0; c < NO; ++c) {
    Hp[c] = mx[c];
    sh1[wave][lane * NO + c] = s1[c];
    sh2[wave][lane * NO + c] = s2[c];
  }
  __syncthreads();
  if (t < O) {
    double a = 0.0, bb = 0.0;
#pragma unroll
    for (int w = 0; w < 4; ++w) {
      a += sh1[w][t];
      bb += sh2[w][t];
    }
    pbuf[(size_t)blockIdx.x * O2 + t] = a;
    pbuf[(size_t)blockIdx.x * O2 + O + t] = bb;
  }
}

// ---------------- deterministic parallel fp64 BN reduce + finalize ----------------
__global__ __launch_bounds__(256) void bn_reduce_finalize(const double* __restrict__ pbuf,
                                                          int nblk, int O,
                                                          const float* __restrict__ g,
                                                          const float* __restrict__ bb,
                                                          double invcount,
                                                          float* __restrict__ s_out,
                                                          float* __restrict__ t_out) {
  __shared__ double sh1[256];
  __shared__ double sh2[256];
  int o = blockIdx.x;
  int t = threadIdx.x;
  double s1 = 0.0, s2 = 0.0;
  for (int blk = t; blk < nblk; blk += 256) {
    s1 += pbuf[(size_t)blk * 2 * O + o];
    s2 += pbuf[(size_t)blk * 2 * O + O + o];
  }
  sh1[t] = s1;
  sh2[t] = s2;
  __syncthreads();
  for (int s = 128; s > 0; s >>= 1) {
    if (t < s) {
      sh1[t] += sh1[t + s];
      sh2[t] += sh2[t + s];
    }
    __syncthreads();
  }
  if (t == 0) {
    double mean = sh1[0] * invcount;
    double var = sh2[0] * invcount - mean * mean;
    double s = (double)g[o] / sqrt(var + BNEPS);
    s_out[o] = (float)s;
    t_out[o] = (float)((double)bb[o] - mean * s);
  }
}

// y = leaky(hmax*s+t) into feat column slice (fp32) + featbf (bf16, fused conversion)
__global__ void apply_kernel(const float* __restrict__ hmax, const float* __restrict__ s,
                             const float* __restrict__ tt, float* __restrict__ feat,
                             u16* __restrict__ featbf, int colOff, int logO, int total) {
  int i = blockIdx.x * 256 + threadIdx.x;
  if (i >= total) return;
  int O = 1 << logO;
  int o = i & (O - 1);
  int pp = i >> logO;
  float v = hmax[i] * s[o] + tt[o];
  float r = v > 0.f ? v : SLOPE * v;
  size_t di = (size_t)pp * 512 + colOff + o;
  feat[di] = r;
  unsigned xbits = __float_as_uint(r);
  unsigned rr = xbits + 0x7fff + ((xbits >> 16) & 1);
  featbf[di] = (u16)(rr >> 16);
}

// column partial stats over H (rows x 1024): pbuf[rb][2048] = [sum | sq] (fp64)
__global__ void colstats_kernel(const float* __restrict__ H, double* __restrict__ pbuf) {
  int o = blockIdx.x * 256 + threadIdx.x;
  int rb = blockIdx.y;
  int r0 = rb * 128;
  double s1 = 0.0, s2 = 0.0;
  for (int r = 0; r < 128; ++r) {
    double v = (double)H[(size_t)(r0 + r) * 1024 + o];
    s1 += v;
    s2 += v * v;
  }
  pbuf[(size_t)rb * 2048 + o] = s1;
  pbuf[(size_t)rb * 2048 + 1024 + o] = s2;
}

// out[b][o][n] = leaky(h5[b][n][o]*s+t)
__global__ void out_kernel(const float* __restrict__ h5, const float* __restrict__ s,
                           const float* __restrict__ tt, float* __restrict__ out) {
  __shared__ float tile[32][33];
  int b = blockIdx.z;
  int n0 = blockIdx.x * 32, o0 = blockIdx.y * 32;
  int t = threadIdx.x;
  for (int e = t; e < 1024; e += 256) {
    int rn = e >> 5, co = e & 31;
    int o = o0 + co;
    float v = h5[((size_t)b * NPTS + n0 + rn) * 1024 + o] * s[o] + tt[o];
    tile[rn][co] = v > 0.f ? v : SLOPE * v;
  }
  __syncthreads();
  for (int e = t; e < 1024; e += 256) {
    int ro = e >> 5, cn = e & 31;
    out[((size_t)b * 1024 + o0 + ro) * NPTS + n0 + cn] = tile[cn][ro];
  }
}

// ---------------- host ----------------
extern "C" void kernel_launch(void* const* d_in, const int* in_sizes, int n_in,
                              void* d_out, int out_size, void* d_ws, size_t ws_size,
                              hipStream_t stream) {
  const float* x = (const float*)d_in[0];
  const float* Wm[5] = {(const float*)d_in[1], (const float*)d_in[4], (const float*)d_in[7],
                        (const float*)d_in[10], (const float*)d_in[13]};
  const float* gv[5] = {(const float*)d_in[2], (const float*)d_in[5], (const float*)d_in[8],
                        (const float*)d_in[11], (const float*)d_in[14]};
  const float* bvv[5] = {(const float*)d_in[3], (const float*)d_in[6], (const float*)d_in[9],
                         (const float*)d_in[12], (const float*)d_in[15]};
  float* out = (float*)d_out;

  char* wsb = (char*)d_ws;
  size_t off = 0;
  auto alloc = [&](size_t bytes) -> char* {
    off = (off + 255) & ~(size_t)255;
    char* p = wsb + off;
    off += bytes;
    return p;
  };
  float* xb = (float*)alloc((size_t)BATCH * NPTS * 3 * 4);
  float* xxb = (float*)alloc((size_t)BATCH * NPTS * 4);
  int* idxb = (int*)alloc((size_t)BATCH * NPTS * KNN * 4);
  float* feat = (float*)alloc((size_t)BATCH * NPTS * 512 * 4);
  float* hmax = (float*)alloc((size_t)BATCH * NPTS * 256 * 4);
  float* h5 = (float*)alloc((size_t)BATCH * NPTS * 1024 * 4);
  float* PQ = h5;  // alias: PQ used per-layer, h5 only needed after
  float* U1 = (float*)alloc(3 * 128 * 4);
  float* U2 = (float*)alloc(64 * 128 * 4);
  float* U3 = (float*)alloc(64 * 256 * 4);
  float* U4 = (float*)alloc(128 * 512 * 4);
  u16* featbf = (u16*)alloc((size_t)BATCH * NPTS * 512 * 2);
  u16* w5bf = (u16*)alloc((size_t)1024 * 512 * 2);
  double* pbuf = (double*)alloc((size_t)2048 * 512 * 8);
  float* stv = (float*)alloc(3072 * 4);
  off = (off + 255) & ~(size_t)255;
  size_t avail = (ws_size > off) ? (ws_size - off) : 0;
  size_t slab = (size_t)NPTS * NPTS * 4;  // one batch's dist matrix
  int nbfit = (int)imin((int)(avail / slab), BATCH);  // 0, 1, or 2 slabs fit
  size_t rmax = avail / ((size_t)NPTS * 4);
  int R;
  if (rmax >= NPTS) R = NPTS;
  else {
    R = (int)(rmax & ~(size_t)127);
    if (R < 128) R = 128;
  }
  float* distbuf = (float*)(wsb + off);

  float* sv[5] = {stv + 0, stv + 128, stv + 256, stv + 512, stv + 1024};
  float* tv[5] = {stv + 64, stv + 192, stv + 384, stv + 768, stv + 2048};
  float* Us[4] = {U1, U2, U3, U4};
  const int Cs[4] = {3, 64, 64, 128};
  const int Osz[4] = {64, 64, 128, 256};
  const int ntile = (NPTS / 128) * (NPTS / 128 + 1) / 2;  // 528

  xtrans_kernel<<<(BATCH * 3 * NPTS + 255) / 256, 256, 0, stream>>>(x, xb);
  for (int l = 0; l < 4; ++l)
    uprep_kernel<<<(Cs[l] * Osz[l] + 255) / 256, 256, 0, stream>>>(Wm[l], Us[l], Osz[l], Cs[l]);
  tobf16_kernel<<<(1024 * 512 / 4 + 255) / 256, 256, 0, stream>>>(Wm[4], w5bf, 1024 * 512 / 4);

  auto knn = [&](const float* Xbase, int lda, int C) {
    xx_kernel<<<(BATCH * NPTS + 255) / 256, 256, 0, stream>>>(Xbase, lda, C, xxb);
    size_t selems = (size_t)NPTS * NPTS;
    if (nbfit >= BATCH) {
      // both batches in one dispatch: 2x grid, 2 dist slabs
      gemm_dist_sym_kernel<<<dim3(ntile, BATCH), 256, 0, stream>>>(Xbase, lda, xxb, distbuf, C,
                                                                   selems);
      topk_fast_kernel<<<dim3(NPTS / 4, BATCH), 256, 0, stream>>>(
          distbuf, selems, Xbase, (size_t)NPTS * lda, lda, C, idxb, (size_t)NPTS * KNN, 0, NPTS);
    } else if (nbfit >= 1) {
      for (int b = 0; b < BATCH; ++b) {
        const float* Xb = Xbase + (size_t)b * NPTS * lda;
        gemm_dist_sym_kernel<<<dim3(ntile, 1), 256, 0, stream>>>(Xb, lda, xxb + (size_t)b * NPTS,
                                                                 distbuf, C, 0);
        topk_fast_kernel<<<dim3(NPTS / 4, 1), 256, 0, stream>>>(
            distbuf, 0, Xb, 0, lda, C, idxb + (size_t)b * NPTS * KNN, 0, 0, NPTS);
      }
    } else {
      for (int b = 0; b < BATCH; ++b) {
        const float* Xb = Xbase + (size_t)b * NPTS * lda;
        for (int n0 = 0; n0 < NPTS; n0 += R) {
          int rows = imin(R, NPTS - n0);
          gemm128<true, true><<<dim3(NPTS / 128, rows / 128), 256, 0, stream>>>(
              Xb + (size_t)n0 * lda, lda, Xb, lda, distbuf, NPTS, C, xxb + (size_t)b * NPTS + n0,
              xxb + (size_t)b * NPTS);
          topk_fast_kernel<<<dim3(rows / 4, 1), 256, 0, stream>>>(
              distbuf, 0, Xb, 0, lda, C, idxb + (size_t)b * NPTS * KNN, 0, n0, rows);
        }
      }
    }
  };

  auto edge = [&](int li, const float* Xbase, int lda, int C, int O, int colOff) {
    if (li == 0) {
      dist3_topk_kernel<<<dim3(NPTS / 4, BATCH), 256, 0, stream>>>(Xbase, idxb);
    } else {
      knn(Xbase, lda, C);
    }
    int O2 = 2 * O;
    gemm128<false, false><<<dim3(O2 / 128, BATCH * NPTS / 128), 256, 0, stream>>>(
        Xbase, lda, Us[li], O2, PQ, O2, C, nullptr, nullptr);
    int nblk = BATCH * NPTS / 4;
    if (O == 64)
      gathermax_kernel<1><<<nblk, 256, 0, stream>>>(PQ, idxb, hmax, O, pbuf);
    else if (O == 128)
      gathermax_kernel<2><<<nblk, 256, 0, stream>>>(PQ, idxb, hmax, O, pbuf);
    else
      gathermax_kernel<4><<<nblk, 256, 0, stream>>>(PQ, idxb, hmax, O, pbuf);
    bn_reduce_finalize<<<O, 256, 0, stream>>>(pbuf, nblk, O, gv[li], bvv[li],
                                              1.0 / ((double)BATCH * NPTS * KNN), sv[li], tv[li]);
    int logO = (O == 64) ? 6 : (O == 128) ? 7 : 8;
    int total = BATCH * NPTS * O;
    apply_kernel<<<(total + 255) / 256, 256, 0, stream>>>(hmax, sv[li], tv[li], feat, featbf,
                                                          colOff, logO, total);
  };

  edge(0, xb, 3, 3, 64, 0);
  edge(1, feat, 512, 64, 64, 64);
  edge(2, feat + 64, 512, 64, 128, 128);
  edge(3, feat + 128, 512, 128, 256, 256);

  fc_mfma_kernel<<<dim3(1024 / 128, BATCH * NPTS / 128), 256, 0, stream>>>(featbf, w5bf, h5);
  colstats_kernel<<<dim3(4, 64), 256, 0, stream>>>(h5, pbuf);
  bn_reduce_finalize<<<1024, 256, 0, stream>>>(pbuf, 64, 1024, gv[4], bvv[4],
                                               1.0 / ((double)BATCH * NPTS), sv[4], tv[4]);
  out_kernel<<<dim3(NPTS / 32, 1024 / 32, BATCH), 256, 0, stream>>>(h5, sv[4], tv[4], out);
}

// Round 13
// 643.118 us; speedup vs baseline: 1.6975x; 1.1119x over previous
//
#include <hip/hip_runtime.h>
#include <cmath>

#define KNN 20
#define NPTS 4096
#define BATCH 2
#define SLOPE 0.2f
#define BNEPS 1e-5
#define GTK 16
#define MAXCAND 256

typedef unsigned short u16;
typedef __attribute__((ext_vector_type(8))) short bf16x8;
typedef __attribute__((ext_vector_type(4))) float f32x4;
typedef _Float16 h8 __attribute__((ext_vector_type(8)));
typedef _Float16 h4 __attribute__((ext_vector_type(4)));

static __device__ __host__ inline int imin(int a, int b) { return a < b ? a : b; }

// ---------------- utility kernels ----------------
// x (B,3,N) -> xb (B,N,3)
__global__ void xtrans_kernel(const float* __restrict__ x, float* __restrict__ xb) {
  int i = blockIdx.x * 256 + threadIdx.x;
  if (i < BATCH * 3 * NPTS) {
    int b = i / (3 * NPTS);
    int r = i - b * 3 * NPTS;
    int c = r / NPTS;
    int n = r - c * NPTS;
    xb[((size_t)b * NPTS + n) * 3 + c] = x[i];
  }
}

// W (O, 2C) -> U (C, 2O): U[j][o]=W[o][j]; U[j][O+o]=W[o][C+j]-W[o][j]
__global__ void uprep_kernel(const float* __restrict__ W, float* __restrict__ U, int O, int C) {
  int i = blockIdx.x * 256 + threadIdx.x;
  if (i < C * O) {
    int j = i / O, o = i - j * O;
    float w1 = W[(size_t)o * 2 * C + j];
    float w2 = W[(size_t)o * 2 * C + C + j];
    U[(size_t)j * 2 * O + o] = w1;
    U[(size_t)j * 2 * O + O + o] = w2 - w1;
  }
}

// squared norms per point (fp64 accumulate, fp32 store — candidate pass only)
__global__ void xx_kernel(const float* __restrict__ X, int stride, int C, float* __restrict__ xx) {
  int i = blockIdx.x * 256 + threadIdx.x;
  if (i < BATCH * NPTS) {
    const float* r = X + (size_t)i * stride;
    double s = 0.0;
    for (int c = 0; c < C; ++c) s += (double)r[c] * (double)r[c];
    xx[i] = (float)s;
  }
}

// fp32 -> bf16 (RNE), 4 elements/thread
__global__ void tobf16_kernel(const float* __restrict__ src, u16* __restrict__ dst, int n4) {
  int i = blockIdx.x * 256 + threadIdx.x;
  if (i < n4) {
    float4 v = *(const float4*)&src[(size_t)i * 4];
    unsigned o[4];
#pragma unroll
    for (int j = 0; j < 4; ++j) {
      unsigned x = __float_as_uint(((const float*)&v)[j]);
      unsigned rr = x + 0x7fff + ((x >> 16) & 1);
      o[j] = rr >> 16;
    }
    uint2 pk;
    pk.x = o[0] | (o[1] << 16);
    pk.y = o[2] | (o[3] << 16);
    *(uint2*)&dst[(size_t)i * 4] = pk;
  }
}

// ---------------- generic 128x128 fp32 GEMM, 8x8 micro (single-buffered) ----------------
// C[M x N] = A[M x K] * (BT ? B[N x K]^T : B[K x N]); DIST epilogue writes fp16:
// (half)(2*acc - xxA[r] - xxB[c]). k-major swizzled LDS.
template <bool BT, bool DIST>
__global__ __launch_bounds__(256) void gemm128(const float* __restrict__ A, int lda,
                                               const float* __restrict__ B, int ldb,
                                               void* __restrict__ Cout, int ldc, int K,
                                               const float* __restrict__ xxA,
                                               const float* __restrict__ xxB) {
  __shared__ __align__(16) float sA[GTK][144];
  __shared__ __align__(16) float sB[GTK][144];
  int t = threadIdx.x;
  int tx = t & 15, ty = t >> 4;
  int row0 = blockIdx.y * 128, col0 = blockIdx.x * 128;
  float acc[8][8] = {};

  for (int k0 = 0; k0 < K; k0 += GTK) {
    bool fast = (k0 + GTK <= K);
    if (fast) {
#pragma unroll
      for (int it = 0; it < 2; ++it) {
        int i = t + it * 256;
        int r = i >> 2, q = i & 3;
        const float4 av = *(const float4*)&A[(size_t)(row0 + r) * lda + k0 + q * 4];
        int pr = r + ((r >> 5) << 2);
        sA[q * 4 + 0][pr] = av.x;
        sA[q * 4 + 1][pr] = av.y;
        sA[q * 4 + 2][pr] = av.z;
        sA[q * 4 + 3][pr] = av.w;
      }
    } else {
#pragma unroll
      for (int it = 0; it < 2; ++it) {
        int i = t + it * 256;
        int r = i >> 2, q = i & 3;
        int pr = r + ((r >> 5) << 2);
#pragma unroll
        for (int j = 0; j < 4; ++j) {
          int k = q * 4 + j;
          sA[k][pr] = (k0 + k < K) ? A[(size_t)(row0 + r) * lda + k0 + k] : 0.f;
        }
      }
    }
    if (BT) {
      if (fast) {
#pragma unroll
        for (int it = 0; it < 2; ++it) {
          int i = t + it * 256;
          int r = i >> 2, q = i & 3;
          const float4 bv = *(const float4*)&B[(size_t)(col0 + r) * ldb + k0 + q * 4];
          int pr = r + ((r >> 5) << 2);
          sB[q * 4 + 0][pr] = bv.x;
          sB[q * 4 + 1][pr] = bv.y;
          sB[q * 4 + 2][pr] = bv.z;
          sB[q * 4 + 3][pr] = bv.w;
        }
      } else {
#pragma unroll
        for (int it = 0; it < 2; ++it) {
          int i = t + it * 256;
          int r = i >> 2, q = i & 3;
          int pr = r + ((r >> 5) << 2);
#pragma unroll
          for (int j = 0; j < 4; ++j) {
            int k = q * 4 + j;
            sB[k][pr] = (k0 + k < K) ? B[(size_t)(col0 + r) * ldb + k0 + k] : 0.f;
          }
        }
      }
    } else {
#pragma unroll
      for (int it = 0; it < 2; ++it) {
        int i = t + it * 256;
        int k = i >> 5, nq = (i & 31) * 4;
        int pc = nq + ((nq >> 5) << 2);
        float4 bv = make_float4(0.f, 0.f, 0.f, 0.f);
        if (k0 + k < K) bv = *(const float4*)&B[(size_t)(k0 + k) * ldb + col0 + nq];
        *(float4*)&sB[k][pc] = bv;
      }
    }
    __syncthreads();
    int prA = ty * 8 + ((ty >> 2) << 2);
    int prB = tx * 8 + ((tx >> 2) << 2);
#pragma unroll
    for (int kk = 0; kk < GTK; ++kk) {
      float a[8], b[8];
      *(float4*)&a[0] = *(const float4*)&sA[kk][prA];
      *(float4*)&a[4] = *(const float4*)&sA[kk][prA + 4];
      *(float4*)&b[0] = *(const float4*)&sB[kk][prB];
      *(float4*)&b[4] = *(const float4*)&sB[kk][prB + 4];
#pragma unroll
      for (int i = 0; i < 8; ++i)
#pragma unroll
        for (int j = 0; j < 8; ++j) acc[i][j] += a[i] * b[j];
    }
    __syncthreads();
  }

  if (DIST) {
    _Float16* Ch = (_Float16*)Cout;
#pragma unroll
    for (int i = 0; i < 8; ++i) {
      int gr = row0 + ty * 8 + i;
      float xa = xxA[gr];
      h8 o;
#pragma unroll
      for (int j = 0; j < 8; ++j) {
        int gc = col0 + tx * 8 + j;
        o[j] = (_Float16)(2.f * acc[i][j] - xa - xxB[gc]);
      }
      *(h8*)&Ch[(size_t)gr * ldc + col0 + tx * 8] = o;
    }
  } else {
    float* Cf = (float*)Cout;
#pragma unroll
    for (int i = 0; i < 8; ++i) {
      int gr = row0 + ty * 8 + i;
#pragma unroll
      for (int jq = 0; jq < 2; ++jq) {
        float4 o;
#pragma unroll
        for (int j = 0; j < 4; ++j) ((float*)&o)[j] = acc[i][jq * 4 + j];
        *(float4*)&Cf[(size_t)gr * ldc + col0 + tx * 8 + jq * 4] = o;
      }
    }
  }
}

// ---------------- symmetric distance GEMM: lower-triangle tiles, mirrored write (fp16) -----
// grid (ntile, nbatch). dist batch slab stride = dstride half-elements.
// Both orientations written directly from the 8x8 register tile as packed h8 stores
// (cols contiguous for direct, rows contiguous for mirror) — identical converted values.
__global__ __launch_bounds__(256) void gemm_dist_sym_kernel(const float* __restrict__ X, int lda,
                                                            const float* __restrict__ xx,
                                                            _Float16* __restrict__ dist, int K,
                                                            size_t dstride) {
  __shared__ __align__(16) float sA[GTK][144];
  __shared__ __align__(16) float sB[GTK][144];
  int t = threadIdx.x;
  int tx = t & 15, ty = t >> 4;
  const float* Xb = X + (size_t)blockIdx.y * NPTS * lda;
  const float* xxv = xx + (size_t)blockIdx.y * NPTS;
  _Float16* db = dist + (size_t)blockIdx.y * dstride;
  int l = blockIdx.x;
  int bi = (int)((sqrtf(8.f * (float)l + 1.f) - 1.f) * 0.5f);
  while ((bi + 1) * (bi + 2) / 2 <= l) ++bi;
  while (bi * (bi + 1) / 2 > l) --bi;
  int bj = l - bi * (bi + 1) / 2;
  int row0 = bi * 128, col0 = bj * 128;
  float acc[8][8] = {};

  for (int k0 = 0; k0 < K; k0 += GTK) {
#pragma unroll
    for (int it = 0; it < 2; ++it) {
      int i = t + it * 256;
      int r = i >> 2, q = i & 3;
      const float4 av = *(const float4*)&Xb[(size_t)(row0 + r) * lda + k0 + q * 4];
      const float4 bv = *(const float4*)&Xb[(size_t)(col0 + r) * lda + k0 + q * 4];
      int pr = r + ((r >> 5) << 2);
      sA[q * 4 + 0][pr] = av.x;
      sA[q * 4 + 1][pr] = av.y;
      sA[q * 4 + 2][pr] = av.z;
      sA[q * 4 + 3][pr] = av.w;
      sB[q * 4 + 0][pr] = bv.x;
      sB[q * 4 + 1][pr] = bv.y;
      sB[q * 4 + 2][pr] = bv.z;
      sB[q * 4 + 3][pr] = bv.w;
    }
    __syncthreads();
    int prA = ty * 8 + ((ty >> 2) << 2);
    int prB = tx * 8 + ((tx >> 2) << 2);
#pragma unroll
    for (int kk = 0; kk < GTK; ++kk) {
      float a[8], b[8];
      *(float4*)&a[0] = *(const float4*)&sA[kk][prA];
      *(float4*)&a[4] = *(const float4*)&sA[kk][prA + 4];
      *(float4*)&b[0] = *(const float4*)&sB[kk][prB];
      *(float4*)&b[4] = *(const float4*)&sB[kk][prB + 4];
#pragma unroll
      for (int i = 0; i < 8; ++i)
#pragma unroll
        for (int j = 0; j < 8; ++j) acc[i][j] += a[i] * b[j];
    }
    __syncthreads();
  }

  // DIST transform in registers
  {
    float xa[8], xb_[8];
#pragma unroll
    for (int i = 0; i < 8; ++i) xa[i] = xxv[row0 + ty * 8 + i];
#pragma unroll
    for (int j = 0; j < 8; ++j) xb_[j] = xxv[col0 + tx * 8 + j];
#pragma unroll
    for (int i = 0; i < 8; ++i)
#pragma unroll
      for (int j = 0; j < 8; ++j) acc[i][j] = 2.f * acc[i][j] - xa[i] - xb_[j];
  }
  // direct tile: cols contiguous per row
#pragma unroll
  for (int i = 0; i < 8; ++i) {
    h8 o;
#pragma unroll
    for (int j = 0; j < 8; ++j) o[j] = (_Float16)acc[i][j];
    *(h8*)&db[(size_t)(row0 + ty * 8 + i) * NPTS + col0 + tx * 8] = o;
  }
  // mirrored tile: rows contiguous per col (same converted values)
  if (bi != bj) {
#pragma unroll
    for (int j = 0; j < 8; ++j) {
      h8 o;
#pragma unroll
      for (int i = 0; i < 8; ++i) o[i] = (_Float16)acc[i][j];
      *(h8*)&db[(size_t)(col0 + tx * 8 + j) * NPTS + row0 + ty * 8] = o;
    }
  }
}

// ---------------- bf16 MFMA FC: C[8192x1024] = A[8192x512] * B[1024x512]^T ----------------
__global__ __launch_bounds__(256) void fc_mfma_kernel(const u16* __restrict__ A,
                                                      const u16* __restrict__ B,
                                                      float* __restrict__ C) {
  __shared__ u16 sA[128][56];
  __shared__ u16 sB[128][56];
  int t = threadIdx.x;
  int lane = t & 63, wave = t >> 6;
  int row0 = blockIdx.y * 128, col0 = blockIdx.x * 128;
  int wr = (wave >> 1) * 64, wc = (wave & 1) * 64;
  int m = lane & 15, q = lane >> 4;
  f32x4 acc[4][4];
#pragma unroll
  for (int i = 0; i < 4; ++i)
#pragma unroll
    for (int j = 0; j < 4; ++j) acc[i][j] = (f32x4){0.f, 0.f, 0.f, 0.f};
  for (int k0 = 0; k0 < 512; k0 += 32) {
#pragma unroll
    for (int it = 0; it < 2; ++it) {
      int i = t + it * 256;
      int r = i >> 2, ch = (i & 3) * 8;
      *(uint4*)&sA[r][ch] = *(const uint4*)&A[(size_t)(row0 + r) * 512 + k0 + ch];
      *(uint4*)&sB[r][ch] = *(const uint4*)&B[(size_t)(col0 + r) * 512 + k0 + ch];
    }
    __syncthreads();
    bf16x8 af[4], bf[4];
#pragma unroll
    for (int i = 0; i < 4; ++i) af[i] = *(const bf16x8*)&sA[wr + i * 16 + m][q * 8];
#pragma unroll
    for (int j = 0; j < 4; ++j) bf[j] = *(const bf16x8*)&sB[wc + j * 16 + m][q * 8];
#pragma unroll
    for (int i = 0; i < 4; ++i)
#pragma unroll
      for (int j = 0; j < 4; ++j)
        acc[i][j] = __builtin_amdgcn_mfma_f32_16x16x32_bf16(af[i], bf[j], acc[i][j], 0, 0, 0);
    __syncthreads();
  }
#pragma unroll
  for (int i = 0; i < 4; ++i)
#pragma unroll
    for (int j = 0; j < 4; ++j)
#pragma unroll
      for (int reg = 0; reg < 4; ++reg)
        C[(size_t)(row0 + wr + i * 16 + q * 4 + reg) * 1024 + col0 + wc + j * 16 + m] =
            acc[i][j][reg];
}

// ---------------- shared top-k selection helpers ----------------
__device__ inline bool comp_less(double v, int i, double ov, int oi) {
  // ascending-by-value; ties: larger index sorts "less" -> descending read gives lower idx first
  return (v < ov) || (v == ov && i > oi);
}

// ---------------- fast top-k: threshold filter (fp16 dist) + fp64 rescore + bitonic sort ---
// grid (rows/4, nbatch); batch strides in elements.
__global__ __launch_bounds__(256) void topk_fast_kernel(const _Float16* __restrict__ dist,
                                                        size_t dstride,
                                                        const float* __restrict__ Xb,
                                                        size_t xstride, int lda, int C,
                                                        int* __restrict__ idxout, size_t istride,
                                                        int n0, int rows) {
  __shared__ int scand[4][MAXCAND];
  int wave = threadIdx.x >> 6, lane = threadIdx.x & 63;
  int row = blockIdx.x * 4 + wave;
  if (row >= rows) return;
  const _Float16* distb = dist + (size_t)blockIdx.y * dstride;
  const float* Xbb = Xb + (size_t)blockIdx.y * xstride;
  int* idxb = idxout + (size_t)blockIdx.y * istride;
  const _Float16* d = distb + (size_t)row * NPTS;
  float v[16][4];
  float lmax = -__builtin_inff();
#pragma unroll
  for (int s = 0; s < 16; ++s) {
    h4 hv = *(const h4*)&d[s * 256 + lane * 4];
#pragma unroll
    for (int c = 0; c < 4; ++c) {
      v[s][c] = (float)hv[c];
      lmax = fmaxf(lmax, v[s][c]);
    }
  }

  float sv = lmax;
  for (int k = 2; k <= 64; k <<= 1) {
    for (int j = k >> 1; j > 0; j >>= 1) {
      float ov = __shfl_xor(sv, j);
      bool up = ((lane & k) == 0);
      bool lower = ((lane & j) == 0);
      bool mineLess = sv < ov;
      bool keepMine = (up == lower) ? mineLess : !mineLess;
      sv = keepMine ? sv : ov;
    }
  }
  float T = __shfl(sv, 44);

  int myCnt = 0;
#pragma unroll
  for (int s = 0; s < 16; ++s)
#pragma unroll
    for (int c = 0; c < 4; ++c) myCnt += (v[s][c] >= T) ? 1 : 0;
  int ofs = myCnt;
  for (int dlt = 1; dlt < 64; dlt <<= 1) {
    int o = __shfl_up(ofs, dlt);
    if (lane >= dlt) ofs += o;
  }
  int total = __shfl(ofs, 63);
  ofs -= myCnt;
  int w = ofs;
#pragma unroll
  for (int s = 0; s < 16; ++s)
#pragma unroll
    for (int c = 0; c < 4; ++c) {
      if (v[s][c] >= T) {
        if (w < MAXCAND) scand[wave][w] = s * 256 + lane * 4 + c;
        ++w;
      }
    }
  int cnt = imin(total, MAXCAND);
  int gn = n0 + row;
  const float* crow = Xbb + (size_t)gn * lda;
  int nch = (cnt + 63) >> 6;

  double runV = -__builtin_inf();
  int runI = 0x7fffffff;
  for (int ch = 0; ch < nch; ++ch) {
    int slot = ch * 64 + lane;
    int m = (slot < cnt) ? scand[wave][slot] : -1;
    double val = -__builtin_inf();
    int vi = 0x7fffffff;
    if (m >= 0) {
      const float* mrow = Xbb + (size_t)m * lda;
      double dd = 0.0;
      for (int c = 0; c < C; c += 4) {
        float4 a = *(const float4*)&crow[c];
        float4 b = *(const float4*)&mrow[c];
#pragma unroll
        for (int qq = 0; qq < 4; ++qq) {
          double df = (double)((const float*)&a)[qq] - (double)((const float*)&b)[qq];
          dd = fma(df, df, dd);
        }
      }
      val = -dd;
      vi = m;
    }
    for (int k = 2; k <= 64; k <<= 1) {
      for (int j = k >> 1; j > 0; j >>= 1) {
        double ov = __shfl_xor(val, j);
        int oi = __shfl_xor(vi, j);
        bool up = ((lane & k) == 0);
        bool lower = ((lane & j) == 0);
        bool mineLess = comp_less(val, vi, ov, oi);
        bool keepMine = (up == lower) ? mineLess : !mineLess;
        if (!keepMine) { val = ov; vi = oi; }
      }
    }
    if (ch == 0) {
      runV = val;
      runI = vi;
    } else {
      double rv = __shfl(val, 63 - lane);
      int ri = __shfl(vi, 63 - lane);
      if (comp_less(runV, runI, rv, ri)) { runV = rv; runI = ri; }
      for (int j = 32; j > 0; j >>= 1) {
        double ov = __shfl_xor(runV, j);
        int oi = __shfl_xor(runI, j);
        bool lower = ((lane & j) == 0);
        bool mineLess = comp_less(runV, runI, ov, oi);
        bool keepMine = lower ? mineLess : !mineLess;
        if (!keepMine) { runV = ov; runI = oi; }
      }
    }
  }
  if (lane >= 44) idxb[(size_t)gn * KNN + (63 - lane)] = runI;
}

// ---------------- fused layer-1 kNN (C=3): whole point set in LDS ----------------
__global__ __launch_bounds__(256) void dist3_topk_kernel(const float* __restrict__ Xb,
                                                         int* __restrict__ idxout) {
  __shared__ float xs[NPTS], ys[NPTS], zs[NPTS];
  __shared__ int scand[4][MAXCAND];
  int t = threadIdx.x;
  const float* Xbb = Xb + (size_t)blockIdx.y * NPTS * 3;
  for (int i = t; i < NPTS * 3; i += 256) {
    int n = i / 3, c = i - n * 3;
    float v = Xbb[i];
    if (c == 0) xs[n] = v;
    else if (c == 1) ys[n] = v;
    else zs[n] = v;
  }
  __syncthreads();
  int wave = t >> 6, lane = t & 63;
  int row = blockIdx.x * 4 + wave;
  float cx = xs[row], cy = ys[row], cz = zs[row];
  float v[16][4];
  float lmax = -__builtin_inff();
#pragma unroll
  for (int s = 0; s < 16; ++s)
#pragma unroll
    for (int c = 0; c < 4; ++c) {
      int m = s * 256 + c * 64 + lane;
      float dx = cx - xs[m], dy = cy - ys[m], dz = cz - zs[m];
      float dv = -(dx * dx + dy * dy + dz * dz);
      v[s][c] = dv;
      lmax = fmaxf(lmax, dv);
    }

  float sv = lmax;
  for (int k = 2; k <= 64; k <<= 1) {
    for (int j = k >> 1; j > 0; j >>= 1) {
      float ov = __shfl_xor(sv, j);
      bool up = ((lane & k) == 0);
      bool lower = ((lane & j) == 0);
      bool mineLess = sv < ov;
      bool keepMine = (up == lower) ? mineLess : !mineLess;
      sv = keepMine ? sv : ov;
    }
  }
  float T = __shfl(sv, 44);

  int myCnt = 0;
#pragma unroll
  for (int s = 0; s < 16; ++s)
#pragma unroll
    for (int c = 0; c < 4; ++c) myCnt += (v[s][c] >= T) ? 1 : 0;
  int ofs = myCnt;
  for (int dlt = 1; dlt < 64; dlt <<= 1) {
    int o = __shfl_up(ofs, dlt);
    if (lane >= dlt) ofs += o;
  }
  int total = __shfl(ofs, 63);
  ofs -= myCnt;
  int w = ofs;
#pragma unroll
  for (int s = 0; s < 16; ++s)
#pragma unroll
    for (int c = 0; c < 4; ++c) {
      if (v[s][c] >= T) {
        if (w < MAXCAND) scand[wave][w] = s * 256 + c * 64 + lane;
        ++w;
      }
    }
  int cnt = imin(total, MAXCAND);
  int nch = (cnt + 63) >> 6;

  double runV = -__builtin_inf();
  int runI = 0x7fffffff;
  for (int ch = 0; ch < nch; ++ch) {
    int slot = ch * 64 + lane;
    int m = (slot < cnt) ? scand[wave][slot] : -1;
    double val = -__builtin_inf();
    int vi = 0x7fffffff;
    if (m >= 0) {
      double dx = (double)cx - (double)xs[m];
      double dy = (double)cy - (double)ys[m];
      double dz = (double)cz - (double)zs[m];
      val = -(dx * dx + dy * dy + dz * dz);
      vi = m;
    }
    for (int k = 2; k <= 64; k <<= 1) {
      for (int j = k >> 1; j > 0; j >>= 1) {
        double ov = __shfl_xor(val, j);
        int oi = __shfl_xor(vi, j);
        bool up = ((lane & k) == 0);
        bool lower = ((lane & j) == 0);
        bool mineLess = comp_less(val, vi, ov, oi);
        bool keepMine = (up == lower) ? mineLess : !mineLess;
        if (!keepMine) { val = ov; vi = oi; }
      }
    }
    if (ch == 0) {
      runV = val;
      runI = vi;
    } else {
      double rv = __shfl(val, 63 - lane);
      int ri = __shfl(vi, 63 - lane);
      if (comp_less(runV, runI, rv, ri)) { runV = rv; runI = ri; }
      for (int j = 32; j > 0; j >>= 1) {
        double ov = __shfl_xor(runV, j);
        int oi = __shfl_xor(runI, j);
        bool lower = ((lane & j) == 0);
        bool mineLess = comp_less(runV, runI, ov, oi);
        bool keepMine = lower ? mineLess : !mineLess;
        if (!keepMine) { runV = ov; runI = oi; }
      }
    }
  }
  if (lane >= 44)
    idxout[((size_t)blockIdx.y * NPTS + row) * KNN + (63 - lane)] = runI;
}

// ---------------- gather-max + per-block fp64 BN partial stats ----------------
template <int NO>
__global__ __launch_bounds__(256) void gathermax_kernel(const float* __restrict__ PQ,
                                                        const int* __restrict__ idx,
                                                        float* __restrict__ hmax, int O,
                                                        double* __restrict__ pbuf) {
  __shared__ double sh1[4][256];
  __shared__ double sh2[4][256];
  int t = threadIdx.x;
  int wave = t >> 6, lane = t & 63;
  int pt = blockIdx.x * 4 + wave;
  int b = pt >> 12;
  int O2 = 2 * O;
  int iv = idx[(size_t)pt * KNN + (lane % KNN)];
  const float* Qp = PQ + (size_t)pt * O2 + O + lane * NO;
  float q[NO], mx[NO];
  double s1[NO], s2[NO];
#pragma unroll
  for (int c = 0; c < NO; ++c) {
    q[c] = Qp[c];
    mx[c] = -__builtin_inff();
    s1[c] = 0.0;
    s2[c] = 0.0;
  }
#pragma unroll
  for (int k = 0; k < KNN; ++k) {
    int m = __shfl(iv, k);
    const float* Pp = PQ + ((size_t)(b << 12) + m) * O2 + lane * NO;
    float p[NO];
#pragma unroll
    for (int c = 0; c < NO; ++c) p[c] = Pp[c];
#pragma unroll
    for (int c = 0; c < NO; ++c) {
      float h = p[c] + q[c];
      mx[c] = fmaxf(mx[c], h);
      double hd = (double)h;
      s1[c] += hd;
      s2[c] += hd * hd;
    }
  }
  float* Hp = hmax + (size_t)pt * O + lane * NO;
#pragma unroll
  for (int c = 0; c < NO; ++c) {
    Hp[c] = mx[c];
    sh1[wave][lane * NO + c] = s1[c];
    sh2[wave][lane * NO + c] = s2[c];
  }
  __syncthreads();
  if (t < O) {
    double a = 0.0, bb = 0.0;
#pragma unroll
    for (int w = 0; w < 4; ++w) {
      a += sh1[w][t];
      bb += sh2[w][t];
    }
    pbuf[(size_t)blockIdx.x * O2 + t] = a;
    pbuf[(size_t)blockIdx.x * O2 + O + t] = bb;
  }
}

// ---------------- deterministic parallel fp64 BN reduce + finalize ----------------
__global__ __launch_bounds__(256) void bn_reduce_finalize(const double* __restrict__ pbuf,
                                                          int nblk, int O,
                                                          const float* __restrict__ g,
                                                          const float* __restrict__ bb,
                                                          double invcount,
                                                          float* __restrict__ s_out,
                                                          float* __restrict__ t_out) {
  __shared__ double sh1[256];
  __shared__ double sh2[256];
  int o = blockIdx.x;
  int t = threadIdx.x;
  double s1 = 0.0, s2 = 0.0;
  for (int blk = t; blk < nblk; blk += 256) {
    s1 += pbuf[(size_t)blk * 2 * O + o];
    s2 += pbuf[(size_t)blk * 2 * O + O + o];
  }
  sh1[t] = s1;
  sh2[t] = s2;
  __syncthreads();
  for (int s = 128; s > 0; s >>= 1) {
    if (t < s) {
      sh1[t] += sh1[t + s];
      sh2[t] += sh2[t + s];
    }
    __syncthreads();
  }
  if (t == 0) {
    double mean = sh1[0] * invcount;
    double var = sh2[0] * invcount - mean * mean;
    double s = (double)g[o] / sqrt(var + BNEPS);
    s_out[o] = (float)s;
    t_out[o] = (float)((double)bb[o] - mean * s);
  }
}

// y = leaky(hmax*s+t) into feat column slice (fp32) + featbf (bf16, fused conversion)
__global__ void apply_kernel(const float* __restrict__ hmax, const float* __restrict__ s,
                             const float* __restrict__ tt, float* __restrict__ feat,
                             u16* __restrict__ featbf, int colOff, int logO, int total) {
  int i = blockIdx.x * 256 + threadIdx.x;
  if (i >= total) return;
  int O = 1 << logO;
  int o = i & (O - 1);
  int pp = i >> logO;
  float v = hmax[i] * s[o] + tt[o];
  float r = v > 0.f ? v : SLOPE * v;
  size_t di = (size_t)pp * 512 + colOff + o;
  feat[di] = r;
  unsigned xbits = __float_as_uint(r);
  unsigned rr = xbits + 0x7fff + ((xbits >> 16) & 1);
  featbf[di] = (u16)(rr >> 16);
}

// column partial stats over H (rows x 1024): pbuf[rb][2048] = [sum | sq] (fp64)
__global__ void colstats_kernel(const float* __restrict__ H, double* __restrict__ pbuf) {
  int o = blockIdx.x * 256 + threadIdx.x;
  int rb = blockIdx.y;
  int r0 = rb * 128;
  double s1 = 0.0, s2 = 0.0;
  for (int r = 0; r < 128; ++r) {
    double v = (double)H[(size_t)(r0 + r) * 1024 + o];
    s1 += v;
    s2 += v * v;
  }
  pbuf[(size_t)rb * 2048 + o] = s1;
  pbuf[(size_t)rb * 2048 + 1024 + o] = s2;
}

// out[b][o][n] = leaky(h5[b][n][o]*s+t)
__global__ void out_kernel(const float* __restrict__ h5, const float* __restrict__ s,
                           const float* __restrict__ tt, float* __restrict__ out) {
  __shared__ float tile[32][33];
  int b = blockIdx.z;
  int n0 = blockIdx.x * 32, o0 = blockIdx.y * 32;
  int t = threadIdx.x;
  for (int e = t; e < 1024; e += 256) {
    int rn = e >> 5, co = e & 31;
    int o = o0 + co;
    float v = h5[((size_t)b * NPTS + n0 + rn) * 1024 + o] * s[o] + tt[o];
    tile[rn][co] = v > 0.f ? v : SLOPE * v;
  }
  __syncthreads();
  for (int e = t; e < 1024; e += 256) {
    int ro = e >> 5, cn = e & 31;
    out[((size_t)b * 1024 + o0 + ro) * NPTS + n0 + cn] = tile[cn][ro];
  }
}

// ---------------- host ----------------
extern "C" void kernel_launch(void* const* d_in, const int* in_sizes, int n_in,
                              void* d_out, int out_size, void* d_ws, size_t ws_size,
                              hipStream_t stream) {
  const float* x = (const float*)d_in[0];
  const float* Wm[5] = {(const float*)d_in[1], (const float*)d_in[4], (const float*)d_in[7],
                        (const float*)d_in[10], (const float*)d_in[13]};
  const float* gv[5] = {(const float*)d_in[2], (const float*)d_in[5], (const float*)d_in[8],
                        (const float*)d_in[11], (const float*)d_in[14]};
  const float* bvv[5] = {(const float*)d_in[3], (const float*)d_in[6], (const float*)d_in[9],
                         (const float*)d_in[12], (const float*)d_in[15]};
  float* out = (float*)d_out;

  char* wsb = (char*)d_ws;
  size_t off = 0;
  auto alloc = [&](size_t bytes) -> char* {
    off = (off + 255) & ~(size_t)255;
    char* p = wsb + off;
    off += bytes;
    return p;
  };
  float* xb = (float*)alloc((size_t)BATCH * NPTS * 3 * 4);
  float* xxb = (float*)alloc((size_t)BATCH * NPTS * 4);
  int* idxb = (int*)alloc((size_t)BATCH * NPTS * KNN * 4);
  float* feat = (float*)alloc((size_t)BATCH * NPTS * 512 * 4);
  float* hmax = (float*)alloc((size_t)BATCH * NPTS * 256 * 4);
  float* h5 = (float*)alloc((size_t)BATCH * NPTS * 1024 * 4);
  float* PQ = h5;  // alias: PQ used per-layer, h5 only needed after
  float* U1 = (float*)alloc(3 * 128 * 4);
  float* U2 = (float*)alloc(64 * 128 * 4);
  float* U3 = (float*)alloc(64 * 256 * 4);
  float* U4 = (float*)alloc(128 * 512 * 4);
  u16* featbf = (u16*)alloc((size_t)BATCH * NPTS * 512 * 2);
  u16* w5bf = (u16*)alloc((size_t)1024 * 512 * 2);
  double* pbuf = (double*)alloc((size_t)2048 * 512 * 8);
  float* stv = (float*)alloc(3072 * 4);
  off = (off + 255) & ~(size_t)255;
  size_t avail = (ws_size > off) ? (ws_size - off) : 0;
  size_t slab = (size_t)NPTS * NPTS * 2;            // one batch's fp16 dist matrix
  int nbfit = (int)imin((int)(avail / slab), BATCH);  // 0, 1, or 2 slabs fit
  size_t rmax = avail / ((size_t)NPTS * 2);
  int R;
  if (rmax >= NPTS) R = NPTS;
  else {
    R = (int)(rmax & ~(size_t)127);
    if (R < 128) R = 128;
  }
  _Float16* distbuf = (_Float16*)(wsb + off);

  float* sv[5] = {stv + 0, stv + 128, stv + 256, stv + 512, stv + 1024};
  float* tv[5] = {stv + 64, stv + 192, stv + 384, stv + 768, stv + 2048};
  float* Us[4] = {U1, U2, U3, U4};
  const int Cs[4] = {3, 64, 64, 128};
  const int Osz[4] = {64, 64, 128, 256};
  const int ntile = (NPTS / 128) * (NPTS / 128 + 1) / 2;  // 528

  xtrans_kernel<<<(BATCH * 3 * NPTS + 255) / 256, 256, 0, stream>>>(x, xb);
  for (int l = 0; l < 4; ++l)
    uprep_kernel<<<(Cs[l] * Osz[l] + 255) / 256, 256, 0, stream>>>(Wm[l], Us[l], Osz[l], Cs[l]);
  tobf16_kernel<<<(1024 * 512 / 4 + 255) / 256, 256, 0, stream>>>(Wm[4], w5bf, 1024 * 512 / 4);

  auto knn = [&](const float* Xbase, int lda, int C) {
    xx_kernel<<<(BATCH * NPTS + 255) / 256, 256, 0, stream>>>(Xbase, lda, C, xxb);
    size_t selems = (size_t)NPTS * NPTS;
    if (nbfit >= BATCH) {
      gemm_dist_sym_kernel<<<dim3(ntile, BATCH), 256, 0, stream>>>(Xbase, lda, xxb, distbuf, C,
                                                                   selems);
      topk_fast_kernel<<<dim3(NPTS / 4, BATCH), 256, 0, stream>>>(
          distbuf, selems, Xbase, (size_t)NPTS * lda, lda, C, idxb, (size_t)NPTS * KNN, 0, NPTS);
    } else if (nbfit >= 1) {
      for (int b = 0; b < BATCH; ++b) {
        const float* Xb = Xbase + (size_t)b * NPTS * lda;
        gemm_dist_sym_kernel<<<dim3(ntile, 1), 256, 0, stream>>>(Xb, lda, xxb + (size_t)b * NPTS,
                                                                 distbuf, C, 0);
        topk_fast_kernel<<<dim3(NPTS / 4, 1), 256, 0, stream>>>(
            distbuf, 0, Xb, 0, lda, C, idxb + (size_t)b * NPTS * KNN, 0, 0, NPTS);
      }
    } else {
      for (int b = 0; b < BATCH; ++b) {
        const float* Xb = Xbase + (size_t)b * NPTS * lda;
        for (int n0 = 0; n0 < NPTS; n0 += R) {
          int rows = imin(R, NPTS - n0);
          gemm128<true, true><<<dim3(NPTS / 128, rows / 128), 256, 0, stream>>>(
              Xb + (size_t)n0 * lda, lda, Xb, lda, (void*)distbuf, NPTS, C,
              xxb + (size_t)b * NPTS + n0, xxb + (size_t)b * NPTS);
          topk_fast_kernel<<<dim3(rows / 4, 1), 256, 0, stream>>>(
              distbuf, 0, Xb, 0, lda, C, idxb + (size_t)b * NPTS * KNN, 0, n0, rows);
        }
      }
    }
  };

  auto edge = [&](int li, const float* Xbase, int lda, int C, int O, int colOff) {
    if (li == 0) {
      dist3_topk_kernel<<<dim3(NPTS / 4, BATCH), 256, 0, stream>>>(Xbase, idxb);
    } else {
      knn(Xbase, lda, C);
    }
    int O2 = 2 * O;
    gemm128<false, false><<<dim3(O2 / 128, BATCH * NPTS / 128), 256, 0, stream>>>(
        Xbase, lda, Us[li], O2, (void*)PQ, O2, C, nullptr, nullptr);
    int nblk = BATCH * NPTS / 4;
    if (O == 64)
      gathermax_kernel<1><<<nblk, 256, 0, stream>>>(PQ, idxb, hmax, O, pbuf);
    else if (O == 128)
      gathermax_kernel<2><<<nblk, 256, 0, stream>>>(PQ, idxb, hmax, O, pbuf);
    else
      gathermax_kernel<4><<<nblk, 256, 0, stream>>>(PQ, idxb, hmax, O, pbuf);
    bn_reduce_finalize<<<O, 256, 0, stream>>>(pbuf, nblk, O, gv[li], bvv[li],
                                              1.0 / ((double)BATCH * NPTS * KNN), sv[li], tv[li]);
    int logO = (O == 64) ? 6 : (O == 128) ? 7 : 8;
    int total = BATCH * NPTS * O;
    apply_kernel<<<(total + 255) / 256, 256, 0, stream>>>(hmax, sv[li], tv[li], feat, featbf,
                                                          colOff, logO, total);
  };

  edge(0, xb, 3, 3, 64, 0);
  edge(1, feat, 512, 64, 64, 64);
  edge(2, feat + 64, 512, 64, 128, 128);
  edge(3, feat + 128, 512, 128, 256, 256);

  fc_mfma_kernel<<<dim3(1024 / 128, BATCH * NPTS / 128), 256, 0, stream>>>(featbf, w5bf, h5);
  colstats_kernel<<<dim3(4, 64), 256, 0, stream>>>(h5, pbuf);
  bn_reduce_finalize<<<1024, 256, 0, stream>>>(pbuf, 64, 1024, gv[4], bvv[4],
                                               1.0 / ((double)BATCH * NPTS), sv[4], tv[4]);
  out_kernel<<<dim3(NPTS / 32, 1024 / 32, BATCH), 256, 0, stream>>>(h5, sv[4], tv[4], out);
}

// Round 15
// 602.368 us; speedup vs baseline: 1.8123x; 1.0676x over previous
//
#include <hip/hip_runtime.h>
#include <cmath>

#define KNN 20
#define NPTS 4096
#define BATCH 2
#define SLOPE 0.2f
#define BNEPS 1e-5
#define GTK 16
#define MAXCAND 256

typedef unsigned short u16;
typedef __attribute__((ext_vector_type(8))) short bf16x8;
typedef __attribute__((ext_vector_type(4))) float f32x4;
typedef _Float16 h8 __attribute__((ext_vector_type(8)));
typedef _Float16 h4 __attribute__((ext_vector_type(4)));

static __device__ __host__ inline int imin(int a, int b) { return a < b ? a : b; }

__device__ inline u16 f2bf(float v) {
  unsigned x = __float_as_uint(v);
  unsigned rr = x + 0x7fff + ((x >> 16) & 1);
  return (u16)(rr >> 16);
}

// ---------------- utility kernels ----------------
// x (B,3,N) -> xb (B,N,3)
__global__ void xtrans_kernel(const float* __restrict__ x, float* __restrict__ xb) {
  int i = blockIdx.x * 256 + threadIdx.x;
  if (i < BATCH * 3 * NPTS) {
    int b = i / (3 * NPTS);
    int r = i - b * 3 * NPTS;
    int c = r / NPTS;
    int n = r - c * NPTS;
    xb[((size_t)b * NPTS + n) * 3 + c] = x[i];
  }
}

// W (O, 2C) -> U (C, 2O): U[j][o]=W[o][j]; U[j][O+o]=W[o][C+j]-W[o][j]
__global__ void uprep_kernel(const float* __restrict__ W, float* __restrict__ U, int O, int C) {
  int i = blockIdx.x * 256 + threadIdx.x;
  if (i < C * O) {
    int j = i / O, o = i - j * O;
    float w1 = W[(size_t)o * 2 * C + j];
    float w2 = W[(size_t)o * 2 * C + C + j];
    U[(size_t)j * 2 * O + o] = w1;
    U[(size_t)j * 2 * O + O + o] = w2 - w1;
  }
}

// squared norms per point (fp64 accumulate, fp32 store — candidate pass only)
__global__ void xx_kernel(const float* __restrict__ X, int stride, int C, float* __restrict__ xx) {
  int i = blockIdx.x * 256 + threadIdx.x;
  if (i < BATCH * NPTS) {
    const float* r = X + (size_t)i * stride;
    double s = 0.0;
    for (int c = 0; c < C; ++c) s += (double)r[c] * (double)r[c];
    xx[i] = (float)s;
  }
}

// fp32 -> bf16 (RNE), 4 elements/thread
__global__ void tobf16_kernel(const float* __restrict__ src, u16* __restrict__ dst, int n4) {
  int i = blockIdx.x * 256 + threadIdx.x;
  if (i < n4) {
    float4 v = *(const float4*)&src[(size_t)i * 4];
    unsigned o[4];
#pragma unroll
    for (int j = 0; j < 4; ++j) o[j] = f2bf(((const float*)&v)[j]);
    uint2 pk;
    pk.x = o[0] | (o[1] << 16);
    pk.y = o[2] | (o[3] << 16);
    *(uint2*)&dst[(size_t)i * 4] = pk;
  }
}

// fp32 X (row-major, lda) -> split hi/lo bf16 (row-major, C), 4 cols/thread
__global__ void tosplit_kernel(const float* __restrict__ X, int lda, int C,
                               u16* __restrict__ hi, u16* __restrict__ lo, int ngroups) {
  int g = blockIdx.x * 256 + threadIdx.x;
  if (g >= ngroups) return;
  int perRow = C >> 2;
  int r = g / perRow;
  int cq = (g - r * perRow) * 4;
  float4 v = *(const float4*)&X[(size_t)r * lda + cq];
  unsigned ho[4], lo_[4];
#pragma unroll
  for (int j = 0; j < 4; ++j) {
    float f = ((const float*)&v)[j];
    u16 h = f2bf(f);
    float hv = __uint_as_float(((unsigned)h) << 16);
    ho[j] = h;
    lo_[j] = f2bf(f - hv);
  }
  uint2 ph, pl;
  ph.x = ho[0] | (ho[1] << 16);
  ph.y = ho[2] | (ho[3] << 16);
  pl.x = lo_[0] | (lo_[1] << 16);
  pl.y = lo_[2] | (lo_[3] << 16);
  size_t di = (size_t)r * C + cq;
  *(uint2*)&hi[di] = ph;
  *(uint2*)&lo[di] = pl;
}

// ---------------- generic 128x128 fp32 GEMM, 8x8 micro (single-buffered) ----------------
// C[M x N] = A[M x K] * (BT ? B[N x K]^T : B[K x N]); DIST epilogue writes fp16.
template <bool BT, bool DIST>
__global__ __launch_bounds__(256) void gemm128(const float* __restrict__ A, int lda,
                                               const float* __restrict__ B, int ldb,
                                               void* __restrict__ Cout, int ldc, int K,
                                               const float* __restrict__ xxA,
                                               const float* __restrict__ xxB) {
  __shared__ __align__(16) float sA[GTK][144];
  __shared__ __align__(16) float sB[GTK][144];
  int t = threadIdx.x;
  int tx = t & 15, ty = t >> 4;
  int row0 = blockIdx.y * 128, col0 = blockIdx.x * 128;
  float acc[8][8] = {};

  for (int k0 = 0; k0 < K; k0 += GTK) {
    bool fast = (k0 + GTK <= K);
    if (fast) {
#pragma unroll
      for (int it = 0; it < 2; ++it) {
        int i = t + it * 256;
        int r = i >> 2, q = i & 3;
        const float4 av = *(const float4*)&A[(size_t)(row0 + r) * lda + k0 + q * 4];
        int pr = r + ((r >> 5) << 2);
        sA[q * 4 + 0][pr] = av.x;
        sA[q * 4 + 1][pr] = av.y;
        sA[q * 4 + 2][pr] = av.z;
        sA[q * 4 + 3][pr] = av.w;
      }
    } else {
#pragma unroll
      for (int it = 0; it < 2; ++it) {
        int i = t + it * 256;
        int r = i >> 2, q = i & 3;
        int pr = r + ((r >> 5) << 2);
#pragma unroll
        for (int j = 0; j < 4; ++j) {
          int k = q * 4 + j;
          sA[k][pr] = (k0 + k < K) ? A[(size_t)(row0 + r) * lda + k0 + k] : 0.f;
        }
      }
    }
    if (BT) {
      if (fast) {
#pragma unroll
        for (int it = 0; it < 2; ++it) {
          int i = t + it * 256;
          int r = i >> 2, q = i & 3;
          const float4 bv = *(const float4*)&B[(size_t)(col0 + r) * ldb + k0 + q * 4];
          int pr = r + ((r >> 5) << 2);
          sB[q * 4 + 0][pr] = bv.x;
          sB[q * 4 + 1][pr] = bv.y;
          sB[q * 4 + 2][pr] = bv.z;
          sB[q * 4 + 3][pr] = bv.w;
        }
      } else {
#pragma unroll
        for (int it = 0; it < 2; ++it) {
          int i = t + it * 256;
          int r = i >> 2, q = i & 3;
          int pr = r + ((r >> 5) << 2);
#pragma unroll
          for (int j = 0; j < 4; ++j) {
            int k = q * 4 + j;
            sB[k][pr] = (k0 + k < K) ? B[(size_t)(col0 + r) * ldb + k0 + k] : 0.f;
          }
        }
      }
    } else {
#pragma unroll
      for (int it = 0; it < 2; ++it) {
        int i = t + it * 256;
        int k = i >> 5, nq = (i & 31) * 4;
        int pc = nq + ((nq >> 5) << 2);
        float4 bv = make_float4(0.f, 0.f, 0.f, 0.f);
        if (k0 + k < K) bv = *(const float4*)&B[(size_t)(k0 + k) * ldb + col0 + nq];
        *(float4*)&sB[k][pc] = bv;
      }
    }
    __syncthreads();
    int prA = ty * 8 + ((ty >> 2) << 2);
    int prB = tx * 8 + ((tx >> 2) << 2);
#pragma unroll
    for (int kk = 0; kk < GTK; ++kk) {
      float a[8], b[8];
      *(float4*)&a[0] = *(const float4*)&sA[kk][prA];
      *(float4*)&a[4] = *(const float4*)&sA[kk][prA + 4];
      *(float4*)&b[0] = *(const float4*)&sB[kk][prB];
      *(float4*)&b[4] = *(const float4*)&sB[kk][prB + 4];
#pragma unroll
      for (int i = 0; i < 8; ++i)
#pragma unroll
        for (int j = 0; j < 8; ++j) acc[i][j] += a[i] * b[j];
    }
    __syncthreads();
  }

  if (DIST) {
    _Float16* Ch = (_Float16*)Cout;
#pragma unroll
    for (int i = 0; i < 8; ++i) {
      int gr = row0 + ty * 8 + i;
      float xa = xxA[gr];
      h8 o;
#pragma unroll
      for (int j = 0; j < 8; ++j) {
        int gc = col0 + tx * 8 + j;
        o[j] = (_Float16)(2.f * acc[i][j] - xa - xxB[gc]);
      }
      *(h8*)&Ch[(size_t)gr * ldc + col0 + tx * 8] = o;
    }
  } else {
    float* Cf = (float*)Cout;
#pragma unroll
    for (int i = 0; i < 8; ++i) {
      int gr = row0 + ty * 8 + i;
#pragma unroll
      for (int jq = 0; jq < 2; ++jq) {
        float4 o;
#pragma unroll
        for (int j = 0; j < 4; ++j) ((float*)&o)[j] = acc[i][jq * 4 + j];
        *(float4*)&Cf[(size_t)gr * ldc + col0 + tx * 8 + jq * 4] = o;
      }
    }
  }
}

// ---------------- split-bf16 MFMA symmetric dist: lower-triangle tiles, mirrored write ----
// <x,y> = hi.hi + hi.lo + lo.hi (3 chained bf16 MFMAs, fp32 acc; lo.lo term ~2^-16 dropped).
// Epilogue: fp16 tile in LDS (rows padded to 136 u16), coalesced h8 writes both orientations.
// grid (ntile, nbatch). Fragment maps identical to fc_mfma (m89-verified).
// LDS layout: 4 slabs of 5120 u16 at offsets a*5120 (Ahi, Alo, Bhi, Blo), rows of 40 u16.
__global__ __launch_bounds__(256) void dist_sym_mfma_kernel(const u16* __restrict__ Xhi,
                                                            const u16* __restrict__ Xlo, int K,
                                                            const float* __restrict__ xx,
                                                            _Float16* __restrict__ dist,
                                                            size_t dstride) {
  __shared__ __align__(16) u16 smem[20544];  // staging 4x128x40 (40960 B) / tile 128x136 (34816 B)
  int t = threadIdx.x;
  int lane = t & 63, wave = t >> 6;
  const u16* xh = Xhi + (size_t)blockIdx.y * NPTS * K;
  const u16* xl = Xlo + (size_t)blockIdx.y * NPTS * K;
  const float* xxv = xx + (size_t)blockIdx.y * NPTS;
  _Float16* db = dist + (size_t)blockIdx.y * dstride;
  int l = blockIdx.x;
  int bi = (int)((sqrtf(8.f * (float)l + 1.f) - 1.f) * 0.5f);
  while ((bi + 1) * (bi + 2) / 2 <= l) ++bi;
  while (bi * (bi + 1) / 2 > l) --bi;
  int bj = l - bi * (bi + 1) / 2;
  int row0 = bi * 128, col0 = bj * 128;
  int wr = (wave >> 1) * 64, wc = (wave & 1) * 64;
  int m = lane & 15, q = lane >> 4;
  f32x4 acc[4][4];
#pragma unroll
  for (int i = 0; i < 4; ++i)
#pragma unroll
    for (int j = 0; j < 4; ++j) acc[i][j] = (f32x4){0.f, 0.f, 0.f, 0.f};

  for (int k0 = 0; k0 < K; k0 += 32) {
#pragma unroll
    for (int it = 0; it < 8; ++it) {
      int e = t + it * 256;
      int a = e >> 9, idx = e & 511;
      int r = idx >> 2, qq = idx & 3;
      const u16* src = (a == 0 || a == 2) ? xh : xl;
      int base = (a < 2) ? row0 : col0;
      *(uint4*)&smem[a * 5120 + r * 40 + qq * 8] =
          *(const uint4*)&src[(size_t)(base + r) * K + k0 + qq * 8];
    }
    __syncthreads();
    bf16x8 ah[4], al[4], bh[4], bl[4];
#pragma unroll
    for (int i = 0; i < 4; ++i) {
      ah[i] = *(const bf16x8*)&smem[0 * 5120 + (wr + i * 16 + m) * 40 + q * 8];
      al[i] = *(const bf16x8*)&smem[1 * 5120 + (wr + i * 16 + m) * 40 + q * 8];
    }
#pragma unroll
    for (int j = 0; j < 4; ++j) {
      bh[j] = *(const bf16x8*)&smem[2 * 5120 + (wc + j * 16 + m) * 40 + q * 8];
      bl[j] = *(const bf16x8*)&smem[3 * 5120 + (wc + j * 16 + m) * 40 + q * 8];
    }
#pragma unroll
    for (int i = 0; i < 4; ++i)
#pragma unroll
      for (int j = 0; j < 4; ++j) {
        acc[i][j] = __builtin_amdgcn_mfma_f32_16x16x32_bf16(ah[i], bh[j], acc[i][j], 0, 0, 0);
        acc[i][j] = __builtin_amdgcn_mfma_f32_16x16x32_bf16(ah[i], bl[j], acc[i][j], 0, 0, 0);
        acc[i][j] = __builtin_amdgcn_mfma_f32_16x16x32_bf16(al[i], bh[j], acc[i][j], 0, 0, 0);
      }
    __syncthreads();
  }

  // DIST transform -> fp16 LDS tile (reuses staging smem; all reads drained by loop-end sync)
  _Float16* tile = (_Float16*)smem;
  {
    float xbv[4];
#pragma unroll
    for (int j = 0; j < 4; ++j) xbv[j] = xxv[col0 + wc + j * 16 + m];
#pragma unroll
    for (int i = 0; i < 4; ++i)
#pragma unroll
      for (int reg = 0; reg < 4; ++reg) {
        int r = wr + i * 16 + q * 4 + reg;
        float xa = xxv[row0 + r];
#pragma unroll
        for (int j = 0; j < 4; ++j)
          tile[r * 136 + wc + j * 16 + m] = (_Float16)(2.f * acc[i][j][reg] - xa - xbv[j]);
      }
  }
  __syncthreads();
  // direct tile (row0, col0): coalesced h8 per 8-col segment
  for (int e = t; e < 2048; e += 256) {
    int r = e >> 4, seg = e & 15;
    *(h8*)&db[(size_t)(row0 + r) * NPTS + col0 + seg * 8] = *(const h8*)&tile[r * 136 + seg * 8];
  }
  // mirrored tile (col0, row0): transposed LDS reads, coalesced global h8 writes
  if (bi != bj) {
    for (int e = t; e < 2048; e += 256) {
      int c = e >> 4, seg = e & 15;
      h8 o;
#pragma unroll
      for (int i = 0; i < 8; ++i) o[i] = tile[(seg * 8 + i) * 136 + c];
      *(h8*)&db[(size_t)(col0 + c) * NPTS + row0 + seg * 8] = o;
    }
  }
}

// ---------------- bf16 MFMA FC: C[8192x1024] = A[8192x512] * B[1024x512]^T ----------------
__global__ __launch_bounds__(256) void fc_mfma_kernel(const u16* __restrict__ A,
                                                      const u16* __restrict__ B,
                                                      float* __restrict__ C) {
  __shared__ u16 sA[128][56];
  __shared__ u16 sB[128][56];
  int t = threadIdx.x;
  int lane = t & 63, wave = t >> 6;
  int row0 = blockIdx.y * 128, col0 = blockIdx.x * 128;
  int wr = (wave >> 1) * 64, wc = (wave & 1) * 64;
  int m = lane & 15, q = lane >> 4;
  f32x4 acc[4][4];
#pragma unroll
  for (int i = 0; i < 4; ++i)
#pragma unroll
    for (int j = 0; j < 4; ++j) acc[i][j] = (f32x4){0.f, 0.f, 0.f, 0.f};
  for (int k0 = 0; k0 < 512; k0 += 32) {
#pragma unroll
    for (int it = 0; it < 2; ++it) {
      int i = t + it * 256;
      int r = i >> 2, ch = (i & 3) * 8;
      *(uint4*)&sA[r][ch] = *(const uint4*)&A[(size_t)(row0 + r) * 512 + k0 + ch];
      *(uint4*)&sB[r][ch] = *(const uint4*)&B[(size_t)(col0 + r) * 512 + k0 + ch];
    }
    __syncthreads();
    bf16x8 af[4], bf[4];
#pragma unroll
    for (int i = 0; i < 4; ++i) af[i] = *(const bf16x8*)&sA[wr + i * 16 + m][q * 8];
#pragma unroll
    for (int j = 0; j < 4; ++j) bf[j] = *(const bf16x8*)&sB[wc + j * 16 + m][q * 8];
#pragma unroll
    for (int i = 0; i < 4; ++i)
#pragma unroll
      for (int j = 0; j < 4; ++j)
        acc[i][j] = __builtin_amdgcn_mfma_f32_16x16x32_bf16(af[i], bf[j], acc[i][j], 0, 0, 0);
    __syncthreads();
  }
#pragma unroll
  for (int i = 0; i < 4; ++i)
#pragma unroll
    for (int j = 0; j < 4; ++j)
#pragma unroll
      for (int reg = 0; reg < 4; ++reg)
        C[(size_t)(row0 + wr + i * 16 + q * 4 + reg) * 1024 + col0 + wc + j * 16 + m] =
            acc[i][j][reg];
}

// ---------------- shared top-k selection helpers ----------------
__device__ inline bool comp_less(double v, int i, double ov, int oi) {
  return (v < ov) || (v == ov && i > oi);
}

// ---------------- fast top-k: threshold filter (fp16 dist) + fp64 rescore + bitonic sort ---
__global__ __launch_bounds__(256) void topk_fast_kernel(const _Float16* __restrict__ dist,
                                                        size_t dstride,
                                                        const float* __restrict__ Xb,
                                                        size_t xstride, int lda, int C,
                                                        int* __restrict__ idxout, size_t istride,
                                                        int n0, int rows) {
  __shared__ int scand[4][MAXCAND];
  int wave = threadIdx.x >> 6, lane = threadIdx.x & 63;
  int row = blockIdx.x * 4 + wave;
  if (row >= rows) return;
  const _Float16* distb = dist + (size_t)blockIdx.y * dstride;
  const float* Xbb = Xb + (size_t)blockIdx.y * xstride;
  int* idxb = idxout + (size_t)blockIdx.y * istride;
  const _Float16* d = distb + (size_t)row * NPTS;
  float v[16][4];
  float lmax = -__builtin_inff();
#pragma unroll
  for (int s = 0; s < 16; ++s) {
    h4 hv = *(const h4*)&d[s * 256 + lane * 4];
#pragma unroll
    for (int c = 0; c < 4; ++c) {
      v[s][c] = (float)hv[c];
      lmax = fmaxf(lmax, v[s][c]);
    }
  }

  float sv = lmax;
  for (int k = 2; k <= 64; k <<= 1) {
    for (int j = k >> 1; j > 0; j >>= 1) {
      float ov = __shfl_xor(sv, j);
      bool up = ((lane & k) == 0);
      bool lower = ((lane & j) == 0);
      bool mineLess = sv < ov;
      bool keepMine = (up == lower) ? mineLess : !mineLess;
      sv = keepMine ? sv : ov;
    }
  }
  float T = __shfl(sv, 44);

  int myCnt = 0;
#pragma unroll
  for (int s = 0; s < 16; ++s)
#pragma unroll
    for (int c = 0; c < 4; ++c) myCnt += (v[s][c] >= T) ? 1 : 0;
  int ofs = myCnt;
  for (int dlt = 1; dlt < 64; dlt <<= 1) {
    int o = __shfl_up(ofs, dlt);
    if (lane >= dlt) ofs += o;
  }
  int total = __shfl(ofs, 63);
  ofs -= myCnt;
  int w = ofs;
#pragma unroll
  for (int s = 0; s < 16; ++s)
#pragma unroll
    for (int c = 0; c < 4; ++c) {
      if (v[s][c] >= T) {
        if (w < MAXCAND) scand[wave][w] = s * 256 + lane * 4 + c;
        ++w;
      }
    }
  int cnt = imin(total, MAXCAND);
  int gn = n0 + row;
  const float* crow = Xbb + (size_t)gn * lda;
  int nch = (cnt + 63) >> 6;

  double runV = -__builtin_inf();
  int runI = 0x7fffffff;
  for (int ch = 0; ch < nch; ++ch) {
    int slot = ch * 64 + lane;
    int m = (slot < cnt) ? scand[wave][slot] : -1;
    double val = -__builtin_inf();
    int vi = 0x7fffffff;
    if (m >= 0) {
      const float* mrow = Xbb + (size_t)m * lda;
      double dd = 0.0;
      for (int c = 0; c < C; c += 4) {
        float4 a = *(const float4*)&crow[c];
        float4 b = *(const float4*)&mrow[c];
#pragma unroll
        for (int qq = 0; qq < 4; ++qq) {
          double df = (double)((const float*)&a)[qq] - (double)((const float*)&b)[qq];
          dd = fma(df, df, dd);
        }
      }
      val = -dd;
      vi = m;
    }
    for (int k = 2; k <= 64; k <<= 1) {
      for (int j = k >> 1; j > 0; j >>= 1) {
        double ov = __shfl_xor(val, j);
        int oi = __shfl_xor(vi, j);
        bool up = ((lane & k) == 0);
        bool lower = ((lane & j) == 0);
        bool mineLess = comp_less(val, vi, ov, oi);
        bool keepMine = (up == lower) ? mineLess : !mineLess;
        if (!keepMine) { val = ov; vi = oi; }
      }
    }
    if (ch == 0) {
      runV = val;
      runI = vi;
    } else {
      double rv = __shfl(val, 63 - lane);
      int ri = __shfl(vi, 63 - lane);
      if (comp_less(runV, runI, rv, ri)) { runV = rv; runI = ri; }
      for (int j = 32; j > 0; j >>= 1) {
        double ov = __shfl_xor(runV, j);
        int oi = __shfl_xor(runI, j);
        bool lower = ((lane & j) == 0);
        bool mineLess = comp_less(runV, runI, ov, oi);
        bool keepMine = lower ? mineLess : !mineLess;
        if (!keepMine) { runV = ov; runI = oi; }
      }
    }
  }
  if (lane >= 44) idxb[(size_t)gn * KNN + (63 - lane)] = runI;
}

// ---------------- fused layer-1 kNN (C=3): whole point set in LDS ----------------
__global__ __launch_bounds__(256) void dist3_topk_kernel(const float* __restrict__ Xb,
                                                         int* __restrict__ idxout) {
  __shared__ float xs[NPTS], ys[NPTS], zs[NPTS];
  __shared__ int scand[4][MAXCAND];
  int t = threadIdx.x;
  const float* Xbb = Xb + (size_t)blockIdx.y * NPTS * 3;
  for (int i = t; i < NPTS * 3; i += 256) {
    int n = i / 3, c = i - n * 3;
    float v = Xbb[i];
    if (c == 0) xs[n] = v;
    else if (c == 1) ys[n] = v;
    else zs[n] = v;
  }
  __syncthreads();
  int wave = t >> 6, lane = t & 63;
  int row = blockIdx.x * 4 + wave;
  float cx = xs[row], cy = ys[row], cz = zs[row];
  float v[16][4];
  float lmax = -__builtin_inff();
#pragma unroll
  for (int s = 0; s < 16; ++s)
#pragma unroll
    for (int c = 0; c < 4; ++c) {
      int m = s * 256 + c * 64 + lane;
      float dx = cx - xs[m], dy = cy - ys[m], dz = cz - zs[m];
      float dv = -(dx * dx + dy * dy + dz * dz);
      v[s][c] = dv;
      lmax = fmaxf(lmax, dv);
    }

  float sv = lmax;
  for (int k = 2; k <= 64; k <<= 1) {
    for (int j = k >> 1; j > 0; j >>= 1) {
      float ov = __shfl_xor(sv, j);
      bool up = ((lane & k) == 0);
      bool lower = ((lane & j) == 0);
      bool mineLess = sv < ov;
      bool keepMine = (up == lower) ? mineLess : !mineLess;
      sv = keepMine ? sv : ov;
    }
  }
  float T = __shfl(sv, 44);

  int myCnt = 0;
#pragma unroll
  for (int s = 0; s < 16; ++s)
#pragma unroll
    for (int c = 0; c < 4; ++c) myCnt += (v[s][c] >= T) ? 1 : 0;
  int ofs = myCnt;
  for (int dlt = 1; dlt < 64; dlt <<= 1) {
    int o = __shfl_up(ofs, dlt);
    if (lane >= dlt) ofs += o;
  }
  int total = __shfl(ofs, 63);
  ofs -= myCnt;
  int w = ofs;
#pragma unroll
  for (int s = 0; s < 16; ++s)
#pragma unroll
    for (int c = 0; c < 4; ++c) {
      if (v[s][c] >= T) {
        if (w < MAXCAND) scand[wave][w] = s * 256 + c * 64 + lane;
        ++w;
      }
    }
  int cnt = imin(total, MAXCAND);
  int nch = (cnt + 63) >> 6;

  double runV = -__builtin_inf();
  int runI = 0x7fffffff;
  for (int ch = 0; ch < nch; ++ch) {
    int slot = ch * 64 + lane;
    int m = (slot < cnt) ? scand[wave][slot] : -1;
    double val = -__builtin_inf();
    int vi = 0x7fffffff;
    if (m >= 0) {
      double dx = (double)cx - (double)xs[m];
      double dy = (double)cy - (double)ys[m];
      double dz = (double)cz - (double)zs[m];
      val = -(dx * dx + dy * dy + dz * dz);
      vi = m;
    }
    for (int k = 2; k <= 64; k <<= 1) {
      for (int j = k >> 1; j > 0; j >>= 1) {
        double ov = __shfl_xor(val, j);
        int oi = __shfl_xor(vi, j);
        bool up = ((lane & k) == 0);
        bool lower = ((lane & j) == 0);
        bool mineLess = comp_less(val, vi, ov, oi);
        bool keepMine = (up == lower) ? mineLess : !mineLess;
        if (!keepMine) { val = ov; vi = oi; }
      }
    }
    if (ch == 0) {
      runV = val;
      runI = vi;
    } else {
      double rv = __shfl(val, 63 - lane);
      int ri = __shfl(vi, 63 - lane);
      if (comp_less(runV, runI, rv, ri)) { runV = rv; runI = ri; }
      for (int j = 32; j > 0; j >>= 1) {
        double ov = __shfl_xor(runV, j);
        int oi = __shfl_xor(runI, j);
        bool lower = ((lane & j) == 0);
        bool mineLess = comp_less(runV, runI, ov, oi);
        bool keepMine = lower ? mineLess : !mineLess;
        if (!keepMine) { runV = ov; runI = oi; }
      }
    }
  }
  if (lane >= 44)
    idxout[((size_t)blockIdx.y * NPTS + row) * KNN + (63 - lane)] = runI;
}

// ---------------- gather-max + per-block fp64 BN partial stats ----------------
template <int NO>
__global__ __launch_bounds__(256) void gathermax_kernel(const float* __restrict__ PQ,
                                                        const int* __restrict__ idx,
                                                        float* __restrict__ hmax, int O,
                                                        double* __restrict__ pbuf) {
  __shared__ double sh1[4][256];
  __shared__ double sh2[4][256];
  int t = threadIdx.x;
  int wave = t >> 6, lane = t & 63;
  int pt = blockIdx.x * 4 + wave;
  int b = pt >> 12;
  int O2 = 2 * O;
  int iv = idx[(size_t)pt * KNN + (lane % KNN)];
  const float* Qp = PQ + (size_t)pt * O2 + O + lane * NO;
  float q[NO], mx[NO];
  double s1[NO], s2[NO];
#pragma unroll
  for (int c = 0; c < NO; ++c) {
    q[c] = Qp[c];
    mx[c] = -__builtin_inff();
    s1[c] = 0.0;
    s2[c] = 0.0;
  }
#pragma unroll
  for (int k = 0; k < KNN; ++k) {
    int m = __shfl(iv, k);
    const float* Pp = PQ + ((size_t)(b << 12) + m) * O2 + lane * NO;
    float p[NO];
#pragma unroll
    for (int c = 0; c < NO; ++c) p[c] = Pp[c];
#pragma unroll
    for (int c = 0; c < NO; ++c) {
      float h = p[c] + q[c];
      mx[c] = fmaxf(mx[c], h);
      double hd = (double)h;
      s1[c] += hd;
      s2[c] += hd * hd;
    }
  }
  float* Hp = hmax + (size_t)pt * O + lane * NO;
#pragma unroll
  for (int c = 0; c < NO; ++c) {
    Hp[c] = mx[c];
    sh1[wave][lane * NO + c] = s1[c];
    sh2[wave][lane * NO + c] = s2[c];
  }
  __syncthreads();
  if (t < O) {
    double a = 0.0, bb = 0.0;
#pragma unroll
    for (int w = 0; w < 4; ++w) {
      a += sh1[w][t];
      bb += sh2[w][t];
    }
    pbuf[(size_t)blockIdx.x * O2 + t] = a;
    pbuf[(size_t)blockIdx.x * O2 + O + t] = bb;
  }
}

// ---------------- deterministic parallel fp64 BN reduce + finalize ----------------
__global__ __launch_bounds__(256) void bn_reduce_finalize(const double* __restrict__ pbuf,
                                                          int nblk, int O,
                                                          const float* __restrict__ g,
                                                          const float* __restrict__ bb,
                                                          double invcount,
                                                          float* __restrict__ s_out,
                                                          float* __restrict__ t_out) {
  __shared__ double sh1[256];
  __shared__ double sh2[256];
  int o = blockIdx.x;
  int t = threadIdx.x;
  double s1 = 0.0, s2 = 0.0;
  for (int blk = t; blk < nblk; blk += 256) {
    s1 += pbuf[(size_t)blk * 2 * O + o];
    s2 += pbuf[(size_t)blk * 2 * O + O + o];
  }
  sh1[t] = s1;
  sh2[t] = s2;
  __syncthreads();
  for (int s = 128; s > 0; s >>= 1) {
    if (t < s) {
      sh1[t] += sh1[t + s];
      sh2[t] += sh2[t + s];
    }
    __syncthreads();
  }
  if (t == 0) {
    double mean = sh1[0] * invcount;
    double var = sh2[0] * invcount - mean * mean;
    double s = (double)g[o] / sqrt(var + BNEPS);
    s_out[o] = (float)s;
    t_out[o] = (float)((double)bb[o] - mean * s);
  }
}

// y = leaky(hmax*s+t) into feat column slice (fp32) + featbf (bf16, fused conversion)
__global__ void apply_kernel(const float* __restrict__ hmax, const float* __restrict__ s,
                             const float* __restrict__ tt, float* __restrict__ feat,
                             u16* __restrict__ featbf, int colOff, int logO, int total) {
  int i = blockIdx.x * 256 + threadIdx.x;
  if (i >= total) return;
  int O = 1 << logO;
  int o = i & (O - 1);
  int pp = i >> logO;
  float v = hmax[i] * s[o] + tt[o];
  float r = v > 0.f ? v : SLOPE * v;
  size_t di = (size_t)pp * 512 + colOff + o;
  feat[di] = r;
  featbf[di] = f2bf(r);
}

// column partial stats over H (rows x 1024): pbuf[rb][2048] = [sum | sq] (fp64)
__global__ void colstats_kernel(const float* __restrict__ H, double* __restrict__ pbuf) {
  int o = blockIdx.x * 256 + threadIdx.x;
  int rb = blockIdx.y;
  int r0 = rb * 128;
  double s1 = 0.0, s2 = 0.0;
  for (int r = 0; r < 128; ++r) {
    double v = (double)H[(size_t)(r0 + r) * 1024 + o];
    s1 += v;
    s2 += v * v;
  }
  pbuf[(size_t)rb * 2048 + o] = s1;
  pbuf[(size_t)rb * 2048 + 1024 + o] = s2;
}

// out[b][o][n] = leaky(h5[b][n][o]*s+t)
__global__ void out_kernel(const float* __restrict__ h5, const float* __restrict__ s,
                           const float* __restrict__ tt, float* __restrict__ out) {
  __shared__ float tile[32][33];
  int b = blockIdx.z;
  int n0 = blockIdx.x * 32, o0 = blockIdx.y * 32;
  int t = threadIdx.x;
  for (int e = t; e < 1024; e += 256) {
    int rn = e >> 5, co = e & 31;
    int o = o0 + co;
    float v = h5[((size_t)b * NPTS + n0 + rn) * 1024 + o] * s[o] + tt[o];
    tile[rn][co] = v > 0.f ? v : SLOPE * v;
  }
  __syncthreads();
  for (int e = t; e < 1024; e += 256) {
    int ro = e >> 5, cn = e & 31;
    out[((size_t)b * 1024 + o0 + ro) * NPTS + n0 + cn] = tile[cn][ro];
  }
}

// ---------------- host ----------------
extern "C" void kernel_launch(void* const* d_in, const int* in_sizes, int n_in,
                              void* d_out, int out_size, void* d_ws, size_t ws_size,
                              hipStream_t stream) {
  const float* x = (const float*)d_in[0];
  const float* Wm[5] = {(const float*)d_in[1], (const float*)d_in[4], (const float*)d_in[7],
                        (const float*)d_in[10], (const float*)d_in[13]};
  const float* gv[5] = {(const float*)d_in[2], (const float*)d_in[5], (const float*)d_in[8],
                        (const float*)d_in[11], (const float*)d_in[14]};
  const float* bvv[5] = {(const float*)d_in[3], (const float*)d_in[6], (const float*)d_in[9],
                         (const float*)d_in[12], (const float*)d_in[15]};
  float* out = (float*)d_out;

  char* wsb = (char*)d_ws;
  size_t off = 0;
  auto alloc = [&](size_t bytes) -> char* {
    off = (off + 255) & ~(size_t)255;
    char* p = wsb + off;
    off += bytes;
    return p;
  };
  float* xb = (float*)alloc((size_t)BATCH * NPTS * 3 * 4);
  float* xxb = (float*)alloc((size_t)BATCH * NPTS * 4);
  int* idxb = (int*)alloc((size_t)BATCH * NPTS * KNN * 4);
  float* feat = (float*)alloc((size_t)BATCH * NPTS * 512 * 4);
  float* hmax = (float*)alloc((size_t)BATCH * NPTS * 256 * 4);
  float* h5 = (float*)alloc((size_t)BATCH * NPTS * 1024 * 4);
  float* PQ = h5;  // alias: PQ used per-layer, h5 only needed after
  float* U1 = (float*)alloc(3 * 128 * 4);
  float* U2 = (float*)alloc(64 * 128 * 4);
  float* U3 = (float*)alloc(64 * 256 * 4);
  float* U4 = (float*)alloc(128 * 512 * 4);
  u16* featbf = (u16*)alloc((size_t)BATCH * NPTS * 512 * 2);
  u16* w5bf = (u16*)alloc((size_t)1024 * 512 * 2);
  u16* xhi = (u16*)alloc((size_t)BATCH * NPTS * 128 * 2);
  u16* xlo = (u16*)alloc((size_t)BATCH * NPTS * 128 * 2);
  double* pbuf = (double*)alloc((size_t)2048 * 512 * 8);
  float* stv = (float*)alloc(3072 * 4);
  off = (off + 255) & ~(size_t)255;
  size_t avail = (ws_size > off) ? (ws_size - off) : 0;
  size_t slab = (size_t)NPTS * NPTS * 2;              // one batch's fp16 dist matrix
  int nbfit = (int)imin((int)(avail / slab), BATCH);  // 0, 1, or 2 slabs fit
  size_t rmax = avail / ((size_t)NPTS * 2);
  int R;
  if (rmax >= NPTS) R = NPTS;
  else {
    R = (int)(rmax & ~(size_t)127);
    if (R < 128) R = 128;
  }
  _Float16* distbuf = (_Float16*)(wsb + off);

  float* sv[5] = {stv + 0, stv + 128, stv + 256, stv + 512, stv + 1024};
  float* tv[5] = {stv + 64, stv + 192, stv + 384, stv + 768, stv + 2048};
  float* Us[4] = {U1, U2, U3, U4};
  const int Cs[4] = {3, 64, 64, 128};
  const int Osz[4] = {64, 64, 128, 256};
  const int ntile = (NPTS / 128) * (NPTS / 128 + 1) / 2;  // 528

  xtrans_kernel<<<(BATCH * 3 * NPTS + 255) / 256, 256, 0, stream>>>(x, xb);
  for (int l = 0; l < 4; ++l)
    uprep_kernel<<<(Cs[l] * Osz[l] + 255) / 256, 256, 0, stream>>>(Wm[l], Us[l], Osz[l], Cs[l]);
  tobf16_kernel<<<(1024 * 512 / 4 + 255) / 256, 256, 0, stream>>>(Wm[4], w5bf, 1024 * 512 / 4);

  auto knn = [&](const float* Xbase, int lda, int C) {
    xx_kernel<<<(BATCH * NPTS + 255) / 256, 256, 0, stream>>>(Xbase, lda, C, xxb);
    size_t selems = (size_t)NPTS * NPTS;
    if (nbfit >= 1) {
      int ngroups = BATCH * NPTS * (C / 4);
      tosplit_kernel<<<(ngroups + 255) / 256, 256, 0, stream>>>(Xbase, lda, C, xhi, xlo, ngroups);
    }
    if (nbfit >= BATCH) {
      dist_sym_mfma_kernel<<<dim3(ntile, BATCH), 256, 0, stream>>>(xhi, xlo, C, xxb, distbuf,
                                                                   selems);
      topk_fast_kernel<<<dim3(NPTS / 4, BATCH), 256, 0, stream>>>(
          distbuf, selems, Xbase, (size_t)NPTS * lda, lda, C, idxb, (size_t)NPTS * KNN, 0, NPTS);
    } else if (nbfit >= 1) {
      for (int b = 0; b < BATCH; ++b) {
        const float* Xb = Xbase + (size_t)b * NPTS * lda;
        dist_sym_mfma_kernel<<<dim3(ntile, 1), 256, 0, stream>>>(
            xhi + (size_t)b * NPTS * C, xlo + (size_t)b * NPTS * C, C, xxb + (size_t)b * NPTS,
            distbuf, 0);
        topk_fast_kernel<<<dim3(NPTS / 4, 1), 256, 0, stream>>>(
            distbuf, 0, Xb, 0, lda, C, idxb + (size_t)b * NPTS * KNN, 0, 0, NPTS);
      }
    } else {
      for (int b = 0; b < BATCH; ++b) {
        const float* Xb = Xbase + (size_t)b * NPTS * lda;
        for (int n0 = 0; n0 < NPTS; n0 += R) {
          int rows = imin(R, NPTS - n0);
          gemm128<true, true><<<dim3(NPTS / 128, rows / 128), 256, 0, stream>>>(
              Xb + (size_t)n0 * lda, lda, Xb, lda, (void*)distbuf, NPTS, C,
              xxb + (size_t)b * NPTS + n0, xxb + (size_t)b * NPTS);
          topk_fast_kernel<<<dim3(rows / 4, 1), 256, 0, stream>>>(
              distbuf, 0, Xb, 0, lda, C, idxb + (size_t)b * NPTS * KNN, 0, n0, rows);
        }
      }
    }
  };

  auto edge = [&](int li, const float* Xbase, int lda, int C, int O, int colOff) {
    if (li == 0) {
      dist3_topk_kernel<<<dim3(NPTS / 4, BATCH), 256, 0, stream>>>(Xbase, idxb);
    } else {
      knn(Xbase, lda, C);
    }
    int O2 = 2 * O;
    gemm128<false, false><<<dim3(O2 / 128, BATCH * NPTS / 128), 256, 0, stream>>>(
        Xbase, lda, Us[li], O2, (void*)PQ, O2, C, nullptr, nullptr);
    int nblk = BATCH * NPTS / 4;
    if (O == 64)
      gathermax_kernel<1><<<nblk, 256, 0, stream>>>(PQ, idxb, hmax, O, pbuf);
    else if (O == 128)
      gathermax_kernel<2><<<nblk, 256, 0, stream>>>(PQ, idxb, hmax, O, pbuf);
    else
      gathermax_kernel<4><<<nblk, 256, 0, stream>>>(PQ, idxb, hmax, O, pbuf);
    bn_reduce_finalize<<<O, 256, 0, stream>>>(pbuf, nblk, O, gv[li], bvv[li],
                                              1.0 / ((double)BATCH * NPTS * KNN), sv[li], tv[li]);
    int logO = (O == 64) ? 6 : (O == 128) ? 7 : 8;
    int total = BATCH * NPTS * O;
    apply_kernel<<<(total + 255) / 256, 256, 0, stream>>>(hmax, sv[li], tv[li], feat, featbf,
                                                          colOff, logO, total);
  };

  edge(0, xb, 3, 3, 64, 0);
  edge(1, feat, 512, 64, 64, 64);
  edge(2, feat + 64, 512, 64, 128, 128);
  edge(3, feat + 128, 512, 128, 256, 256);

  fc_mfma_kernel<<<dim3(1024 / 128, BATCH * NPTS / 128), 256, 0, stream>>>(featbf, w5bf, h5);
  colstats_kernel<<<dim3(4, 64), 256, 0, stream>>>(h5, pbuf);
  bn_reduce_finalize<<<1024, 256, 0, stream>>>(pbuf, 64, 1024, gv[4], bvv[4],
                                               1.0 / ((double)BATCH * NPTS), sv[4], tv[4]);
  out_kernel<<<dim3(NPTS / 32, 1024 / 32, BATCH), 256, 0, stream>>>(h5, sv[4], tv[4], out);
}